// Round 3
// 5509.081 us; speedup vs baseline: 1.0033x; 1.0033x over previous
//
#include <hip/hip_runtime.h>
#include <math.h>

#define NVOX 250000
#define NPART 125000
#define NPTS 600000
#define NNEXT 100000
#define NDS 100000
#define NCELL 1382400

static __device__ __forceinline__ float lk(float x) { return x >= 0.f ? x : 0.1f * x; }

// bf16 helpers (RNE)
static __device__ __forceinline__ unsigned short f2bf(float f) {
    unsigned u = __float_as_uint(f);
    unsigned r = (u + 0x7FFFu + ((u >> 16) & 1u)) >> 16;
    return (unsigned short)r;
}
static __device__ __forceinline__ float bf2f(unsigned short h) {
    return __uint_as_float((unsigned)h << 16);
}

typedef short v8s __attribute__((ext_vector_type(8)));   // 8 bf16 = 4 VGPR
typedef float v4f __attribute__((ext_vector_type(4)));   // MFMA acc
#define MFMA16 __builtin_amdgcn_mfma_f32_16x16x32_bf16

// ---------------- fill ----------------
__global__ void fill_u32_kernel(unsigned* __restrict__ p, unsigned v, long n) {
    long i = (long)blockIdx.x * 256 + threadIdx.x;
    if (i < n) p[i] = v;
}

// ---------------- weight transpose + hi/lo split: Wt[k][d][c] = split(W[k][c][d]) ----------------
__global__ void wsplit_kernel(const float* __restrict__ W, unsigned short* __restrict__ hi,
                              unsigned short* __restrict__ lo) {
    int i = blockIdx.x * 256 + threadIdx.x;     // over 27*4096
    if (i < 27 * 4096) {
        int k = i >> 12, rem = i & 4095, d = rem >> 6, c = rem & 63;
        float w = W[k * 4096 + c * 64 + d];
        unsigned short h = f2bf(w);
        hi[i] = h;
        lo[i] = f2bf(w - bf2f(h));
    }
}

// ---------------- activation hi/lo split ----------------
__global__ void xsplit_kernel(const float* __restrict__ X, unsigned short* __restrict__ hi,
                              unsigned short* __restrict__ lo, long n) {
    long i = (long)blockIdx.x * 256 + threadIdx.x;
    if (i < n) {
        float x = X[i];
        unsigned short h = f2bf(x);
        hi[i] = h;
        lo[i] = f2bf(x - bf2f(h));
    }
}

// ---------------- MFMA submanifold conv (register-pipelined v3, inline) ----------------
// Y[n,d] = sum_k sum_c X[nbr[n,k],c] * W[k,c,d], X given as bf16 hi/lo, W as Wt[k][d][c] hi/lo.
// Block: 128 rows x 64 cols, 4 waves, wave = 32 rows. No LDS, no barriers.
// v3 = round-0 structure + register software pipeline (all inline, macro-expanded):
//   indices prefetched 2 k-steps ahead, X fragments double-buffered 1 k-step ahead,
//   so ~8 gather loads are in flight during every 48-MFMA compute phase.

#define LOADX(F0h0,F0h1,F0l0,F0l1,F1h0,F1h1,F1l0,F1l1,j0,j1) do {          \
    const unsigned short* x0h = Xhi + (size_t)(j0) * 64 + qo;              \
    const unsigned short* x0l = Xlo + (size_t)(j0) * 64 + qo;              \
    const unsigned short* x1h = Xhi + (size_t)(j1) * 64 + qo;              \
    const unsigned short* x1l = Xlo + (size_t)(j1) * 64 + qo;              \
    F0h0 = *(const v8s*)(x0h);      F0h1 = *(const v8s*)(x0h + 32);        \
    F0l0 = *(const v8s*)(x0l);      F0l1 = *(const v8s*)(x0l + 32);        \
    F1h0 = *(const v8s*)(x1h);      F1h1 = *(const v8s*)(x1h + 32);        \
    F1l0 = *(const v8s*)(x1l);      F1l1 = *(const v8s*)(x1l + 32);        \
} while (0)

#define COMPUTEK(kk,F0h0,F0h1,F0l0,F0l1,F1h0,F1h1,F1l0,F1l1) do {          \
    const unsigned short* wh = Wthi + (size_t)(kk) * 4096 + m * 64 + qo;   \
    const unsigned short* wl = Wtlo + (size_t)(kk) * 4096 + m * 64 + qo;   \
    _Pragma("unroll")                                                      \
    for (int ct = 0; ct < 4; ++ct) {                                       \
        v8s bh0 = *(const v8s*)(wh + ct * 1024);                           \
        v8s bh1 = *(const v8s*)(wh + ct * 1024 + 32);                      \
        v8s bl0 = *(const v8s*)(wl + ct * 1024);                           \
        v8s bl1 = *(const v8s*)(wl + ct * 1024 + 32);                      \
        acc[0][ct] = MFMA16(F0h0, bh0, acc[0][ct], 0, 0, 0);               \
        acc[0][ct] = MFMA16(F0h1, bh1, acc[0][ct], 0, 0, 0);               \
        acc[0][ct] = MFMA16(F0l0, bh0, acc[0][ct], 0, 0, 0);               \
        acc[0][ct] = MFMA16(F0l1, bh1, acc[0][ct], 0, 0, 0);               \
        acc[0][ct] = MFMA16(F0h0, bl0, acc[0][ct], 0, 0, 0);               \
        acc[0][ct] = MFMA16(F0h1, bl1, acc[0][ct], 0, 0, 0);               \
        acc[1][ct] = MFMA16(F1h0, bh0, acc[1][ct], 0, 0, 0);               \
        acc[1][ct] = MFMA16(F1h1, bh1, acc[1][ct], 0, 0, 0);               \
        acc[1][ct] = MFMA16(F1l0, bh0, acc[1][ct], 0, 0, 0);               \
        acc[1][ct] = MFMA16(F1l1, bh1, acc[1][ct], 0, 0, 0);               \
        acc[1][ct] = MFMA16(F1h0, bl0, acc[1][ct], 0, 0, 0);               \
        acc[1][ct] = MFMA16(F1h1, bl1, acc[1][ct], 0, 0, 0);               \
    }                                                                      \
} while (0)

__global__ __launch_bounds__(256) void conv_mfma_kernel(
    const unsigned short* __restrict__ Xhi, const unsigned short* __restrict__ Xlo,
    const int* __restrict__ nbr,
    const unsigned short* __restrict__ Wthi, const unsigned short* __restrict__ Wtlo,
    float* __restrict__ Y, int N)
{
    const int t = threadIdx.x;
    const int wave = t >> 6, lane = t & 63;
    const int m = lane & 15, q = lane >> 4;
    const int qo = q * 8;
    const long base = (long)blockIdx.x * 128 + wave * 32;

    long r0 = base + m;        // rowsub 0 A-row
    long r1 = base + 16 + m;   // rowsub 1 A-row
    long r0c = r0 < N ? r0 : (long)(N - 1);
    long r1c = r1 < N ? r1 : (long)(N - 1);
    const long o0g = r0c * 27, o1g = r1c * 27;

    v4f acc[2][4];
    #pragma unroll
    for (int s = 0; s < 2; ++s)
        #pragma unroll
        for (int c = 0; c < 4; ++c)
            acc[s][c] = (v4f){0.f, 0.f, 0.f, 0.f};

    // pipeline state: A-set holds fragments for even k, B-set for odd k
    v8s A0h0, A0h1, A0l0, A0l1, A1h0, A1h1, A1l0, A1l1;
    v8s B0h0, B0h1, B0l0, B0l1, B1h0, B1h1, B1l0, B1l1;

    int ja0 = nbr[o0g + 0], ja1 = nbr[o1g + 0];
    LOADX(A0h0, A0h1, A0l0, A0l1, A1h0, A1h1, A1l0, A1l1, ja0, ja1);
    int jb0 = nbr[o0g + 1], jb1 = nbr[o1g + 1];

    #pragma unroll 1
    for (int k = 0; k < 26; k += 2) {
        // gathers for k+1 in flight during compute of k
        LOADX(B0h0, B0h1, B0l0, B0l1, B1h0, B1h1, B1l0, B1l1, jb0, jb1);
        ja0 = nbr[o0g + k + 2];
        ja1 = nbr[o1g + k + 2];
        COMPUTEK(k, A0h0, A0h1, A0l0, A0l1, A1h0, A1h1, A1l0, A1l1);
        // gathers for k+2 in flight during compute of k+1
        LOADX(A0h0, A0h1, A0l0, A0l1, A1h0, A1h1, A1l0, A1l1, ja0, ja1);
        int kn = (k + 3 < 27) ? (k + 3) : 26;
        jb0 = nbr[o0g + kn];
        jb1 = nbr[o1g + kn];
        COMPUTEK(k + 1, B0h0, B0h1, B0l0, B0l1, B1h0, B1h1, B1l0, B1l1);
    }
    COMPUTEK(26, A0h0, A0h1, A0l0, A0l1, A1h0, A1h1, A1l0, A1l1);

    // C/D layout: col = lane&15, row(within 16) = q*4 + reg
    #pragma unroll
    for (int s = 0; s < 2; ++s)
        #pragma unroll
        for (int ct = 0; ct < 4; ++ct)
            #pragma unroll
            for (int rg = 0; rg < 4; ++rg) {
                long r = base + s * 16 + q * 4 + rg;
                if (r < N) Y[r * 64 + ct * 16 + m] = acc[s][ct][rg];
            }
}

// ---------------- per-column sum / sumsq ----------------
template<int CC>
__global__ __launch_bounds__(256) void colstats_kernel(const float* __restrict__ Y, int N, float* __restrict__ stats) {
    constexpr int RG = 256 / CC;
    const int t = threadIdx.x;
    const int c = t % CC, rg = t / CC;
    float s = 0.f, s2 = 0.f;
    for (long r = (long)blockIdx.x * RG + rg; r < N; r += (long)gridDim.x * RG) {
        float v = Y[r * CC + c];
        s += v; s2 += v * v;
    }
    __shared__ float sh[256], sh2[256];
    sh[t] = s; sh2[t] = s2;
    __syncthreads();
    if (t < CC) {
        #pragma unroll
        for (int g = 1; g < RG; ++g) { s += sh[g * CC + t]; s2 += sh2[g * CC + t]; }
        atomicAdd(&stats[t], s);
        atomicAdd(&stats[CC + t], s2);
    }
}

__global__ void mkscale_kernel(float* __restrict__ stats, const float* __restrict__ g,
                               const float* __restrict__ b, float invN, int CC) {
    int c = threadIdx.x;
    if (c < CC) {
        float mu = stats[c] * invN;
        float var = stats[CC + c] * invN - mu * mu;
        float sc = g[c] * rsqrtf(var + 1e-5f);
        stats[2 * CC + c] = sc;
        stats[3 * CC + c] = b[c] - mu * sc;
    }
}

// MODE: 0 = y*s+sh ; 1 = leaky(y*s+sh) ; 2 = leaky(y*s+sh + res) ; 3 = res2 + leaky(y*s+sh + res)
// PAIR: also emit bf16 hi/lo split of the result (next conv's input)
template<int CC, int MODE, int PAIR>
__global__ __launch_bounds__(256) void apply_bn_kernel(
    const float* __restrict__ Yin, const float* __restrict__ stats,
    const float* __restrict__ res, const float* __restrict__ res2,
    float* __restrict__ out, unsigned short* __restrict__ ohi,
    unsigned short* __restrict__ olo, long n4)
{
    long i = (long)blockIdx.x * 256 + threadIdx.x;
    if (i >= n4) return;
    int c4 = (int)(i % (CC / 4)) * 4;
    float4 y = ((const float4*)Yin)[i];
    float4 sc = *(const float4*)(stats + 2 * CC + c4);
    float4 sf = *(const float4*)(stats + 3 * CC + c4);
    float x0 = y.x * sc.x + sf.x;
    float x1 = y.y * sc.y + sf.y;
    float x2 = y.z * sc.z + sf.z;
    float x3 = y.w * sc.w + sf.w;
    if (MODE >= 2) {
        float4 rr = ((const float4*)res)[i];
        x0 += rr.x; x1 += rr.y; x2 += rr.z; x3 += rr.w;
    }
    if (MODE >= 1) { x0 = lk(x0); x1 = lk(x1); x2 = lk(x2); x3 = lk(x3); }
    if (MODE == 3) {
        float4 rr2 = ((const float4*)res2)[i];
        x0 += rr2.x; x1 += rr2.y; x2 += rr2.z; x3 += rr2.w;
    }
    ((float4*)out)[i] = make_float4(x0, x1, x2, x3);
    if (PAIR) {
        ushort4 h, l;
        h.x = f2bf(x0); l.x = f2bf(x0 - bf2f(h.x));
        h.y = f2bf(x1); l.y = f2bf(x1 - bf2f(h.y));
        h.z = f2bf(x2); l.z = f2bf(x2 - bf2f(h.z));
        h.w = f2bf(x3); l.w = f2bf(x3 - bf2f(h.w));
        *(ushort4*)(ohi + i * 4) = h;
        *(ushort4*)(olo + i * 4) = l;
    }
}

// ---------------- generic tiled GEMM: Y = act(X[N,CIN] @ W[CIN,COUT] + bias) ----------------
template<int CIN, int COUT, int ACT>
__global__ __launch_bounds__(256) void gemm_kernel(
    const float* __restrict__ X, const float* __restrict__ W,
    const float* __restrict__ bias, float* __restrict__ Y, int N)
{
    constexpr int TX = COUT / 4;
    constexpr int TY = 256 / TX;
    constexpr int ROWS = TY * 4;
    constexpr int CHUNK = (CIN < 64) ? CIN : 64;
    constexpr int NCH = CIN / CHUNK;
    __shared__ float XsT[CHUNK][ROWS + 4];
    __shared__ float Ws[CHUNK][COUT + 4];
    const int t = threadIdx.x;
    const int row0 = blockIdx.x * ROWS;
    const int ty = t / TX, tx = t % TX;
    float acc[4][4] = {{0.f}};
    for (int cc = 0; cc < NCH; ++cc) {
        __syncthreads();
        for (int i = t * 4; i < CHUNK * COUT; i += 1024) {
            int c = i / COUT, d = i % COUT;
            *(float4*)&Ws[c][d] = *(const float4*)(W + (size_t)(cc * CHUNK + c) * COUT + d);
        }
        for (int i = t * 4; i < ROWS * CHUNK; i += 1024) {
            int r = i / CHUNK, c0 = i % CHUNK;
            int gr = row0 + r;
            float4 v = make_float4(0.f, 0.f, 0.f, 0.f);
            if (gr < N) v = *(const float4*)(X + (size_t)gr * CIN + cc * CHUNK + c0);
            XsT[c0 + 0][r] = v.x; XsT[c0 + 1][r] = v.y; XsT[c0 + 2][r] = v.z; XsT[c0 + 3][r] = v.w;
        }
        __syncthreads();
        #pragma unroll 8
        for (int c = 0; c < CHUNK; ++c) {
            float4 xv = *(const float4*)&XsT[c][ty * 4];
            float4 wv = *(const float4*)&Ws[c][tx * 4];
            acc[0][0] += xv.x * wv.x; acc[0][1] += xv.x * wv.y; acc[0][2] += xv.x * wv.z; acc[0][3] += xv.x * wv.w;
            acc[1][0] += xv.y * wv.x; acc[1][1] += xv.y * wv.y; acc[1][2] += xv.y * wv.z; acc[1][3] += xv.y * wv.w;
            acc[2][0] += xv.z * wv.x; acc[2][1] += xv.z * wv.y; acc[2][2] += xv.z * wv.z; acc[2][3] += xv.z * wv.w;
            acc[3][0] += xv.w * wv.x; acc[3][1] += xv.w * wv.y; acc[3][2] += xv.w * wv.z; acc[3][3] += xv.w * wv.w;
        }
    }
    float4 bv = *(const float4*)(bias + tx * 4);
    #pragma unroll
    for (int i2 = 0; i2 < 4; ++i2) {
        int gr = row0 + ty * 4 + i2;
        if (gr < N) {
            float o0 = acc[i2][0] + bv.x, o1 = acc[i2][1] + bv.y;
            float o2 = acc[i2][2] + bv.z, o3 = acc[i2][3] + bv.w;
            if (ACT) { o0 = lk(o0); o1 = lk(o1); o2 = lk(o2); o3 = lk(o3); }
            *(float4*)(Y + (size_t)gr * COUT + tx * 4) = make_float4(o0, o1, o2, o3);
        }
    }
}

// ---------------- fused layer_out + scatter-add (fp32) ----------------
__global__ __launch_bounds__(256) void layer_out_fused_kernel(
    const float* __restrict__ iden, const float* __restrict__ h3,
    const int* __restrict__ cil, const int* __restrict__ dsinv,
    const float* __restrict__ Wo1, const float* __restrict__ bo1,
    const float* __restrict__ Wo2, const float* __restrict__ bo2,
    const int* __restrict__ cin,
    float* __restrict__ psum, float* __restrict__ pcnt, int N)
{
    __shared__ float XsT[64][68];
    __shared__ float Ws[64][68];
    const int t = threadIdx.x;
    const int row0 = blockIdx.x * 64;
    const int ty = t >> 4, tx = t & 15;
    const int lr = t >> 2, ls = t & 3;
    const int gr = row0 + lr;
    int v = (gr < N) ? cil[gr] : 0;
    int vds = dsinv[v];
    float acc[4][4] = {{0.f}};
    for (int cc = 0; cc < 2; ++cc) {
        const float* src = (cc == 0) ? (iden + (size_t)v * 64) : (h3 + (size_t)vds * 64);
        const float* xr = src + ls * 16;
        float4 v0 = *(const float4*)(xr);
        float4 v1 = *(const float4*)(xr + 4);
        float4 v2f = *(const float4*)(xr + 8);
        float4 v3 = *(const float4*)(xr + 12);
        const float* Wk = Wo1 + (size_t)cc * 4096;
        float4 w0 = *(const float4*)(Wk + t * 4);
        float4 w1 = *(const float4*)(Wk + t * 4 + 1024);
        float4 w2 = *(const float4*)(Wk + t * 4 + 2048);
        float4 w3 = *(const float4*)(Wk + t * 4 + 3072);
        __syncthreads();
        {
            int i0 = t * 4;
            *(float4*)&Ws[i0 >> 6][i0 & 63] = w0; i0 += 1024;
            *(float4*)&Ws[i0 >> 6][i0 & 63] = w1; i0 += 1024;
            *(float4*)&Ws[i0 >> 6][i0 & 63] = w2; i0 += 1024;
            *(float4*)&Ws[i0 >> 6][i0 & 63] = w3;
        }
        const int cb = ls * 16;
        XsT[cb + 0][lr] = v0.x; XsT[cb + 1][lr] = v0.y; XsT[cb + 2][lr] = v0.z; XsT[cb + 3][lr] = v0.w;
        XsT[cb + 4][lr] = v1.x; XsT[cb + 5][lr] = v1.y; XsT[cb + 6][lr] = v1.z; XsT[cb + 7][lr] = v1.w;
        XsT[cb + 8][lr] = v2f.x; XsT[cb + 9][lr] = v2f.y; XsT[cb + 10][lr] = v2f.z; XsT[cb + 11][lr] = v2f.w;
        XsT[cb + 12][lr] = v3.x; XsT[cb + 13][lr] = v3.y; XsT[cb + 14][lr] = v3.z; XsT[cb + 15][lr] = v3.w;
        __syncthreads();
        #pragma unroll 16
        for (int c = 0; c < 64; ++c) {
            float4 xv = *(const float4*)&XsT[c][ty * 4];
            float4 wv = *(const float4*)&Ws[c][tx * 4];
            acc[0][0] += xv.x * wv.x; acc[0][1] += xv.x * wv.y; acc[0][2] += xv.x * wv.z; acc[0][3] += xv.x * wv.w;
            acc[1][0] += xv.y * wv.x; acc[1][1] += xv.y * wv.y; acc[1][2] += xv.y * wv.z; acc[1][3] += xv.y * wv.w;
            acc[2][0] += xv.z * wv.x; acc[2][1] += xv.z * wv.y; acc[2][2] += xv.z * wv.z; acc[2][3] += xv.z * wv.w;
            acc[3][0] += xv.w * wv.x; acc[3][1] += xv.w * wv.y; acc[3][2] += xv.w * wv.z; acc[3][3] += xv.w * wv.w;
        }
    }
    float4 u0 = *(const float4*)(Wo2 + t * 4);
    float4 u1 = *(const float4*)(Wo2 + t * 4 + 1024);
    float4 u2 = *(const float4*)(Wo2 + t * 4 + 2048);
    float4 u3 = *(const float4*)(Wo2 + t * 4 + 3072);
    float4 b1v = *(const float4*)(bo1 + tx * 4);
    __syncthreads();
    {
        int i0 = t * 4;
        *(float4*)&Ws[i0 >> 6][i0 & 63] = u0; i0 += 1024;
        *(float4*)&Ws[i0 >> 6][i0 & 63] = u1; i0 += 1024;
        *(float4*)&Ws[i0 >> 6][i0 & 63] = u2; i0 += 1024;
        *(float4*)&Ws[i0 >> 6][i0 & 63] = u3;
    }
    #pragma unroll
    for (int i = 0; i < 4; ++i) {
        XsT[tx * 4 + 0][ty * 4 + i] = lk(acc[i][0] + b1v.x);
        XsT[tx * 4 + 1][ty * 4 + i] = lk(acc[i][1] + b1v.y);
        XsT[tx * 4 + 2][ty * 4 + i] = lk(acc[i][2] + b1v.z);
        XsT[tx * 4 + 3][ty * 4 + i] = lk(acc[i][3] + b1v.w);
    }
    __syncthreads();
    float acc2[4][4] = {{0.f}};
    #pragma unroll 16
    for (int c = 0; c < 64; ++c) {
        float4 xv = *(const float4*)&XsT[c][ty * 4];
        float4 wv = *(const float4*)&Ws[c][tx * 4];
        acc2[0][0] += xv.x * wv.x; acc2[0][1] += xv.x * wv.y; acc2[0][2] += xv.x * wv.z; acc2[0][3] += xv.x * wv.w;
        acc2[1][0] += xv.y * wv.x; acc2[1][1] += xv.y * wv.y; acc2[1][2] += xv.y * wv.z; acc2[1][3] += xv.y * wv.w;
        acc2[2][0] += xv.z * wv.x; acc2[2][1] += xv.z * wv.y; acc2[2][2] += xv.z * wv.z; acc2[2][3] += xv.z * wv.w;
        acc2[3][0] += xv.w * wv.x; acc2[3][1] += xv.w * wv.y; acc2[3][2] += xv.w * wv.z; acc2[3][3] += xv.w * wv.w;
    }
    float4 b2v = *(const float4*)(bo2 + tx * 4);
    #pragma unroll
    for (int i2 = 0; i2 < 4; ++i2) {
        int gr2 = row0 + ty * 4 + i2;
        if (gr2 < N) {
            int tg = cin[gr2];
            float* dst = psum + (size_t)tg * 64 + tx * 4;
            atomicAdd(dst + 0, acc2[i2][0] + b2v.x);
            atomicAdd(dst + 1, acc2[i2][1] + b2v.y);
            atomicAdd(dst + 2, acc2[i2][2] + b2v.z);
            atomicAdd(dst + 3, acc2[i2][3] + b2v.w);
            if (tx == 0) atomicAdd(pcnt + tg, 1.0f);
        }
    }
}

// ---------------- scatter add (segment sum) ----------------
__global__ void scatter_add_kernel(const float* __restrict__ X, const int* __restrict__ idx,
                                   float* __restrict__ sum, float* __restrict__ cnt, long N) {
    long i = (long)blockIdx.x * 256 + threadIdx.x;
    if (i < N * 64) {
        long n = i >> 6; int c = (int)(i & 63);
        int tg = idx[n];
        atomicAdd(&sum[(size_t)tg * 64 + c], X[i]);
        if (c == 0) atomicAdd(&cnt[tg], 1.0f);
    }
}

__global__ void divcnt_kernel(float* __restrict__ sum, const float* __restrict__ cnt, long total) {
    long i = (long)blockIdx.x * 256 + threadIdx.x;
    if (i < total) sum[i] /= fmaxf(cnt[i >> 6], 1.0f);
}

__global__ void gather_out_kernel(const float* __restrict__ pf, const int* __restrict__ cin,
                                  float* __restrict__ out, int N) {
    long i = (long)blockIdx.x * 256 + threadIdx.x;
    if (i < (long)N * 16) {
        int p = (int)(i >> 4), q = (int)(i & 15);
        ((float4*)out)[i] = *(const float4*)(pf + (size_t)cin[p] * 64 + q * 4);
    }
}

// ---------------- logit conv: 1 wave per row, lane = channel ----------------
__global__ __launch_bounds__(256) void logit_kernel(
    const float* __restrict__ vp, const int* __restrict__ nbrp,
    const float* __restrict__ Wlog, const float* __restrict__ blog,
    float* __restrict__ out, int N)
{
    __shared__ float Wl[27 * 64];
    const int t = threadIdx.x;
    for (int i = t; i < 1728; i += 256) Wl[i] = Wlog[i];
    __syncthreads();
    const int wave = t >> 6, lane = t & 63;
    for (long row = (long)blockIdx.x * 4 + wave; row < N; row += (long)gridDim.x * 4) {
        float acc = 0.f;
        #pragma unroll
        for (int k = 0; k < 27; ++k) {
            int j = nbrp[row * 27 + k];
            acc += vp[(size_t)j * 64 + lane] * Wl[k * 64 + lane];
        }
        for (int off = 32; off > 0; off >>= 1) acc += __shfl_down(acc, off, 64);
        if (lane == 0) out[row] = acc + blog[0];
    }
}

// ---------------- loss ----------------
__global__ void loss_scatter1_kernel(const int* __restrict__ coors, int* __restrict__ tflag,
                                     int* __restrict__ winner, int N, int NP) {
    int n = blockIdx.x * 256 + threadIdx.x;
    if (n < N) {
        int b = coors[n * 4], x = coors[n * 4 + 1], y = coors[n * 4 + 2], z = coors[n * 4 + 3];
        int flat = ((b * 240 + x) * 180 + y) * 16 + z;
        tflag[flat] = 1;
        if (n < NP) atomicMax(&winner[flat], n);
    }
}

__global__ void loss_scatter2_kernel(const int* __restrict__ coors, const int* __restrict__ winner,
                                     const float* __restrict__ logit, float* __restrict__ xdense, int NP) {
    int n = blockIdx.x * 256 + threadIdx.x;
    if (n < NP) {
        int b = coors[n * 4], x = coors[n * 4 + 1], y = coors[n * 4 + 2], z = coors[n * 4 + 3];
        int flat = ((b * 240 + x) * 180 + y) * 16 + z;
        if (winner[flat] == n) xdense[flat] = logit[n];
    }
}

__global__ void loss_reduce_kernel(const float* __restrict__ xdense, const int* __restrict__ tflag,
                                   float* __restrict__ accum) {
    int i = blockIdx.x * 256 + threadIdx.x;
    float x = xdense[i];
    float tt = (float)tflag[i];
    float term = fmaxf(x, 0.f) - x * tt + log1pf(expf(-fabsf(x)));
    __shared__ float sh[256];
    sh[threadIdx.x] = term;
    __syncthreads();
    for (int s = 128; s > 0; s >>= 1) {
        if (threadIdx.x < s) sh[threadIdx.x] += sh[threadIdx.x + s];
        __syncthreads();
    }
    if (threadIdx.x == 0) atomicAdd(accum, sh[0]);
}

__global__ void loss_final_kernel(const float* __restrict__ accum, float* __restrict__ out) {
    out[0] = accum[0] / (float)NCELL;
}

// ---------------- host orchestration ----------------
extern "C" void kernel_launch(void* const* d_in, const int* in_sizes, int n_in,
                              void* d_out, int out_size, void* d_ws, size_t ws_size,
                              hipStream_t stream)
{
    const float* feats  = (const float*)d_in[0];
    const float* featsp = (const float*)d_in[1];
    const float* Wv11 = (const float*)d_in[2];
    const float* Wv12 = (const float*)d_in[3];
    const float* Wv21 = (const float*)d_in[4];
    const float* Wv22 = (const float*)d_in[5];
    const float* g11 = (const float*)d_in[6];
    const float* g12 = (const float*)d_in[7];
    const float* g21 = (const float*)d_in[8];
    const float* g22 = (const float*)d_in[9];
    const float* b11 = (const float*)d_in[10];
    const float* b12 = (const float*)d_in[11];
    const float* b21 = (const float*)d_in[12];
    const float* b22 = (const float*)d_in[13];
    const float* Wlog = (const float*)d_in[14];
    const float* blog = (const float*)d_in[15];
    const float* Wi  = (const float*)d_in[16];
    const float* bi  = (const float*)d_in[17];
    const float* Wp1 = (const float*)d_in[18];
    const float* bp1 = (const float*)d_in[19];
    const float* gp1 = (const float*)d_in[20];
    const float* bp1n = (const float*)d_in[21];
    const float* Wp2 = (const float*)d_in[22];
    const float* bp2 = (const float*)d_in[23];
    const float* gp2 = (const float*)d_in[24];
    const float* bp2n = (const float*)d_in[25];
    const float* Wp3 = (const float*)d_in[26];
    const float* bp3 = (const float*)d_in[27];
    const float* Wo1 = (const float*)d_in[28];
    const float* bo1 = (const float*)d_in[29];
    const float* Wo2 = (const float*)d_in[30];
    const float* bo2 = (const float*)d_in[31];
    const int* nbr   = (const int*)d_in[32];
    const int* nbrp  = (const int*)d_in[33];
    const int* coors = (const int*)d_in[34];
    const int* cil   = (const int*)d_in[35];
    const int* cin   = (const int*)d_in[36];
    const int* dsinv = (const int*)d_in[37];
    (void)in_sizes; (void)n_in; (void)out_size; (void)ws_size;

    // ---- ws layout (46,952,561 floats ~= 187.8 MB; round 2 proved >=192 MB available) ----
    float* ws = (float*)d_ws;
    float* A     = ws;                  // 16M : conv fp32 out (full & partial) -> identity
    float* H     = ws + 16000000L;      // 16M : X1 fp32 -> feat_sum
    float* Hpf32 = ws + 32000000L;      //  8M : partial X1 residual
    float* psum  = ws + 40000000L;      //  6.4M
    float* pcnt  = ws + 46400000L;      //  0.1M
    unsigned short* wt = (unsigned short*)(ws + 46500000L);  // 8 x 110592 bf16 (442,368 floats)
    float* stats = ws + 46950000L;      //  10 x 256
    float* lacc  = ws + 46952560L;      //  1
    unsigned short* wh11 = wt + 0L * 110592;
    unsigned short* wl11 = wt + 1L * 110592;
    unsigned short* wh12 = wt + 2L * 110592;
    unsigned short* wl12 = wt + 3L * 110592;
    unsigned short* wh21 = wt + 4L * 110592;
    unsigned short* wl21 = wt + 5L * 110592;
    unsigned short* wh22 = wt + 6L * 110592;
    unsigned short* wl22 = wt + 7L * 110592;

    // ---- d_out as scratch (38.4M floats, fully overwritten by final gather) ----
    float* o = (float*)d_out;
    // conv-phase: full-tensor bf16 pairs
    unsigned short* F0h = (unsigned short*)(o);               // 16M bf16
    unsigned short* F0l = (unsigned short*)(o + 8000000L);
    unsigned short* F1h = (unsigned short*)(o + 16000000L);
    unsigned short* F1l = (unsigned short*)(o + 24000000L);
    // partial-phase pairs (after full convs done)
    unsigned short* P0h = (unsigned short*)(o);
    unsigned short* P0l = (unsigned short*)(o + 4000000L);
    unsigned short* P1h = (unsigned short*)(o + 8000000L);
    unsigned short* P1l = (unsigned short*)(o + 12000000L);
    float* Cp = o + 16000000L;          // 8M : Vp fp32 (logit input)
    // loss region (disjoint from pairs)
    float* xdense = o + 32000000L;      // 1.3824M
    int*   tflag  = (int*)(o + 33382400L);
    int*   winner = (int*)(o + 34764800L);
    float* logitb = o + 36147200L;      // 125k
    float* dscnt  = o + 36272200L;      // 100k
    // post-conv phase (pairs dead)
    float* dssum = o;                   // 6.4M
    float* t1b   = o + 6400000L;        // 3.2M
    float* t2b   = o + 9600000L;        // 3.2M
    float* h3b   = o + 12800000L;       // 6.4M (overlaps dead Cp tail: used only after logit)
    float* out = (float*)d_out;

    auto cdiv = [](long a, long b) { return (unsigned)((a + b - 1) / b); };
    dim3 B256(256);

    // ---- inits ----
    fill_u32_kernel<<<cdiv(2561, 256), B256, 0, stream>>>((unsigned*)stats, 0u, 2561);
    fill_u32_kernel<<<cdiv(6500000, 256), B256, 0, stream>>>((unsigned*)psum, 0u, 6500000);
    fill_u32_kernel<<<cdiv(2764800, 256), B256, 0, stream>>>((unsigned*)xdense, 0u, 2764800);   // xdense+tflag
    fill_u32_kernel<<<cdiv(1382400, 256), B256, 0, stream>>>((unsigned*)winner, 0xFFFFFFFFu, 1382400);

    // ---- weight transpose + split ----
    wsplit_kernel<<<432, B256, 0, stream>>>(Wv11, wh11, wl11);
    wsplit_kernel<<<432, B256, 0, stream>>>(Wv12, wh12, wl12);
    wsplit_kernel<<<432, B256, 0, stream>>>(Wv21, wh21, wl21);
    wsplit_kernel<<<432, B256, 0, stream>>>(Wv22, wh22, wl22);

    // ---- full tensor chain ----
    xsplit_kernel<<<cdiv(16000000, 256), B256, 0, stream>>>(feats, F0h, F0l, 16000000L);
    // s0: conv1(F0) -> A ; bn leaky -> A(inplace) + F1
    conv_mfma_kernel<<<cdiv(NVOX, 128), B256, 0, stream>>>(F0h, F0l, nbr, wh11, wl11, A, NVOX);
    colstats_kernel<64><<<256, B256, 0, stream>>>(A, NVOX, stats + 0 * 256);
    mkscale_kernel<<<1, 64, 0, stream>>>(stats + 0 * 256, g11, b11, 1.0f / NVOX, 64);
    apply_bn_kernel<64, 1, 1><<<cdiv(NVOX * 16L, 256), B256, 0, stream>>>(A, stats + 0 * 256, nullptr, nullptr, A, F1h, F1l, NVOX * 16L);
    // s1: conv2(F1) -> A ; bn + res(feats) leaky -> H(=X1) + F0
    conv_mfma_kernel<<<cdiv(NVOX, 128), B256, 0, stream>>>(F1h, F1l, nbr, wh12, wl12, A, NVOX);
    colstats_kernel<64><<<256, B256, 0, stream>>>(A, NVOX, stats + 1 * 256);
    mkscale_kernel<<<1, 64, 0, stream>>>(stats + 1 * 256, g12, b12, 1.0f / NVOX, 64);
    apply_bn_kernel<64, 2, 1><<<cdiv(NVOX * 16L, 256), B256, 0, stream>>>(A, stats + 1 * 256, feats, nullptr, H, F0h, F0l, NVOX * 16L);
    // s2: conv3(F0) -> A ; bn leaky -> A + F1
    conv_mfma_kernel<<<cdiv(NVOX, 128), B256, 0, stream>>>(F0h, F0l, nbr, wh21, wl21, A, NVOX);
    colstats_kernel<64><<<256, B256, 0, stream>>>(A, NVOX, stats + 2 * 256);
    mkscale_kernel<<<1, 64, 0, stream>>>(stats + 2 * 256, g21, b21, 1.0f / NVOX, 64);
    apply_bn_kernel<64, 1, 1><<<cdiv(NVOX * 16L, 256), B256, 0, stream>>>(A, stats + 2 * 256, nullptr, nullptr, A, F1h, F1l, NVOX * 16L);
    // s3: conv4(F1) -> A ; bn + res(X1=H) leaky + feats -> H(=feat_sum)
    conv_mfma_kernel<<<cdiv(NVOX, 128), B256, 0, stream>>>(F1h, F1l, nbr, wh22, wl22, A, NVOX);
    colstats_kernel<64><<<256, B256, 0, stream>>>(A, NVOX, stats + 3 * 256);
    mkscale_kernel<<<1, 64, 0, stream>>>(stats + 3 * 256, g22, b22, 1.0f / NVOX, 64);
    apply_bn_kernel<64, 3, 0><<<cdiv(NVOX * 16L, 256), B256, 0, stream>>>(A, stats + 3 * 256, H, feats, H, nullptr, nullptr, NVOX * 16L);

    // ---- partial tensor chain (same weights) ----
    xsplit_kernel<<<cdiv(8000000, 256), B256, 0, stream>>>(featsp, P0h, P0l, 8000000L);
    conv_mfma_kernel<<<cdiv(NPART, 128), B256, 0, stream>>>(P0h, P0l, nbrp, wh11, wl11, A, NPART);
    colstats_kernel<64><<<256, B256, 0, stream>>>(A, NPART, stats + 4 * 256);
    mkscale_kernel<<<1, 64, 0, stream>>>(stats + 4 * 256, g11, b11, 1.0f / NPART, 64);
    apply_bn_kernel<64, 1, 1><<<cdiv(NPART * 16L, 256), B256, 0, stream>>>(A, stats + 4 * 256, nullptr, nullptr, A, P1h, P1l, NPART * 16L);
    conv_mfma_kernel<<<cdiv(NPART, 128), B256, 0, stream>>>(P1h, P1l, nbrp, wh12, wl12, A, NPART);
    colstats_kernel<64><<<256, B256, 0, stream>>>(A, NPART, stats + 5 * 256);
    mkscale_kernel<<<1, 64, 0, stream>>>(stats + 5 * 256, g12, b12, 1.0f / NPART, 64);
    apply_bn_kernel<64, 2, 1><<<cdiv(NPART * 16L, 256), B256, 0, stream>>>(A, stats + 5 * 256, featsp, nullptr, Hpf32, P0h, P0l, NPART * 16L);
    conv_mfma_kernel<<<cdiv(NPART, 128), B256, 0, stream>>>(P0h, P0l, nbrp, wh21, wl21, A, NPART);
    colstats_kernel<64><<<256, B256, 0, stream>>>(A, NPART, stats + 6 * 256);
    mkscale_kernel<<<1, 64, 0, stream>>>(stats + 6 * 256, g21, b21, 1.0f / NPART, 64);
    apply_bn_kernel<64, 1, 1><<<cdiv(NPART * 16L, 256), B256, 0, stream>>>(A, stats + 6 * 256, nullptr, nullptr, A, P1h, P1l, NPART * 16L);
    conv_mfma_kernel<<<cdiv(NPART, 128), B256, 0, stream>>>(P1h, P1l, nbrp, wh22, wl22, A, NPART);
    colstats_kernel<64><<<256, B256, 0, stream>>>(A, NPART, stats + 7 * 256);
    mkscale_kernel<<<1, 64, 0, stream>>>(stats + 7 * 256, g22, b22, 1.0f / NPART, 64);
    apply_bn_kernel<64, 2, 0><<<cdiv(NPART * 16L, 256), B256, 0, stream>>>(A, stats + 7 * 256, Hpf32, nullptr, Cp, nullptr, nullptr, NPART * 16L);

    // ---- logits + BCE loss ----
    logit_kernel<<<cdiv(NPART, 4), B256, 0, stream>>>(Cp, nbrp, Wlog, blog, logitb, NPART);
    loss_scatter1_kernel<<<cdiv(NVOX, 256), B256, 0, stream>>>(coors, tflag, winner, NVOX, NPART);
    loss_scatter2_kernel<<<cdiv(NPART, 256), B256, 0, stream>>>(coors, winner, logitb, xdense, NPART);
    loss_reduce_kernel<<<NCELL / 256, B256, 0, stream>>>(xdense, tflag, lacc);

    // ---- point encoder (pairs dead; reuse o[0..19.2M)) ----
    fill_u32_kernel<<<cdiv(6400000, 256), B256, 0, stream>>>((unsigned*)dssum, 0u, 6400000);
    fill_u32_kernel<<<cdiv(100000, 256), B256, 0, stream>>>((unsigned*)dscnt, 0u, 100000);
    scatter_add_kernel<<<cdiv((long)NVOX * 64, 256), B256, 0, stream>>>(H, dsinv, dssum, dscnt, (long)NVOX);
    divcnt_kernel<<<cdiv((long)NDS * 64, 256), B256, 0, stream>>>(dssum, dscnt, (long)NDS * 64);
    gemm_kernel<64, 64, 1><<<cdiv(NVOX, 64), B256, 0, stream>>>(H, Wi, bi, A, NVOX);   // A = identity

    gemm_kernel<64, 32, 1><<<cdiv(NDS, 128), B256, 0, stream>>>(dssum, Wp1, bp1, t1b, NDS);
    colstats_kernel<32><<<256, B256, 0, stream>>>(t1b, NDS, stats + 8 * 256);
    mkscale_kernel<<<1, 64, 0, stream>>>(stats + 8 * 256, gp1, bp1n, 1.0f / NDS, 32);
    apply_bn_kernel<32, 0, 0><<<cdiv((long)NDS * 8, 256), B256, 0, stream>>>(t1b, stats + 8 * 256, nullptr, nullptr, t1b, nullptr, nullptr, (long)NDS * 8);

    gemm_kernel<32, 32, 1><<<cdiv(NDS, 128), B256, 0, stream>>>(t1b, Wp2, bp2, t2b, NDS);
    colstats_kernel<32><<<256, B256, 0, stream>>>(t2b, NDS, stats + 9 * 256);
    mkscale_kernel<<<1, 64, 0, stream>>>(stats + 9 * 256, gp2, bp2n, 1.0f / NDS, 32);
    apply_bn_kernel<32, 0, 0><<<cdiv((long)NDS * 8, 256), B256, 0, stream>>>(t2b, stats + 9 * 256, nullptr, nullptr, t2b, nullptr, nullptr, (long)NDS * 8);

    gemm_kernel<32, 64, 1><<<cdiv(NDS, 64), B256, 0, stream>>>(t2b, Wp3, bp3, h3b, NDS);

    // ---- fused layer_out + scatter-mean ----
    layer_out_fused_kernel<<<cdiv(NPTS, 64), B256, 0, stream>>>(A, h3b, cil, dsinv, Wo1, bo1, Wo2, bo2, cin, psum, pcnt, NPTS);
    divcnt_kernel<<<cdiv((long)NNEXT * 64, 256), B256, 0, stream>>>(psum, pcnt, (long)NNEXT * 64);

    // ---- final outputs ----
    gather_out_kernel<<<cdiv((long)NPTS * 16, 256), B256, 0, stream>>>(psum, cin, out, NPTS);
    loss_final_kernel<<<1, 1, 0, stream>>>(lacc, out + 38400000L);
}

// Round 4
// 3845.905 us; speedup vs baseline: 1.4372x; 1.4325x over previous
//
#include <hip/hip_runtime.h>
#include <math.h>

#define NVOX 250000
#define NPART 125000
#define NPTS 600000
#define NNEXT 100000
#define NDS 100000
#define NCELL 1382400

static __device__ __forceinline__ float lk(float x) { return x >= 0.f ? x : 0.1f * x; }

// bf16 helpers (RNE)
static __device__ __forceinline__ unsigned short f2bf(float f) {
    unsigned u = __float_as_uint(f);
    unsigned r = (u + 0x7FFFu + ((u >> 16) & 1u)) >> 16;
    return (unsigned short)r;
}
static __device__ __forceinline__ float bf2f(unsigned short h) {
    return __uint_as_float((unsigned)h << 16);
}

typedef short v8s __attribute__((ext_vector_type(8)));   // 8 bf16 = 4 VGPR
typedef float v4f __attribute__((ext_vector_type(4)));   // MFMA acc
#define MFMA16 __builtin_amdgcn_mfma_f32_16x16x32_bf16

// ---------------- fill ----------------
__global__ void fill_u32_kernel(unsigned* __restrict__ p, unsigned v, long n) {
    long i = (long)blockIdx.x * 256 + threadIdx.x;
    if (i < n) p[i] = v;
}

// ---------------- weight transpose + hi/lo split: Wt[k][d][c] = split(W[k][c][d]) ----------------
__global__ void wsplit_kernel(const float* __restrict__ W, unsigned short* __restrict__ hi,
                              unsigned short* __restrict__ lo) {
    int i = blockIdx.x * 256 + threadIdx.x;     // over 27*4096
    if (i < 27 * 4096) {
        int k = i >> 12, rem = i & 4095, d = rem >> 6, c = rem & 63;
        float w = W[k * 4096 + c * 64 + d];
        unsigned short h = f2bf(w);
        hi[i] = h;
        lo[i] = f2bf(w - bf2f(h));
    }
}

// ---------------- activation hi/lo split ----------------
__global__ void xsplit_kernel(const float* __restrict__ X, unsigned short* __restrict__ hi,
                              unsigned short* __restrict__ lo, long n) {
    long i = (long)blockIdx.x * 256 + threadIdx.x;
    if (i < n) {
        float x = X[i];
        unsigned short h = f2bf(x);
        hi[i] = h;
        lo[i] = f2bf(x - bf2f(h));
    }
}

// ---------------- MFMA submanifold conv (v4: W staged in LDS, double-buffered) ----------------
// Y[n,d] = sum_k sum_c X[nbr[n,k],c] * W[k,c,d], X given as bf16 hi/lo, W as Wt[k][d][c] hi/lo.
// Block: 128 rows x 64 cols, 4 waves, wave = 32 rows.
// v4 rationale (counters r0/r3): conv time invariant to occupancy & per-wave pipelining,
// all pipes idle -> per-CU outstanding-miss (MSHR) ceiling. Per wave*k, W re-reads were
// 256 L1-miss lines vs X's 128. Staging W[k] in LDS (16KB, 2-buf, reg-staged, XOR-swizzled
// to kill the 16-way ds_read bank conflict) cuts MSHR demand ~2.5x. Numerics identical.
__global__ __launch_bounds__(256) void conv_mfma_kernel(
    const unsigned short* __restrict__ Xhi, const unsigned short* __restrict__ Xlo,
    const int* __restrict__ nbr,
    const unsigned short* __restrict__ Wthi, const unsigned short* __restrict__ Wtlo,
    float* __restrict__ Y, int N)
{
    __shared__ __align__(16) unsigned short Wlds[2][8192];   // 2 bufs x (hi 8KB | lo 8KB) = 32 KB

    const int t = threadIdx.x;
    const int wave = t >> 6, lane = t & 63;
    const int m = lane & 15, q = lane >> 4;
    const int qo = q * 8;
    const long base = (long)blockIdx.x * 128 + wave * 32;

    long r0 = base + m;        // rowsub 0 A-row
    long r1 = base + 16 + m;   // rowsub 1 A-row
    long r0c = r0 < N ? r0 : (long)(N - 1);
    long r1c = r1 < N ? r1 : (long)(N - 1);
    const long o0g = r0c * 27, o1g = r1c * 27;

    // staging geometry: thread covers 4 x 16B of the 16KB (hi|lo) tile, bijective over 256 threads
    const int zb = wave * 4096 + lane * 16;
    const int z0 = zb, z1 = zb + 1024, z2 = zb + 2048, z3 = zb + 3072;
    // XOR swizzle (row = byte>>7, use row&7 on bits 4-6) -> conflict-free ds_read_b128
    const int d0 = z0 ^ (((z0 >> 7) & 7) << 4);
    const int d1 = z1 ^ (((z1 >> 7) & 7) << 4);
    const int d2 = z2 ^ (((z2 >> 7) & 7) << 4);
    const int d3 = z3 ^ (((z3 >> 7) & 7) << 4);

    v4f acc[2][4];
    #pragma unroll
    for (int s = 0; s < 2; ++s)
        #pragma unroll
        for (int c = 0; c < 4; ++c)
            acc[s][c] = (v4f){0.f, 0.f, 0.f, 0.f};

    // prologue: stage W[0] into buf 0
    {
        const char* ghb = (const char*)Wthi;
        const char* glb = (const char*)Wtlo;
        v8s w0 = *(const v8s*)(z0 < 8192 ? ghb + z0 : glb + (z0 - 8192));
        v8s w1 = *(const v8s*)(z1 < 8192 ? ghb + z1 : glb + (z1 - 8192));
        v8s w2 = *(const v8s*)(z2 < 8192 ? ghb + z2 : glb + (z2 - 8192));
        v8s w3 = *(const v8s*)(z3 < 8192 ? ghb + z3 : glb + (z3 - 8192));
        char* lb = (char*)&Wlds[0][0];
        *(v8s*)(lb + d0) = w0; *(v8s*)(lb + d1) = w1;
        *(v8s*)(lb + d2) = w2; *(v8s*)(lb + d3) = w3;
    }
    __syncthreads();

    #pragma unroll 1
    for (int k = 0; k < 27; ++k) {
        const int cb = k & 1;
        const bool st = (k + 1 < 27);
        v8s w0, w1, w2, w3;
        if (st) {   // issue next-k W loads early; latency hides under this k's compute
            const char* ghb = (const char*)(Wthi + (size_t)(k + 1) * 4096);
            const char* glb = (const char*)(Wtlo + (size_t)(k + 1) * 4096);
            w0 = *(const v8s*)(z0 < 8192 ? ghb + z0 : glb + (z0 - 8192));
            w1 = *(const v8s*)(z1 < 8192 ? ghb + z1 : glb + (z1 - 8192));
            w2 = *(const v8s*)(z2 < 8192 ? ghb + z2 : glb + (z2 - 8192));
            w3 = *(const v8s*)(z3 < 8192 ? ghb + z3 : glb + (z3 - 8192));
        }
        // X gathers for this k
        int j0 = nbr[o0g + k];
        int j1 = nbr[o1g + k];
        const unsigned short* x0h = Xhi + (size_t)j0 * 64 + qo;
        const unsigned short* x0l = Xlo + (size_t)j0 * 64 + qo;
        const unsigned short* x1h = Xhi + (size_t)j1 * 64 + qo;
        const unsigned short* x1l = Xlo + (size_t)j1 * 64 + qo;
        v8s a0h0 = *(const v8s*)(x0h);
        v8s a0h1 = *(const v8s*)(x0h + 32);
        v8s a0l0 = *(const v8s*)(x0l);
        v8s a0l1 = *(const v8s*)(x0l + 32);
        v8s a1h0 = *(const v8s*)(x1h);
        v8s a1h1 = *(const v8s*)(x1h + 32);
        v8s a1l0 = *(const v8s*)(x1l);
        v8s a1l1 = *(const v8s*)(x1l + 32);
        // B fragments from LDS buf cb (swizzled reads)
        const char* wb = (const char*)&Wlds[cb][0];
        const int sw = (m & 7) << 4;
        #pragma unroll
        for (int ct = 0; ct < 4; ++ct) {
            const int rowoff = (ct * 16 + m) * 128;
            v8s bh0 = *(const v8s*)(wb + rowoff + ((q * 16) ^ sw));
            v8s bh1 = *(const v8s*)(wb + rowoff + ((q * 16 + 64) ^ sw));
            v8s bl0 = *(const v8s*)(wb + 8192 + rowoff + ((q * 16) ^ sw));
            v8s bl1 = *(const v8s*)(wb + 8192 + rowoff + ((q * 16 + 64) ^ sw));
            acc[0][ct] = MFMA16(a0h0, bh0, acc[0][ct], 0, 0, 0);
            acc[0][ct] = MFMA16(a0h1, bh1, acc[0][ct], 0, 0, 0);
            acc[0][ct] = MFMA16(a0l0, bh0, acc[0][ct], 0, 0, 0);
            acc[0][ct] = MFMA16(a0l1, bh1, acc[0][ct], 0, 0, 0);
            acc[0][ct] = MFMA16(a0h0, bl0, acc[0][ct], 0, 0, 0);
            acc[0][ct] = MFMA16(a0h1, bl1, acc[0][ct], 0, 0, 0);
            acc[1][ct] = MFMA16(a1h0, bh0, acc[1][ct], 0, 0, 0);
            acc[1][ct] = MFMA16(a1h1, bh1, acc[1][ct], 0, 0, 0);
            acc[1][ct] = MFMA16(a1l0, bh0, acc[1][ct], 0, 0, 0);
            acc[1][ct] = MFMA16(a1l1, bh1, acc[1][ct], 0, 0, 0);
            acc[1][ct] = MFMA16(a1h0, bl0, acc[1][ct], 0, 0, 0);
            acc[1][ct] = MFMA16(a1h1, bl1, acc[1][ct], 0, 0, 0);
        }
        if (st) {   // write next-k W into the other buffer (loads completed during compute)
            char* lb = (char*)&Wlds[1 - cb][0];
            *(v8s*)(lb + d0) = w0; *(v8s*)(lb + d1) = w1;
            *(v8s*)(lb + d2) = w2; *(v8s*)(lb + d3) = w3;
        }
        __syncthreads();   // drains ds_writes; protects both buffers across iterations
    }

    // C/D layout: col = lane&15, row(within 16) = q*4 + reg
    #pragma unroll
    for (int s = 0; s < 2; ++s)
        #pragma unroll
        for (int ct = 0; ct < 4; ++ct)
            #pragma unroll
            for (int rg = 0; rg < 4; ++rg) {
                long r = base + s * 16 + q * 4 + rg;
                if (r < N) Y[r * 64 + ct * 16 + m] = acc[s][ct][rg];
            }
}

// ---------------- per-column sum / sumsq ----------------
template<int CC>
__global__ __launch_bounds__(256) void colstats_kernel(const float* __restrict__ Y, int N, float* __restrict__ stats) {
    constexpr int RG = 256 / CC;
    const int t = threadIdx.x;
    const int c = t % CC, rg = t / CC;
    float s = 0.f, s2 = 0.f;
    for (long r = (long)blockIdx.x * RG + rg; r < N; r += (long)gridDim.x * RG) {
        float v = Y[r * CC + c];
        s += v; s2 += v * v;
    }
    __shared__ float sh[256], sh2[256];
    sh[t] = s; sh2[t] = s2;
    __syncthreads();
    if (t < CC) {
        #pragma unroll
        for (int g = 1; g < RG; ++g) { s += sh[g * CC + t]; s2 += sh2[g * CC + t]; }
        atomicAdd(&stats[t], s);
        atomicAdd(&stats[CC + t], s2);
    }
}

__global__ void mkscale_kernel(float* __restrict__ stats, const float* __restrict__ g,
                               const float* __restrict__ b, float invN, int CC) {
    int c = threadIdx.x;
    if (c < CC) {
        float mu = stats[c] * invN;
        float var = stats[CC + c] * invN - mu * mu;
        float sc = g[c] * rsqrtf(var + 1e-5f);
        stats[2 * CC + c] = sc;
        stats[3 * CC + c] = b[c] - mu * sc;
    }
}

// MODE: 0 = y*s+sh ; 1 = leaky(y*s+sh) ; 2 = leaky(y*s+sh + res) ; 3 = res2 + leaky(y*s+sh + res)
// PAIR: also emit bf16 hi/lo split of the result (next conv's input)
template<int CC, int MODE, int PAIR>
__global__ __launch_bounds__(256) void apply_bn_kernel(
    const float* __restrict__ Yin, const float* __restrict__ stats,
    const float* __restrict__ res, const float* __restrict__ res2,
    float* __restrict__ out, unsigned short* __restrict__ ohi,
    unsigned short* __restrict__ olo, long n4)
{
    long i = (long)blockIdx.x * 256 + threadIdx.x;
    if (i >= n4) return;
    int c4 = (int)(i % (CC / 4)) * 4;
    float4 y = ((const float4*)Yin)[i];
    float4 sc = *(const float4*)(stats + 2 * CC + c4);
    float4 sf = *(const float4*)(stats + 3 * CC + c4);
    float x0 = y.x * sc.x + sf.x;
    float x1 = y.y * sc.y + sf.y;
    float x2 = y.z * sc.z + sf.z;
    float x3 = y.w * sc.w + sf.w;
    if (MODE >= 2) {
        float4 rr = ((const float4*)res)[i];
        x0 += rr.x; x1 += rr.y; x2 += rr.z; x3 += rr.w;
    }
    if (MODE >= 1) { x0 = lk(x0); x1 = lk(x1); x2 = lk(x2); x3 = lk(x3); }
    if (MODE == 3) {
        float4 rr2 = ((const float4*)res2)[i];
        x0 += rr2.x; x1 += rr2.y; x2 += rr2.z; x3 += rr2.w;
    }
    ((float4*)out)[i] = make_float4(x0, x1, x2, x3);
    if (PAIR) {
        ushort4 h, l;
        h.x = f2bf(x0); l.x = f2bf(x0 - bf2f(h.x));
        h.y = f2bf(x1); l.y = f2bf(x1 - bf2f(h.y));
        h.z = f2bf(x2); l.z = f2bf(x2 - bf2f(h.z));
        h.w = f2bf(x3); l.w = f2bf(x3 - bf2f(h.w));
        *(ushort4*)(ohi + i * 4) = h;
        *(ushort4*)(olo + i * 4) = l;
    }
}

// ---------------- generic tiled GEMM: Y = act(X[N,CIN] @ W[CIN,COUT] + bias) ----------------
template<int CIN, int COUT, int ACT>
__global__ __launch_bounds__(256) void gemm_kernel(
    const float* __restrict__ X, const float* __restrict__ W,
    const float* __restrict__ bias, float* __restrict__ Y, int N)
{
    constexpr int TX = COUT / 4;
    constexpr int TY = 256 / TX;
    constexpr int ROWS = TY * 4;
    constexpr int CHUNK = (CIN < 64) ? CIN : 64;
    constexpr int NCH = CIN / CHUNK;
    __shared__ float XsT[CHUNK][ROWS + 4];
    __shared__ float Ws[CHUNK][COUT + 4];
    const int t = threadIdx.x;
    const int row0 = blockIdx.x * ROWS;
    const int ty = t / TX, tx = t % TX;
    float acc[4][4] = {{0.f}};
    for (int cc = 0; cc < NCH; ++cc) {
        __syncthreads();
        for (int i = t * 4; i < CHUNK * COUT; i += 1024) {
            int c = i / COUT, d = i % COUT;
            *(float4*)&Ws[c][d] = *(const float4*)(W + (size_t)(cc * CHUNK + c) * COUT + d);
        }
        for (int i = t * 4; i < ROWS * CHUNK; i += 1024) {
            int r = i / CHUNK, c0 = i % CHUNK;
            int gr = row0 + r;
            float4 v = make_float4(0.f, 0.f, 0.f, 0.f);
            if (gr < N) v = *(const float4*)(X + (size_t)gr * CIN + cc * CHUNK + c0);
            XsT[c0 + 0][r] = v.x; XsT[c0 + 1][r] = v.y; XsT[c0 + 2][r] = v.z; XsT[c0 + 3][r] = v.w;
        }
        __syncthreads();
        #pragma unroll 8
        for (int c = 0; c < CHUNK; ++c) {
            float4 xv = *(const float4*)&XsT[c][ty * 4];
            float4 wv = *(const float4*)&Ws[c][tx * 4];
            acc[0][0] += xv.x * wv.x; acc[0][1] += xv.x * wv.y; acc[0][2] += xv.x * wv.z; acc[0][3] += xv.x * wv.w;
            acc[1][0] += xv.y * wv.x; acc[1][1] += xv.y * wv.y; acc[1][2] += xv.y * wv.z; acc[1][3] += xv.y * wv.w;
            acc[2][0] += xv.z * wv.x; acc[2][1] += xv.z * wv.y; acc[2][2] += xv.z * wv.z; acc[2][3] += xv.z * wv.w;
            acc[3][0] += xv.w * wv.x; acc[3][1] += xv.w * wv.y; acc[3][2] += xv.w * wv.z; acc[3][3] += xv.w * wv.w;
        }
    }
    float4 bv = *(const float4*)(bias + tx * 4);
    #pragma unroll
    for (int i2 = 0; i2 < 4; ++i2) {
        int gr = row0 + ty * 4 + i2;
        if (gr < N) {
            float o0 = acc[i2][0] + bv.x, o1 = acc[i2][1] + bv.y;
            float o2 = acc[i2][2] + bv.z, o3 = acc[i2][3] + bv.w;
            if (ACT) { o0 = lk(o0); o1 = lk(o1); o2 = lk(o2); o3 = lk(o3); }
            *(float4*)(Y + (size_t)gr * COUT + tx * 4) = make_float4(o0, o1, o2, o3);
        }
    }
}

// ---------------- fused layer_out + scatter-add (fp32) ----------------
__global__ __launch_bounds__(256) void layer_out_fused_kernel(
    const float* __restrict__ iden, const float* __restrict__ h3,
    const int* __restrict__ cil, const int* __restrict__ dsinv,
    const float* __restrict__ Wo1, const float* __restrict__ bo1,
    const float* __restrict__ Wo2, const float* __restrict__ bo2,
    const int* __restrict__ cin,
    float* __restrict__ psum, float* __restrict__ pcnt, int N)
{
    __shared__ float XsT[64][68];
    __shared__ float Ws[64][68];
    const int t = threadIdx.x;
    const int row0 = blockIdx.x * 64;
    const int ty = t >> 4, tx = t & 15;
    const int lr = t >> 2, ls = t & 3;
    const int gr = row0 + lr;
    int v = (gr < N) ? cil[gr] : 0;
    int vds = dsinv[v];
    float acc[4][4] = {{0.f}};
    for (int cc = 0; cc < 2; ++cc) {
        const float* src = (cc == 0) ? (iden + (size_t)v * 64) : (h3 + (size_t)vds * 64);
        const float* xr = src + ls * 16;
        float4 v0 = *(const float4*)(xr);
        float4 v1 = *(const float4*)(xr + 4);
        float4 v2f = *(const float4*)(xr + 8);
        float4 v3 = *(const float4*)(xr + 12);
        const float* Wk = Wo1 + (size_t)cc * 4096;
        float4 w0 = *(const float4*)(Wk + t * 4);
        float4 w1 = *(const float4*)(Wk + t * 4 + 1024);
        float4 w2 = *(const float4*)(Wk + t * 4 + 2048);
        float4 w3 = *(const float4*)(Wk + t * 4 + 3072);
        __syncthreads();
        {
            int i0 = t * 4;
            *(float4*)&Ws[i0 >> 6][i0 & 63] = w0; i0 += 1024;
            *(float4*)&Ws[i0 >> 6][i0 & 63] = w1; i0 += 1024;
            *(float4*)&Ws[i0 >> 6][i0 & 63] = w2; i0 += 1024;
            *(float4*)&Ws[i0 >> 6][i0 & 63] = w3;
        }
        const int cb = ls * 16;
        XsT[cb + 0][lr] = v0.x; XsT[cb + 1][lr] = v0.y; XsT[cb + 2][lr] = v0.z; XsT[cb + 3][lr] = v0.w;
        XsT[cb + 4][lr] = v1.x; XsT[cb + 5][lr] = v1.y; XsT[cb + 6][lr] = v1.z; XsT[cb + 7][lr] = v1.w;
        XsT[cb + 8][lr] = v2f.x; XsT[cb + 9][lr] = v2f.y; XsT[cb + 10][lr] = v2f.z; XsT[cb + 11][lr] = v2f.w;
        XsT[cb + 12][lr] = v3.x; XsT[cb + 13][lr] = v3.y; XsT[cb + 14][lr] = v3.z; XsT[cb + 15][lr] = v3.w;
        __syncthreads();
        #pragma unroll 16
        for (int c = 0; c < 64; ++c) {
            float4 xv = *(const float4*)&XsT[c][ty * 4];
            float4 wv = *(const float4*)&Ws[c][tx * 4];
            acc[0][0] += xv.x * wv.x; acc[0][1] += xv.x * wv.y; acc[0][2] += xv.x * wv.z; acc[0][3] += xv.x * wv.w;
            acc[1][0] += xv.y * wv.x; acc[1][1] += xv.y * wv.y; acc[1][2] += xv.y * wv.z; acc[1][3] += xv.y * wv.w;
            acc[2][0] += xv.z * wv.x; acc[2][1] += xv.z * wv.y; acc[2][2] += xv.z * wv.z; acc[2][3] += xv.z * wv.w;
            acc[3][0] += xv.w * wv.x; acc[3][1] += xv.w * wv.y; acc[3][2] += xv.w * wv.z; acc[3][3] += xv.w * wv.w;
        }
    }
    float4 u0 = *(const float4*)(Wo2 + t * 4);
    float4 u1 = *(const float4*)(Wo2 + t * 4 + 1024);
    float4 u2 = *(const float4*)(Wo2 + t * 4 + 2048);
    float4 u3 = *(const float4*)(Wo2 + t * 4 + 3072);
    float4 b1v = *(const float4*)(bo1 + tx * 4);
    __syncthreads();
    {
        int i0 = t * 4;
        *(float4*)&Ws[i0 >> 6][i0 & 63] = u0; i0 += 1024;
        *(float4*)&Ws[i0 >> 6][i0 & 63] = u1; i0 += 1024;
        *(float4*)&Ws[i0 >> 6][i0 & 63] = u2; i0 += 1024;
        *(float4*)&Ws[i0 >> 6][i0 & 63] = u3;
    }
    #pragma unroll
    for (int i = 0; i < 4; ++i) {
        XsT[tx * 4 + 0][ty * 4 + i] = lk(acc[i][0] + b1v.x);
        XsT[tx * 4 + 1][ty * 4 + i] = lk(acc[i][1] + b1v.y);
        XsT[tx * 4 + 2][ty * 4 + i] = lk(acc[i][2] + b1v.z);
        XsT[tx * 4 + 3][ty * 4 + i] = lk(acc[i][3] + b1v.w);
    }
    __syncthreads();
    float acc2[4][4] = {{0.f}};
    #pragma unroll 16
    for (int c = 0; c < 64; ++c) {
        float4 xv = *(const float4*)&XsT[c][ty * 4];
        float4 wv = *(const float4*)&Ws[c][tx * 4];
        acc2[0][0] += xv.x * wv.x; acc2[0][1] += xv.x * wv.y; acc2[0][2] += xv.x * wv.z; acc2[0][3] += xv.x * wv.w;
        acc2[1][0] += xv.y * wv.x; acc2[1][1] += xv.y * wv.y; acc2[1][2] += xv.y * wv.z; acc2[1][3] += xv.y * wv.w;
        acc2[2][0] += xv.z * wv.x; acc2[2][1] += xv.z * wv.y; acc2[2][2] += xv.z * wv.z; acc2[2][3] += xv.z * wv.w;
        acc2[3][0] += xv.w * wv.x; acc2[3][1] += xv.w * wv.y; acc2[3][2] += xv.w * wv.z; acc2[3][3] += xv.w * wv.w;
    }
    float4 b2v = *(const float4*)(bo2 + tx * 4);
    #pragma unroll
    for (int i2 = 0; i2 < 4; ++i2) {
        int gr2 = row0 + ty * 4 + i2;
        if (gr2 < N) {
            int tg = cin[gr2];
            float* dst = psum + (size_t)tg * 64 + tx * 4;
            atomicAdd(dst + 0, acc2[i2][0] + b2v.x);
            atomicAdd(dst + 1, acc2[i2][1] + b2v.y);
            atomicAdd(dst + 2, acc2[i2][2] + b2v.z);
            atomicAdd(dst + 3, acc2[i2][3] + b2v.w);
            if (tx == 0) atomicAdd(pcnt + tg, 1.0f);
        }
    }
}

// ---------------- scatter add (segment sum) ----------------
__global__ void scatter_add_kernel(const float* __restrict__ X, const int* __restrict__ idx,
                                   float* __restrict__ sum, float* __restrict__ cnt, long N) {
    long i = (long)blockIdx.x * 256 + threadIdx.x;
    if (i < N * 64) {
        long n = i >> 6; int c = (int)(i & 63);
        int tg = idx[n];
        atomicAdd(&sum[(size_t)tg * 64 + c], X[i]);
        if (c == 0) atomicAdd(&cnt[tg], 1.0f);
    }
}

__global__ void divcnt_kernel(float* __restrict__ sum, const float* __restrict__ cnt, long total) {
    long i = (long)blockIdx.x * 256 + threadIdx.x;
    if (i < total) sum[i] /= fmaxf(cnt[i >> 6], 1.0f);
}

__global__ void gather_out_kernel(const float* __restrict__ pf, const int* __restrict__ cin,
                                  float* __restrict__ out, int N) {
    long i = (long)blockIdx.x * 256 + threadIdx.x;
    if (i < (long)N * 16) {
        int p = (int)(i >> 4), q = (int)(i & 15);
        ((float4*)out)[i] = *(const float4*)(pf + (size_t)cin[p] * 64 + q * 4);
    }
}

// ---------------- logit conv: 1 wave per row, lane = channel ----------------
__global__ __launch_bounds__(256) void logit_kernel(
    const float* __restrict__ vp, const int* __restrict__ nbrp,
    const float* __restrict__ Wlog, const float* __restrict__ blog,
    float* __restrict__ out, int N)
{
    __shared__ float Wl[27 * 64];
    const int t = threadIdx.x;
    for (int i = t; i < 1728; i += 256) Wl[i] = Wlog[i];
    __syncthreads();
    const int wave = t >> 6, lane = t & 63;
    for (long row = (long)blockIdx.x * 4 + wave; row < N; row += (long)gridDim.x * 4) {
        float acc = 0.f;
        #pragma unroll
        for (int k = 0; k < 27; ++k) {
            int j = nbrp[row * 27 + k];
            acc += vp[(size_t)j * 64 + lane] * Wl[k * 64 + lane];
        }
        for (int off = 32; off > 0; off >>= 1) acc += __shfl_down(acc, off, 64);
        if (lane == 0) out[row] = acc + blog[0];
    }
}

// ---------------- loss ----------------
__global__ void loss_scatter1_kernel(const int* __restrict__ coors, int* __restrict__ tflag,
                                     int* __restrict__ winner, int N, int NP) {
    int n = blockIdx.x * 256 + threadIdx.x;
    if (n < N) {
        int b = coors[n * 4], x = coors[n * 4 + 1], y = coors[n * 4 + 2], z = coors[n * 4 + 3];
        int flat = ((b * 240 + x) * 180 + y) * 16 + z;
        tflag[flat] = 1;
        if (n < NP) atomicMax(&winner[flat], n);
    }
}

__global__ void loss_scatter2_kernel(const int* __restrict__ coors, const int* __restrict__ winner,
                                     const float* __restrict__ logit, float* __restrict__ xdense, int NP) {
    int n = blockIdx.x * 256 + threadIdx.x;
    if (n < NP) {
        int b = coors[n * 4], x = coors[n * 4 + 1], y = coors[n * 4 + 2], z = coors[n * 4 + 3];
        int flat = ((b * 240 + x) * 180 + y) * 16 + z;
        if (winner[flat] == n) xdense[flat] = logit[n];
    }
}

__global__ void loss_reduce_kernel(const float* __restrict__ xdense, const int* __restrict__ tflag,
                                   float* __restrict__ accum) {
    int i = blockIdx.x * 256 + threadIdx.x;
    float x = xdense[i];
    float tt = (float)tflag[i];
    float term = fmaxf(x, 0.f) - x * tt + log1pf(expf(-fabsf(x)));
    __shared__ float sh[256];
    sh[threadIdx.x] = term;
    __syncthreads();
    for (int s = 128; s > 0; s >>= 1) {
        if (threadIdx.x < s) sh[threadIdx.x] += sh[threadIdx.x + s];
        __syncthreads();
    }
    if (threadIdx.x == 0) atomicAdd(accum, sh[0]);
}

__global__ void loss_final_kernel(const float* __restrict__ accum, float* __restrict__ out) {
    out[0] = accum[0] / (float)NCELL;
}

// ---------------- host orchestration ----------------
extern "C" void kernel_launch(void* const* d_in, const int* in_sizes, int n_in,
                              void* d_out, int out_size, void* d_ws, size_t ws_size,
                              hipStream_t stream)
{
    const float* feats  = (const float*)d_in[0];
    const float* featsp = (const float*)d_in[1];
    const float* Wv11 = (const float*)d_in[2];
    const float* Wv12 = (const float*)d_in[3];
    const float* Wv21 = (const float*)d_in[4];
    const float* Wv22 = (const float*)d_in[5];
    const float* g11 = (const float*)d_in[6];
    const float* g12 = (const float*)d_in[7];
    const float* g21 = (const float*)d_in[8];
    const float* g22 = (const float*)d_in[9];
    const float* b11 = (const float*)d_in[10];
    const float* b12 = (const float*)d_in[11];
    const float* b21 = (const float*)d_in[12];
    const float* b22 = (const float*)d_in[13];
    const float* Wlog = (const float*)d_in[14];
    const float* blog = (const float*)d_in[15];
    const float* Wi  = (const float*)d_in[16];
    const float* bi  = (const float*)d_in[17];
    const float* Wp1 = (const float*)d_in[18];
    const float* bp1 = (const float*)d_in[19];
    const float* gp1 = (const float*)d_in[20];
    const float* bp1n = (const float*)d_in[21];
    const float* Wp2 = (const float*)d_in[22];
    const float* bp2 = (const float*)d_in[23];
    const float* gp2 = (const float*)d_in[24];
    const float* bp2n = (const float*)d_in[25];
    const float* Wp3 = (const float*)d_in[26];
    const float* bp3 = (const float*)d_in[27];
    const float* Wo1 = (const float*)d_in[28];
    const float* bo1 = (const float*)d_in[29];
    const float* Wo2 = (const float*)d_in[30];
    const float* bo2 = (const float*)d_in[31];
    const int* nbr   = (const int*)d_in[32];
    const int* nbrp  = (const int*)d_in[33];
    const int* coors = (const int*)d_in[34];
    const int* cil   = (const int*)d_in[35];
    const int* cin   = (const int*)d_in[36];
    const int* dsinv = (const int*)d_in[37];
    (void)in_sizes; (void)n_in; (void)out_size; (void)ws_size;

    // ---- ws layout (46,952,561 floats ~= 187.8 MB; round 2 proved >=192 MB available) ----
    float* ws = (float*)d_ws;
    float* A     = ws;                  // 16M : conv fp32 out (full & partial) -> identity
    float* H     = ws + 16000000L;      // 16M : X1 fp32 -> feat_sum
    float* Hpf32 = ws + 32000000L;      //  8M : partial X1 residual
    float* psum  = ws + 40000000L;      //  6.4M
    float* pcnt  = ws + 46400000L;      //  0.1M
    unsigned short* wt = (unsigned short*)(ws + 46500000L);  // 8 x 110592 bf16 (442,368 floats)
    float* stats = ws + 46950000L;      //  10 x 256
    float* lacc  = ws + 46952560L;      //  1
    unsigned short* wh11 = wt + 0L * 110592;
    unsigned short* wl11 = wt + 1L * 110592;
    unsigned short* wh12 = wt + 2L * 110592;
    unsigned short* wl12 = wt + 3L * 110592;
    unsigned short* wh21 = wt + 4L * 110592;
    unsigned short* wl21 = wt + 5L * 110592;
    unsigned short* wh22 = wt + 6L * 110592;
    unsigned short* wl22 = wt + 7L * 110592;

    // ---- d_out as scratch (38.4M floats, fully overwritten by final gather) ----
    float* o = (float*)d_out;
    // conv-phase: full-tensor bf16 pairs
    unsigned short* F0h = (unsigned short*)(o);               // 16M bf16
    unsigned short* F0l = (unsigned short*)(o + 8000000L);
    unsigned short* F1h = (unsigned short*)(o + 16000000L);
    unsigned short* F1l = (unsigned short*)(o + 24000000L);
    // partial-phase pairs (after full convs done)
    unsigned short* P0h = (unsigned short*)(o);
    unsigned short* P0l = (unsigned short*)(o + 4000000L);
    unsigned short* P1h = (unsigned short*)(o + 8000000L);
    unsigned short* P1l = (unsigned short*)(o + 12000000L);
    float* Cp = o + 16000000L;          // 8M : Vp fp32 (logit input)
    // loss region (disjoint from pairs)
    float* xdense = o + 32000000L;      // 1.3824M
    int*   tflag  = (int*)(o + 33382400L);
    int*   winner = (int*)(o + 34764800L);
    float* logitb = o + 36147200L;      // 125k
    float* dscnt  = o + 36272200L;      // 100k
    // post-conv phase (pairs dead)
    float* dssum = o;                   // 6.4M
    float* t1b   = o + 6400000L;        // 3.2M
    float* t2b   = o + 9600000L;        // 3.2M
    float* h3b   = o + 12800000L;       // 6.4M (overlaps dead Cp tail: used only after logit)
    float* out = (float*)d_out;

    auto cdiv = [](long a, long b) { return (unsigned)((a + b - 1) / b); };
    dim3 B256(256);

    // ---- inits ----
    fill_u32_kernel<<<cdiv(2561, 256), B256, 0, stream>>>((unsigned*)stats, 0u, 2561);
    fill_u32_kernel<<<cdiv(6500000, 256), B256, 0, stream>>>((unsigned*)psum, 0u, 6500000);
    fill_u32_kernel<<<cdiv(2764800, 256), B256, 0, stream>>>((unsigned*)xdense, 0u, 2764800);   // xdense+tflag
    fill_u32_kernel<<<cdiv(1382400, 256), B256, 0, stream>>>((unsigned*)winner, 0xFFFFFFFFu, 1382400);

    // ---- weight transpose + split ----
    wsplit_kernel<<<432, B256, 0, stream>>>(Wv11, wh11, wl11);
    wsplit_kernel<<<432, B256, 0, stream>>>(Wv12, wh12, wl12);
    wsplit_kernel<<<432, B256, 0, stream>>>(Wv21, wh21, wl21);
    wsplit_kernel<<<432, B256, 0, stream>>>(Wv22, wh22, wl22);

    // ---- full tensor chain ----
    xsplit_kernel<<<cdiv(16000000, 256), B256, 0, stream>>>(feats, F0h, F0l, 16000000L);
    // s0: conv1(F0) -> A ; bn leaky -> A(inplace) + F1
    conv_mfma_kernel<<<cdiv(NVOX, 128), B256, 0, stream>>>(F0h, F0l, nbr, wh11, wl11, A, NVOX);
    colstats_kernel<64><<<256, B256, 0, stream>>>(A, NVOX, stats + 0 * 256);
    mkscale_kernel<<<1, 64, 0, stream>>>(stats + 0 * 256, g11, b11, 1.0f / NVOX, 64);
    apply_bn_kernel<64, 1, 1><<<cdiv(NVOX * 16L, 256), B256, 0, stream>>>(A, stats + 0 * 256, nullptr, nullptr, A, F1h, F1l, NVOX * 16L);
    // s1: conv2(F1) -> A ; bn + res(feats) leaky -> H(=X1) + F0
    conv_mfma_kernel<<<cdiv(NVOX, 128), B256, 0, stream>>>(F1h, F1l, nbr, wh12, wl12, A, NVOX);
    colstats_kernel<64><<<256, B256, 0, stream>>>(A, NVOX, stats + 1 * 256);
    mkscale_kernel<<<1, 64, 0, stream>>>(stats + 1 * 256, g12, b12, 1.0f / NVOX, 64);
    apply_bn_kernel<64, 2, 1><<<cdiv(NVOX * 16L, 256), B256, 0, stream>>>(A, stats + 1 * 256, feats, nullptr, H, F0h, F0l, NVOX * 16L);
    // s2: conv3(F0) -> A ; bn leaky -> A + F1
    conv_mfma_kernel<<<cdiv(NVOX, 128), B256, 0, stream>>>(F0h, F0l, nbr, wh21, wl21, A, NVOX);
    colstats_kernel<64><<<256, B256, 0, stream>>>(A, NVOX, stats + 2 * 256);
    mkscale_kernel<<<1, 64, 0, stream>>>(stats + 2 * 256, g21, b21, 1.0f / NVOX, 64);
    apply_bn_kernel<64, 1, 1><<<cdiv(NVOX * 16L, 256), B256, 0, stream>>>(A, stats + 2 * 256, nullptr, nullptr, A, F1h, F1l, NVOX * 16L);
    // s3: conv4(F1) -> A ; bn + res(X1=H) leaky + feats -> H(=feat_sum)
    conv_mfma_kernel<<<cdiv(NVOX, 128), B256, 0, stream>>>(F1h, F1l, nbr, wh22, wl22, A, NVOX);
    colstats_kernel<64><<<256, B256, 0, stream>>>(A, NVOX, stats + 3 * 256);
    mkscale_kernel<<<1, 64, 0, stream>>>(stats + 3 * 256, g22, b22, 1.0f / NVOX, 64);
    apply_bn_kernel<64, 3, 0><<<cdiv(NVOX * 16L, 256), B256, 0, stream>>>(A, stats + 3 * 256, H, feats, H, nullptr, nullptr, NVOX * 16L);

    // ---- partial tensor chain (same weights) ----
    xsplit_kernel<<<cdiv(8000000, 256), B256, 0, stream>>>(featsp, P0h, P0l, 8000000L);
    conv_mfma_kernel<<<cdiv(NPART, 128), B256, 0, stream>>>(P0h, P0l, nbrp, wh11, wl11, A, NPART);
    colstats_kernel<64><<<256, B256, 0, stream>>>(A, NPART, stats + 4 * 256);
    mkscale_kernel<<<1, 64, 0, stream>>>(stats + 4 * 256, g11, b11, 1.0f / NPART, 64);
    apply_bn_kernel<64, 1, 1><<<cdiv(NPART * 16L, 256), B256, 0, stream>>>(A, stats + 4 * 256, nullptr, nullptr, A, P1h, P1l, NPART * 16L);
    conv_mfma_kernel<<<cdiv(NPART, 128), B256, 0, stream>>>(P1h, P1l, nbrp, wh12, wl12, A, NPART);
    colstats_kernel<64><<<256, B256, 0, stream>>>(A, NPART, stats + 5 * 256);
    mkscale_kernel<<<1, 64, 0, stream>>>(stats + 5 * 256, g12, b12, 1.0f / NPART, 64);
    apply_bn_kernel<64, 2, 1><<<cdiv(NPART * 16L, 256), B256, 0, stream>>>(A, stats + 5 * 256, featsp, nullptr, Hpf32, P0h, P0l, NPART * 16L);
    conv_mfma_kernel<<<cdiv(NPART, 128), B256, 0, stream>>>(P0h, P0l, nbrp, wh21, wl21, A, NPART);
    colstats_kernel<64><<<256, B256, 0, stream>>>(A, NPART, stats + 6 * 256);
    mkscale_kernel<<<1, 64, 0, stream>>>(stats + 6 * 256, g21, b21, 1.0f / NPART, 64);
    apply_bn_kernel<64, 1, 1><<<cdiv(NPART * 16L, 256), B256, 0, stream>>>(A, stats + 6 * 256, nullptr, nullptr, A, P1h, P1l, NPART * 16L);
    conv_mfma_kernel<<<cdiv(NPART, 128), B256, 0, stream>>>(P1h, P1l, nbrp, wh22, wl22, A, NPART);
    colstats_kernel<64><<<256, B256, 0, stream>>>(A, NPART, stats + 7 * 256);
    mkscale_kernel<<<1, 64, 0, stream>>>(stats + 7 * 256, g22, b22, 1.0f / NPART, 64);
    apply_bn_kernel<64, 2, 0><<<cdiv(NPART * 16L, 256), B256, 0, stream>>>(A, stats + 7 * 256, Hpf32, nullptr, Cp, nullptr, nullptr, NPART * 16L);

    // ---- logits + BCE loss ----
    logit_kernel<<<cdiv(NPART, 4), B256, 0, stream>>>(Cp, nbrp, Wlog, blog, logitb, NPART);
    loss_scatter1_kernel<<<cdiv(NVOX, 256), B256, 0, stream>>>(coors, tflag, winner, NVOX, NPART);
    loss_scatter2_kernel<<<cdiv(NPART, 256), B256, 0, stream>>>(coors, winner, logitb, xdense, NPART);
    loss_reduce_kernel<<<NCELL / 256, B256, 0, stream>>>(xdense, tflag, lacc);

    // ---- point encoder (pairs dead; reuse o[0..19.2M)) ----
    fill_u32_kernel<<<cdiv(6400000, 256), B256, 0, stream>>>((unsigned*)dssum, 0u, 6400000);
    fill_u32_kernel<<<cdiv(100000, 256), B256, 0, stream>>>((unsigned*)dscnt, 0u, 100000);
    scatter_add_kernel<<<cdiv((long)NVOX * 64, 256), B256, 0, stream>>>(H, dsinv, dssum, dscnt, (long)NVOX);
    divcnt_kernel<<<cdiv((long)NDS * 64, 256), B256, 0, stream>>>(dssum, dscnt, (long)NDS * 64);
    gemm_kernel<64, 64, 1><<<cdiv(NVOX, 64), B256, 0, stream>>>(H, Wi, bi, A, NVOX);   // A = identity

    gemm_kernel<64, 32, 1><<<cdiv(NDS, 128), B256, 0, stream>>>(dssum, Wp1, bp1, t1b, NDS);
    colstats_kernel<32><<<256, B256, 0, stream>>>(t1b, NDS, stats + 8 * 256);
    mkscale_kernel<<<1, 64, 0, stream>>>(stats + 8 * 256, gp1, bp1n, 1.0f / NDS, 32);
    apply_bn_kernel<32, 0, 0><<<cdiv((long)NDS * 8, 256), B256, 0, stream>>>(t1b, stats + 8 * 256, nullptr, nullptr, t1b, nullptr, nullptr, (long)NDS * 8);

    gemm_kernel<32, 32, 1><<<cdiv(NDS, 128), B256, 0, stream>>>(t1b, Wp2, bp2, t2b, NDS);
    colstats_kernel<32><<<256, B256, 0, stream>>>(t2b, NDS, stats + 9 * 256);
    mkscale_kernel<<<1, 64, 0, stream>>>(stats + 9 * 256, gp2, bp2n, 1.0f / NDS, 32);
    apply_bn_kernel<32, 0, 0><<<cdiv((long)NDS * 8, 256), B256, 0, stream>>>(t2b, stats + 9 * 256, nullptr, nullptr, t2b, nullptr, nullptr, (long)NDS * 8);

    gemm_kernel<32, 64, 1><<<cdiv(NDS, 64), B256, 0, stream>>>(t2b, Wp3, bp3, h3b, NDS);

    // ---- fused layer_out + scatter-mean ----
    layer_out_fused_kernel<<<cdiv(NPTS, 64), B256, 0, stream>>>(A, h3b, cil, dsinv, Wo1, bo1, Wo2, bo2, cin, psum, pcnt, NPTS);
    divcnt_kernel<<<cdiv((long)NNEXT * 64, 256), B256, 0, stream>>>(psum, pcnt, (long)NNEXT * 64);

    // ---- final outputs ----
    gather_out_kernel<<<cdiv((long)NPTS * 16, 256), B256, 0, stream>>>(psum, cin, out, NPTS);
    loss_final_kernel<<<1, 1, 0, stream>>>(lacc, out + 38400000L);
}

// Round 6
// 3633.290 us; speedup vs baseline: 1.5213x; 1.0585x over previous
//
#include <hip/hip_runtime.h>
#include <math.h>

#define NVOX 250000
#define NPART 125000
#define NPTS 600000
#define NNEXT 100000
#define NDS 100000
#define NCELL 1382400

static __device__ __forceinline__ float lk(float x) { return x >= 0.f ? x : 0.1f * x; }

// bf16 helpers (RNE)
static __device__ __forceinline__ unsigned short f2bf(float f) {
    unsigned u = __float_as_uint(f);
    unsigned r = (u + 0x7FFFu + ((u >> 16) & 1u)) >> 16;
    return (unsigned short)r;
}
static __device__ __forceinline__ float bf2f(unsigned short h) {
    return __uint_as_float((unsigned)h << 16);
}

typedef short v8s __attribute__((ext_vector_type(8)));   // 8 bf16 = 4 VGPR
typedef float v4f __attribute__((ext_vector_type(4)));   // MFMA acc
#define MFMA16 __builtin_amdgcn_mfma_f32_16x16x32_bf16

// lob 3-region row addressing (regions are dead buffers at layer_out time; see host layout)
static __device__ __forceinline__ float* lob_row(float* r0, float* r1, float* r2, int row) {
    if (row < 200000) return r0 + (size_t)row * 64;
    if (row < 500000) return r1 + (size_t)(row - 200000) * 64;
    return r2 + (size_t)(row - 500000) * 64;
}

// ---------------- fill ----------------
__global__ void fill_u32_kernel(unsigned* __restrict__ p, unsigned v, long n) {
    long i = (long)blockIdx.x * 256 + threadIdx.x;
    if (i < n) p[i] = v;
}

// ---------------- weight transpose + hi/lo split: Wt[k][d][c] = split(W[k][c][d]) ----------------
__global__ void wsplit_kernel(const float* __restrict__ W, unsigned short* __restrict__ hi,
                              unsigned short* __restrict__ lo) {
    int i = blockIdx.x * 256 + threadIdx.x;     // over 27*4096
    if (i < 27 * 4096) {
        int k = i >> 12, rem = i & 4095, d = rem >> 6, c = rem & 63;
        float w = W[k * 4096 + c * 64 + d];
        unsigned short h = f2bf(w);
        hi[i] = h;
        lo[i] = f2bf(w - bf2f(h));
    }
}

// ---------------- activation hi/lo split ----------------
__global__ void xsplit_kernel(const float* __restrict__ X, unsigned short* __restrict__ hi,
                              unsigned short* __restrict__ lo, long n) {
    long i = (long)blockIdx.x * 256 + threadIdx.x;
    if (i < n) {
        float x = X[i];
        unsigned short h = f2bf(x);
        hi[i] = h;
        lo[i] = f2bf(x - bf2f(h));
    }
}

// ---------------- MFMA submanifold conv (v4: W staged in LDS, double-buffered) ----------------
// Proven round 4: 620 -> ~340 us (MSHR relief). Unchanged.
__global__ __launch_bounds__(256) void conv_mfma_kernel(
    const unsigned short* __restrict__ Xhi, const unsigned short* __restrict__ Xlo,
    const int* __restrict__ nbr,
    const unsigned short* __restrict__ Wthi, const unsigned short* __restrict__ Wtlo,
    float* __restrict__ Y, int N)
{
    __shared__ __align__(16) unsigned short Wlds[2][8192];   // 2 bufs x (hi 8KB | lo 8KB) = 32 KB

    const int t = threadIdx.x;
    const int wave = t >> 6, lane = t & 63;
    const int m = lane & 15, q = lane >> 4;
    const int qo = q * 8;
    const long base = (long)blockIdx.x * 128 + wave * 32;

    long r0 = base + m;        // rowsub 0 A-row
    long r1 = base + 16 + m;   // rowsub 1 A-row
    long r0c = r0 < N ? r0 : (long)(N - 1);
    long r1c = r1 < N ? r1 : (long)(N - 1);
    const long o0g = r0c * 27, o1g = r1c * 27;

    // staging geometry: thread covers 4 x 16B of the 16KB (hi|lo) tile, bijective over 256 threads
    const int zb = wave * 4096 + lane * 16;
    const int z0 = zb, z1 = zb + 1024, z2 = zb + 2048, z3 = zb + 3072;
    // XOR swizzle -> conflict-free ds_read_b128
    const int d0 = z0 ^ (((z0 >> 7) & 7) << 4);
    const int d1 = z1 ^ (((z1 >> 7) & 7) << 4);
    const int d2 = z2 ^ (((z2 >> 7) & 7) << 4);
    const int d3 = z3 ^ (((z3 >> 7) & 7) << 4);

    v4f acc[2][4];
    #pragma unroll
    for (int s = 0; s < 2; ++s)
        #pragma unroll
        for (int c = 0; c < 4; ++c)
            acc[s][c] = (v4f){0.f, 0.f, 0.f, 0.f};

    // prologue: stage W[0] into buf 0
    {
        const char* ghb = (const char*)Wthi;
        const char* glb = (const char*)Wtlo;
        v8s w0 = *(const v8s*)(z0 < 8192 ? ghb + z0 : glb + (z0 - 8192));
        v8s w1 = *(const v8s*)(z1 < 8192 ? ghb + z1 : glb + (z1 - 8192));
        v8s w2 = *(const v8s*)(z2 < 8192 ? ghb + z2 : glb + (z2 - 8192));
        v8s w3 = *(const v8s*)(z3 < 8192 ? ghb + z3 : glb + (z3 - 8192));
        char* lb = (char*)&Wlds[0][0];
        *(v8s*)(lb + d0) = w0; *(v8s*)(lb + d1) = w1;
        *(v8s*)(lb + d2) = w2; *(v8s*)(lb + d3) = w3;
    }
    __syncthreads();

    #pragma unroll 1
    for (int k = 0; k < 27; ++k) {
        const int cb = k & 1;
        const bool st = (k + 1 < 27);
        v8s w0, w1, w2, w3;
        if (st) {   // issue next-k W loads early; latency hides under this k's compute
            const char* ghb = (const char*)(Wthi + (size_t)(k + 1) * 4096);
            const char* glb = (const char*)(Wtlo + (size_t)(k + 1) * 4096);
            w0 = *(const v8s*)(z0 < 8192 ? ghb + z0 : glb + (z0 - 8192));
            w1 = *(const v8s*)(z1 < 8192 ? ghb + z1 : glb + (z1 - 8192));
            w2 = *(const v8s*)(z2 < 8192 ? ghb + z2 : glb + (z2 - 8192));
            w3 = *(const v8s*)(z3 < 8192 ? ghb + z3 : glb + (z3 - 8192));
        }
        // X gathers for this k
        int j0 = nbr[o0g + k];
        int j1 = nbr[o1g + k];
        const unsigned short* x0h = Xhi + (size_t)j0 * 64 + qo;
        const unsigned short* x0l = Xlo + (size_t)j0 * 64 + qo;
        const unsigned short* x1h = Xhi + (size_t)j1 * 64 + qo;
        const unsigned short* x1l = Xlo + (size_t)j1 * 64 + qo;
        v8s a0h0 = *(const v8s*)(x0h);
        v8s a0h1 = *(const v8s*)(x0h + 32);
        v8s a0l0 = *(const v8s*)(x0l);
        v8s a0l1 = *(const v8s*)(x0l + 32);
        v8s a1h0 = *(const v8s*)(x1h);
        v8s a1h1 = *(const v8s*)(x1h + 32);
        v8s a1l0 = *(const v8s*)(x1l);
        v8s a1l1 = *(const v8s*)(x1l + 32);
        // B fragments from LDS buf cb (swizzled reads)
        const char* wb = (const char*)&Wlds[cb][0];
        const int sw = (m & 7) << 4;
        #pragma unroll
        for (int ct = 0; ct < 4; ++ct) {
            const int rowoff = (ct * 16 + m) * 128;
            v8s bh0 = *(const v8s*)(wb + rowoff + ((q * 16) ^ sw));
            v8s bh1 = *(const v8s*)(wb + rowoff + ((q * 16 + 64) ^ sw));
            v8s bl0 = *(const v8s*)(wb + 8192 + rowoff + ((q * 16) ^ sw));
            v8s bl1 = *(const v8s*)(wb + 8192 + rowoff + ((q * 16 + 64) ^ sw));
            acc[0][ct] = MFMA16(a0h0, bh0, acc[0][ct], 0, 0, 0);
            acc[0][ct] = MFMA16(a0h1, bh1, acc[0][ct], 0, 0, 0);
            acc[0][ct] = MFMA16(a0l0, bh0, acc[0][ct], 0, 0, 0);
            acc[0][ct] = MFMA16(a0l1, bh1, acc[0][ct], 0, 0, 0);
            acc[0][ct] = MFMA16(a0h0, bl0, acc[0][ct], 0, 0, 0);
            acc[0][ct] = MFMA16(a0h1, bl1, acc[0][ct], 0, 0, 0);
            acc[1][ct] = MFMA16(a1h0, bh0, acc[1][ct], 0, 0, 0);
            acc[1][ct] = MFMA16(a1h1, bh1, acc[1][ct], 0, 0, 0);
            acc[1][ct] = MFMA16(a1l0, bh0, acc[1][ct], 0, 0, 0);
            acc[1][ct] = MFMA16(a1l1, bh1, acc[1][ct], 0, 0, 0);
            acc[1][ct] = MFMA16(a1h0, bl0, acc[1][ct], 0, 0, 0);
            acc[1][ct] = MFMA16(a1h1, bl1, acc[1][ct], 0, 0, 0);
        }
        if (st) {
            char* lb = (char*)&Wlds[1 - cb][0];
            *(v8s*)(lb + d0) = w0; *(v8s*)(lb + d1) = w1;
            *(v8s*)(lb + d2) = w2; *(v8s*)(lb + d3) = w3;
        }
        __syncthreads();
    }

    // C/D layout: col = lane&15, row(within 16) = q*4 + reg
    #pragma unroll
    for (int s = 0; s < 2; ++s)
        #pragma unroll
        for (int ct = 0; ct < 4; ++ct)
            #pragma unroll
            for (int rg = 0; rg < 4; ++rg) {
                long r = base + s * 16 + q * 4 + rg;
                if (r < N) Y[r * 64 + ct * 16 + m] = acc[s][ct][rg];
            }
}

// ---------------- per-column sum / sumsq ----------------
template<int CC>
__global__ __launch_bounds__(256) void colstats_kernel(const float* __restrict__ Y, int N, float* __restrict__ stats) {
    constexpr int RG = 256 / CC;
    const int t = threadIdx.x;
    const int c = t % CC, rg = t / CC;
    float s = 0.f, s2 = 0.f;
    for (long r = (long)blockIdx.x * RG + rg; r < N; r += (long)gridDim.x * RG) {
        float v = Y[r * CC + c];
        s += v; s2 += v * v;
    }
    __shared__ float sh[256], sh2[256];
    sh[t] = s; sh2[t] = s2;
    __syncthreads();
    if (t < CC) {
        #pragma unroll
        for (int g = 1; g < RG; ++g) { s += sh[g * CC + t]; s2 += sh2[g * CC + t]; }
        atomicAdd(&stats[t], s);
        atomicAdd(&stats[CC + t], s2);
    }
}

__global__ void mkscale_kernel(float* __restrict__ stats, const float* __restrict__ g,
                               const float* __restrict__ b, float invN, int CC) {
    int c = threadIdx.x;
    if (c < CC) {
        float mu = stats[c] * invN;
        float var = stats[CC + c] * invN - mu * mu;
        float sc = g[c] * rsqrtf(var + 1e-5f);
        stats[2 * CC + c] = sc;
        stats[3 * CC + c] = b[c] - mu * sc;
    }
}

// MODE: 0 = y*s+sh ; 1 = leaky(y*s+sh) ; 2 = leaky(y*s+sh + res) ; 3 = res2 + leaky(y*s+sh + res)
// PAIR: also emit bf16 hi/lo split of the result (next conv's input)
template<int CC, int MODE, int PAIR>
__global__ __launch_bounds__(256) void apply_bn_kernel(
    const float* __restrict__ Yin, const float* __restrict__ stats,
    const float* __restrict__ res, const float* __restrict__ res2,
    float* __restrict__ out, unsigned short* __restrict__ ohi,
    unsigned short* __restrict__ olo, long n4)
{
    long i = (long)blockIdx.x * 256 + threadIdx.x;
    if (i >= n4) return;
    int c4 = (int)(i % (CC / 4)) * 4;
    float4 y = ((const float4*)Yin)[i];
    float4 sc = *(const float4*)(stats + 2 * CC + c4);
    float4 sf = *(const float4*)(stats + 3 * CC + c4);
    float x0 = y.x * sc.x + sf.x;
    float x1 = y.y * sc.y + sf.y;
    float x2 = y.z * sc.z + sf.z;
    float x3 = y.w * sc.w + sf.w;
    if (MODE >= 2) {
        float4 rr = ((const float4*)res)[i];
        x0 += rr.x; x1 += rr.y; x2 += rr.z; x3 += rr.w;
    }
    if (MODE >= 1) { x0 = lk(x0); x1 = lk(x1); x2 = lk(x2); x3 = lk(x3); }
    if (MODE == 3) {
        float4 rr2 = ((const float4*)res2)[i];
        x0 += rr2.x; x1 += rr2.y; x2 += rr2.z; x3 += rr2.w;
    }
    ((float4*)out)[i] = make_float4(x0, x1, x2, x3);
    if (PAIR) {
        ushort4 h, l;
        h.x = f2bf(x0); l.x = f2bf(x0 - bf2f(h.x));
        h.y = f2bf(x1); l.y = f2bf(x1 - bf2f(h.y));
        h.z = f2bf(x2); l.z = f2bf(x2 - bf2f(h.z));
        h.w = f2bf(x3); l.w = f2bf(x3 - bf2f(h.w));
        *(ushort4*)(ohi + i * 4) = h;
        *(ushort4*)(olo + i * 4) = l;
    }
}

// ---------------- generic tiled GEMM: Y = act(X[N,CIN] @ W[CIN,COUT] + bias) ----------------
template<int CIN, int COUT, int ACT>
__global__ __launch_bounds__(256) void gemm_kernel(
    const float* __restrict__ X, const float* __restrict__ W,
    const float* __restrict__ bias, float* __restrict__ Y, int N)
{
    constexpr int TX = COUT / 4;
    constexpr int TY = 256 / TX;
    constexpr int ROWS = TY * 4;
    constexpr int CHUNK = (CIN < 64) ? CIN : 64;
    constexpr int NCH = CIN / CHUNK;
    __shared__ float XsT[CHUNK][ROWS + 4];
    __shared__ float Ws[CHUNK][COUT + 4];
    const int t = threadIdx.x;
    const int row0 = blockIdx.x * ROWS;
    const int ty = t / TX, tx = t % TX;
    float acc[4][4] = {{0.f}};
    for (int cc = 0; cc < NCH; ++cc) {
        __syncthreads();
        for (int i = t * 4; i < CHUNK * COUT; i += 1024) {
            int c = i / COUT, d = i % COUT;
            *(float4*)&Ws[c][d] = *(const float4*)(W + (size_t)(cc * CHUNK + c) * COUT + d);
        }
        for (int i = t * 4; i < ROWS * CHUNK; i += 1024) {
            int r = i / CHUNK, c0 = i % CHUNK;
            int gr = row0 + r;
            float4 v = make_float4(0.f, 0.f, 0.f, 0.f);
            if (gr < N) v = *(const float4*)(X + (size_t)gr * CIN + cc * CHUNK + c0);
            XsT[c0 + 0][r] = v.x; XsT[c0 + 1][r] = v.y; XsT[c0 + 2][r] = v.z; XsT[c0 + 3][r] = v.w;
        }
        __syncthreads();
        #pragma unroll 8
        for (int c = 0; c < CHUNK; ++c) {
            float4 xv = *(const float4*)&XsT[c][ty * 4];
            float4 wv = *(const float4*)&Ws[c][tx * 4];
            acc[0][0] += xv.x * wv.x; acc[0][1] += xv.x * wv.y; acc[0][2] += xv.x * wv.z; acc[0][3] += xv.x * wv.w;
            acc[1][0] += xv.y * wv.x; acc[1][1] += xv.y * wv.y; acc[1][2] += xv.y * wv.z; acc[1][3] += xv.y * wv.w;
            acc[2][0] += xv.z * wv.x; acc[2][1] += xv.z * wv.y; acc[2][2] += xv.z * wv.z; acc[2][3] += xv.z * wv.w;
            acc[3][0] += xv.w * wv.x; acc[3][1] += xv.w * wv.y; acc[3][2] += xv.w * wv.z; acc[3][3] += xv.w * wv.w;
        }
    }
    float4 bv = *(const float4*)(bias + tx * 4);
    #pragma unroll
    for (int i2 = 0; i2 < 4; ++i2) {
        int gr = row0 + ty * 4 + i2;
        if (gr < N) {
            float o0 = acc[i2][0] + bv.x, o1 = acc[i2][1] + bv.y;
            float o2 = acc[i2][2] + bv.z, o3 = acc[i2][3] + bv.w;
            if (ACT) { o0 = lk(o0); o1 = lk(o1); o2 = lk(o2); o3 = lk(o3); }
            *(float4*)(Y + (size_t)gr * COUT + tx * 4) = make_float4(o0, o1, o2, o3);
        }
    }
}

// ---------------- CSR build: histogram -> 2-level exclusive scan -> stable place ----------------
__global__ void hist_kernel(const int* __restrict__ idx, int* __restrict__ cnt, int n) {
    int i = blockIdx.x * 256 + threadIdx.x;
    if (i < n) atomicAdd(&cnt[idx[i]], 1);
}

__global__ void scan_reduce_kernel(const int* __restrict__ cnt, int* __restrict__ bsum, int T) {
    __shared__ int sh[256];
    const int b = blockIdx.x, t = threadIdx.x;
    int s = 0;
    #pragma unroll
    for (int u = 0; u < 4; ++u) {
        int i = b * 1024 + u * 256 + t;
        if (i < T) s += cnt[i];
    }
    sh[t] = s; __syncthreads();
    for (int st = 128; st > 0; st >>= 1) { if (t < st) sh[t] += sh[t + st]; __syncthreads(); }
    if (t == 0) bsum[b] = sh[0];
}

__global__ void scan_top_kernel(int* __restrict__ bsum, int nb) {
    __shared__ int sh[256];
    const int t = threadIdx.x;
    sh[t] = (t < nb) ? bsum[t] : 0;
    __syncthreads();
    if (t == 0) {
        int run = 0;
        for (int i = 0; i < nb; ++i) { int v = sh[i]; sh[i] = run; run += v; }
    }
    __syncthreads();
    if (t < nb) bsum[t] = sh[t];
}

__global__ void scan_final_kernel(const int* __restrict__ cnt, const int* __restrict__ bsum,
                                  int* __restrict__ offs, int* __restrict__ cursor, int T) {
    __shared__ int sh[256];
    const int b = blockIdx.x, t = threadIdx.x;
    const int i0 = b * 1024 + t * 4;
    int v0 = 0, v1 = 0, v2 = 0, v3 = 0;
    if (i0 + 0 < T) v0 = cnt[i0 + 0];
    if (i0 + 1 < T) v1 = cnt[i0 + 1];
    if (i0 + 2 < T) v2 = cnt[i0 + 2];
    if (i0 + 3 < T) v3 = cnt[i0 + 3];
    const int tot = v0 + v1 + v2 + v3;
    sh[t] = tot; __syncthreads();
    for (int st = 1; st < 256; st <<= 1) {
        int x = (t >= st) ? sh[t - st] : 0;
        __syncthreads();
        sh[t] += x;
        __syncthreads();
    }
    int ex = sh[t] - tot + bsum[b];
    if (i0 + 0 < T) { offs[i0 + 0] = ex; cursor[i0 + 0] = ex; } ex += v0;
    if (i0 + 1 < T) { offs[i0 + 1] = ex; cursor[i0 + 1] = ex; } ex += v1;
    if (i0 + 2 < T) { offs[i0 + 2] = ex; cursor[i0 + 2] = ex; } ex += v2;
    if (i0 + 3 < T) { offs[i0 + 3] = ex; cursor[i0 + 3] = ex; }
}

__global__ void place_kernel(const int* __restrict__ idx, int* __restrict__ cursor,
                             int* __restrict__ perm, int n) {
    int i = blockIdx.x * 256 + threadIdx.x;
    if (i < n) { int p = atomicAdd(&cursor[idx[i]], 1); perm[p] = i; }
}

// ---------------- segment mean via CSR (no atomics): 1 wave per target, lane = channel ----------------
__global__ __launch_bounds__(256) void segmean_kernel(
    const float* __restrict__ src, const int* __restrict__ perm,
    const int* __restrict__ offs, const int* __restrict__ cnt,
    float* __restrict__ dst, int T)
{
    const int wave = threadIdx.x >> 6, lane = threadIdx.x & 63;
    const int tg = blockIdx.x * 4 + wave;
    if (tg >= T) return;
    const int o = offs[tg], c = cnt[tg];
    float acc = 0.f;
    for (int j = 0; j < c; ++j) {
        int r = perm[o + j];
        acc += src[(size_t)r * 64 + lane];
    }
    dst[(size_t)tg * 64 + lane] = acc / fmaxf((float)c, 1.0f);
}

__global__ __launch_bounds__(256) void segmean_lob_kernel(
    float* __restrict__ l0, float* __restrict__ l1, float* __restrict__ l2,
    const int* __restrict__ perm, const int* __restrict__ offs, const int* __restrict__ cnt,
    float* __restrict__ dst, int T)
{
    const int wave = threadIdx.x >> 6, lane = threadIdx.x & 63;
    const int tg = blockIdx.x * 4 + wave;
    if (tg >= T) return;
    const int o = offs[tg], c = cnt[tg];
    float acc = 0.f;
    for (int j = 0; j < c; ++j) {
        int r = perm[o + j];
        acc += lob_row(l0, l1, l2, r)[lane];
    }
    dst[(size_t)tg * 64 + lane] = acc / fmaxf((float)c, 1.0f);
}

// ---------------- fused layer_out -> lob rows (no atomics) ----------------
__global__ __launch_bounds__(256) void layer_out_fused_kernel(
    const float* __restrict__ iden, const float* __restrict__ h3,
    const int* __restrict__ cil, const int* __restrict__ dsinv,
    const float* __restrict__ Wo1, const float* __restrict__ bo1,
    const float* __restrict__ Wo2, const float* __restrict__ bo2,
    float* __restrict__ lob0, float* __restrict__ lob1, float* __restrict__ lob2, int N)
{
    __shared__ float XsT[64][68];
    __shared__ float Ws[64][68];
    const int t = threadIdx.x;
    const int row0 = blockIdx.x * 64;
    const int ty = t >> 4, tx = t & 15;
    const int lr = t >> 2, ls = t & 3;
    const int gr = row0 + lr;
    int v = (gr < N) ? cil[gr] : 0;
    int vds = dsinv[v];
    float acc[4][4] = {{0.f}};
    for (int cc = 0; cc < 2; ++cc) {
        const float* src = (cc == 0) ? (iden + (size_t)v * 64) : (h3 + (size_t)vds * 64);
        const float* xr = src + ls * 16;
        float4 v0 = *(const float4*)(xr);
        float4 v1 = *(const float4*)(xr + 4);
        float4 v2f = *(const float4*)(xr + 8);
        float4 v3 = *(const float4*)(xr + 12);
        const float* Wk = Wo1 + (size_t)cc * 4096;
        float4 w0 = *(const float4*)(Wk + t * 4);
        float4 w1 = *(const float4*)(Wk + t * 4 + 1024);
        float4 w2 = *(const float4*)(Wk + t * 4 + 2048);
        float4 w3 = *(const float4*)(Wk + t * 4 + 3072);
        __syncthreads();
        {
            int i0 = t * 4;
            *(float4*)&Ws[i0 >> 6][i0 & 63] = w0; i0 += 1024;
            *(float4*)&Ws[i0 >> 6][i0 & 63] = w1; i0 += 1024;
            *(float4*)&Ws[i0 >> 6][i0 & 63] = w2; i0 += 1024;
            *(float4*)&Ws[i0 >> 6][i0 & 63] = w3;
        }
        const int cb = ls * 16;
        XsT[cb + 0][lr] = v0.x; XsT[cb + 1][lr] = v0.y; XsT[cb + 2][lr] = v0.z; XsT[cb + 3][lr] = v0.w;
        XsT[cb + 4][lr] = v1.x; XsT[cb + 5][lr] = v1.y; XsT[cb + 6][lr] = v1.z; XsT[cb + 7][lr] = v1.w;
        XsT[cb + 8][lr] = v2f.x; XsT[cb + 9][lr] = v2f.y; XsT[cb + 10][lr] = v2f.z; XsT[cb + 11][lr] = v2f.w;
        XsT[cb + 12][lr] = v3.x; XsT[cb + 13][lr] = v3.y; XsT[cb + 14][lr] = v3.z; XsT[cb + 15][lr] = v3.w;
        __syncthreads();
        #pragma unroll 16
        for (int c = 0; c < 64; ++c) {
            float4 xv = *(const float4*)&XsT[c][ty * 4];
            float4 wv = *(const float4*)&Ws[c][tx * 4];
            acc[0][0] += xv.x * wv.x; acc[0][1] += xv.x * wv.y; acc[0][2] += xv.x * wv.z; acc[0][3] += xv.x * wv.w;
            acc[1][0] += xv.y * wv.x; acc[1][1] += xv.y * wv.y; acc[1][2] += xv.y * wv.z; acc[1][3] += xv.y * wv.w;
            acc[2][0] += xv.z * wv.x; acc[2][1] += xv.z * wv.y; acc[2][2] += xv.z * wv.z; acc[2][3] += xv.z * wv.w;
            acc[3][0] += xv.w * wv.x; acc[3][1] += xv.w * wv.y; acc[3][2] += xv.w * wv.z; acc[3][3] += xv.w * wv.w;
        }
    }
    float4 u0 = *(const float4*)(Wo2 + t * 4);
    float4 u1 = *(const float4*)(Wo2 + t * 4 + 1024);
    float4 u2 = *(const float4*)(Wo2 + t * 4 + 2048);
    float4 u3 = *(const float4*)(Wo2 + t * 4 + 3072);
    float4 b1v = *(const float4*)(bo1 + tx * 4);
    __syncthreads();
    {
        int i0 = t * 4;
        *(float4*)&Ws[i0 >> 6][i0 & 63] = u0; i0 += 1024;
        *(float4*)&Ws[i0 >> 6][i0 & 63] = u1; i0 += 1024;
        *(float4*)&Ws[i0 >> 6][i0 & 63] = u2; i0 += 1024;
        *(float4*)&Ws[i0 >> 6][i0 & 63] = u3;
    }
    #pragma unroll
    for (int i = 0; i < 4; ++i) {
        XsT[tx * 4 + 0][ty * 4 + i] = lk(acc[i][0] + b1v.x);
        XsT[tx * 4 + 1][ty * 4 + i] = lk(acc[i][1] + b1v.y);
        XsT[tx * 4 + 2][ty * 4 + i] = lk(acc[i][2] + b1v.z);
        XsT[tx * 4 + 3][ty * 4 + i] = lk(acc[i][3] + b1v.w);
    }
    __syncthreads();
    float acc2[4][4] = {{0.f}};
    #pragma unroll 16
    for (int c = 0; c < 64; ++c) {
        float4 xv = *(const float4*)&XsT[c][ty * 4];
        float4 wv = *(const float4*)&Ws[c][tx * 4];
        acc2[0][0] += xv.x * wv.x; acc2[0][1] += xv.x * wv.y; acc2[0][2] += xv.x * wv.z; acc2[0][3] += xv.x * wv.w;
        acc2[1][0] += xv.y * wv.x; acc2[1][1] += xv.y * wv.y; acc2[1][2] += xv.y * wv.z; acc2[1][3] += xv.y * wv.w;
        acc2[2][0] += xv.z * wv.x; acc2[2][1] += xv.z * wv.y; acc2[2][2] += xv.z * wv.z; acc2[2][3] += xv.z * wv.w;
        acc2[3][0] += xv.w * wv.x; acc2[3][1] += xv.w * wv.y; acc2[3][2] += xv.w * wv.z; acc2[3][3] += xv.w * wv.w;
    }
    float4 b2v = *(const float4*)(bo2 + tx * 4);
    #pragma unroll
    for (int i2 = 0; i2 < 4; ++i2) {
        int gr2 = row0 + ty * 4 + i2;
        if (gr2 < N) {
            float* dst = lob_row(lob0, lob1, lob2, gr2) + tx * 4;
            *(float4*)dst = make_float4(acc2[i2][0] + b2v.x, acc2[i2][1] + b2v.y,
                                        acc2[i2][2] + b2v.z, acc2[i2][3] + b2v.w);
        }
    }
}

__global__ void gather_out_kernel(const float* __restrict__ pf, const int* __restrict__ cin,
                                  float* __restrict__ out, int N) {
    long i = (long)blockIdx.x * 256 + threadIdx.x;
    if (i < (long)N * 16) {
        int p = (int)(i >> 4), q = (int)(i & 15);
        ((float4*)out)[i] = *(const float4*)(pf + (size_t)cin[p] * 64 + q * 4);
    }
}

// ---------------- logit conv: 1 wave per row, lane = channel ----------------
__global__ __launch_bounds__(256) void logit_kernel(
    const float* __restrict__ vp, const int* __restrict__ nbrp,
    const float* __restrict__ Wlog, const float* __restrict__ blog,
    float* __restrict__ out, int N)
{
    __shared__ float Wl[27 * 64];
    const int t = threadIdx.x;
    for (int i = t; i < 1728; i += 256) Wl[i] = Wlog[i];
    __syncthreads();
    const int wave = t >> 6, lane = t & 63;
    for (long row = (long)blockIdx.x * 4 + wave; row < N; row += (long)gridDim.x * 4) {
        float acc = 0.f;
        #pragma unroll
        for (int k = 0; k < 27; ++k) {
            int j = nbrp[row * 27 + k];
            acc += vp[(size_t)j * 64 + lane] * Wl[k * 64 + lane];
        }
        for (int off = 32; off > 0; off >>= 1) acc += __shfl_down(acc, off, 64);
        if (lane == 0) out[row] = acc + blog[0];
    }
}

// ---------------- loss ----------------
__global__ void loss_scatter1_kernel(const int* __restrict__ coors, int* __restrict__ tflag,
                                     int* __restrict__ winner, int N, int NP) {
    int n = blockIdx.x * 256 + threadIdx.x;
    if (n < N) {
        int b = coors[n * 4], x = coors[n * 4 + 1], y = coors[n * 4 + 2], z = coors[n * 4 + 3];
        int flat = ((b * 240 + x) * 180 + y) * 16 + z;
        tflag[flat] = 1;
        if (n < NP) atomicMax(&winner[flat], n);
    }
}

__global__ void loss_scatter2_kernel(const int* __restrict__ coors, const int* __restrict__ winner,
                                     const float* __restrict__ logit, float* __restrict__ xdense, int NP) {
    int n = blockIdx.x * 256 + threadIdx.x;
    if (n < NP) {
        int b = coors[n * 4], x = coors[n * 4 + 1], y = coors[n * 4 + 2], z = coors[n * 4 + 3];
        int flat = ((b * 240 + x) * 180 + y) * 16 + z;
        if (winner[flat] == n) xdense[flat] = logit[n];
    }
}

__global__ void loss_reduce_kernel(const float* __restrict__ xdense, const int* __restrict__ tflag,
                                   float* __restrict__ accum) {
    int i = blockIdx.x * 256 + threadIdx.x;
    float x = xdense[i];
    float tt = (float)tflag[i];
    float term = fmaxf(x, 0.f) - x * tt + log1pf(expf(-fabsf(x)));
    __shared__ float sh[256];
    sh[threadIdx.x] = term;
    __syncthreads();
    for (int s = 128; s > 0; s >>= 1) {
        if (threadIdx.x < s) sh[threadIdx.x] += sh[threadIdx.x + s];
        __syncthreads();
    }
    if (threadIdx.x == 0) atomicAdd(accum, sh[0]);
}

__global__ void loss_final_kernel(const float* __restrict__ accum, float* __restrict__ out) {
    out[0] = accum[0] / (float)NCELL;
}

// ---------------- host orchestration ----------------
extern "C" void kernel_launch(void* const* d_in, const int* in_sizes, int n_in,
                              void* d_out, int out_size, void* d_ws, size_t ws_size,
                              hipStream_t stream)
{
    const float* feats  = (const float*)d_in[0];
    const float* featsp = (const float*)d_in[1];
    const float* Wv11 = (const float*)d_in[2];
    const float* Wv12 = (const float*)d_in[3];
    const float* Wv21 = (const float*)d_in[4];
    const float* Wv22 = (const float*)d_in[5];
    const float* g11 = (const float*)d_in[6];
    const float* g12 = (const float*)d_in[7];
    const float* g21 = (const float*)d_in[8];
    const float* g22 = (const float*)d_in[9];
    const float* b11 = (const float*)d_in[10];
    const float* b12 = (const float*)d_in[11];
    const float* b21 = (const float*)d_in[12];
    const float* b22 = (const float*)d_in[13];
    const float* Wlog = (const float*)d_in[14];
    const float* blog = (const float*)d_in[15];
    const float* Wi  = (const float*)d_in[16];
    const float* bi  = (const float*)d_in[17];
    const float* Wp1 = (const float*)d_in[18];
    const float* bp1 = (const float*)d_in[19];
    const float* gp1 = (const float*)d_in[20];
    const float* bp1n = (const float*)d_in[21];
    const float* Wp2 = (const float*)d_in[22];
    const float* bp2 = (const float*)d_in[23];
    const float* gp2 = (const float*)d_in[24];
    const float* bp2n = (const float*)d_in[25];
    const float* Wp3 = (const float*)d_in[26];
    const float* bp3 = (const float*)d_in[27];
    const float* Wo1 = (const float*)d_in[28];
    const float* bo1 = (const float*)d_in[29];
    const float* Wo2 = (const float*)d_in[30];
    const float* bo2 = (const float*)d_in[31];
    const int* nbr   = (const int*)d_in[32];
    const int* nbrp  = (const int*)d_in[33];
    const int* coors = (const int*)d_in[34];
    const int* cil   = (const int*)d_in[35];
    const int* cin   = (const int*)d_in[36];
    const int* dsinv = (const int*)d_in[37];
    (void)in_sizes; (void)n_in; (void)out_size; (void)ws_size;

    // ---- ws layout (<= 47M floats; >=192 MB proven available) ----
    float* ws = (float*)d_ws;
    float* A     = ws;                  // 16M : conv fp32 out -> identity (live through layer_out)
    float* H     = ws + 16000000L;      // 16M : X1 fp32 -> feat_sum (dead after segmean_ds + Wi gemm)
    float* Hpf32 = ws + 32000000L;      //  8M : partial X1 residual (dead after partial chain)
    float* lob2  = ws + 32000000L;      //  lob R2: rows 500000..599999 (6.4M; reuses dead Hpf32)
    // CSR arrays (ints) in the Hpf32 tail, 38.4M..40M (written after partial chain)
    int* perm_cin   = (int*)(ws + 38400000L);   // 600k
    int* offs_cin   = (int*)(ws + 39000000L);   // 100k
    int* cursor_cin = (int*)(ws + 39100000L);   // 100k
    int* cnt_cin    = (int*)(ws + 39200000L);   // 100k
    int* perm_ds    = (int*)(ws + 39300000L);   // 250k
    int* offs_ds    = (int*)(ws + 39550000L);   // 100k
    int* cursor_ds  = (int*)(ws + 39650000L);   // 100k
    int* cnt_ds     = (int*)(ws + 39750000L);   // 100k
    int* bsum       = (int*)(ws + 39850000L);   // 256
    float* psum  = ws + 40000000L;      //  6.4M (fully written by segmean_lob; no zero-init)
    unsigned short* wt = (unsigned short*)(ws + 46500000L);  // 8 x 110592 bf16
    float* stats = ws + 46950000L;      //  10 x 256
    float* lacc  = ws + 46952560L;      //  1
    unsigned short* wh11 = wt + 0L * 110592;
    unsigned short* wl11 = wt + 1L * 110592;
    unsigned short* wh12 = wt + 2L * 110592;
    unsigned short* wl12 = wt + 3L * 110592;
    unsigned short* wh21 = wt + 4L * 110592;
    unsigned short* wl21 = wt + 5L * 110592;
    unsigned short* wh22 = wt + 6L * 110592;
    unsigned short* wl22 = wt + 7L * 110592;

    // ---- d_out as scratch (38.4M floats, fully overwritten by final gather) ----
    float* o = (float*)d_out;
    // conv-phase: full-tensor bf16 pairs
    unsigned short* F0h = (unsigned short*)(o);               // 16M bf16
    unsigned short* F0l = (unsigned short*)(o + 8000000L);
    unsigned short* F1h = (unsigned short*)(o + 16000000L);
    unsigned short* F1l = (unsigned short*)(o + 24000000L);
    // partial-phase pairs (after full convs done)
    unsigned short* P0h = (unsigned short*)(o);
    unsigned short* P0l = (unsigned short*)(o + 4000000L);
    unsigned short* P1h = (unsigned short*)(o + 8000000L);
    unsigned short* P1l = (unsigned short*)(o + 12000000L);
    float* Cp = o + 16000000L;          // 8M : Vp fp32 (logit input)
    // loss region (disjoint from pairs; dead once loss_reduce folds into lacc)
    float* xdense = o + 32000000L;      // 1.3824M
    int*   tflag  = (int*)(o + 33382400L);
    int*   winner = (int*)(o + 34764800L);
    float* logitb = o + 36147200L;      // 125k
    // post-conv phase (pairs dead)
    float* dssum = o;                   // 6.4M (dead after Wp1 gemm)
    float* t1b   = o + 6400000L;        // 3.2M
    float* t2b   = o + 9600000L;        // 3.2M
    float* h3b   = o + 12800000L;       // 6.4M (live through layer_out)
    // lob regions (live layer_out -> segmean_lob; all prior tenants dead by then)
    float* lob0 = o;                    // rows 0..199999        (o+0 .. 12.8M)
    float* lob1 = o + 19200000L;        // rows 200000..499999   (o+19.2M .. 38.4M)
    float* out = (float*)d_out;

    auto cdiv = [](long a, long b) { return (unsigned)((a + b - 1) / b); };
    dim3 B256(256);

    // ---- inits ----
    fill_u32_kernel<<<cdiv(2561, 256), B256, 0, stream>>>((unsigned*)stats, 0u, 2561);
    fill_u32_kernel<<<cdiv(2764800, 256), B256, 0, stream>>>((unsigned*)xdense, 0u, 2764800);   // xdense+tflag
    fill_u32_kernel<<<cdiv(1382400, 256), B256, 0, stream>>>((unsigned*)winner, 0xFFFFFFFFu, 1382400);

    // ---- weight transpose + split ----
    wsplit_kernel<<<432, B256, 0, stream>>>(Wv11, wh11, wl11);
    wsplit_kernel<<<432, B256, 0, stream>>>(Wv12, wh12, wl12);
    wsplit_kernel<<<432, B256, 0, stream>>>(Wv21, wh21, wl21);
    wsplit_kernel<<<432, B256, 0, stream>>>(Wv22, wh22, wl22);

    // ---- full tensor chain ----
    xsplit_kernel<<<cdiv(16000000, 256), B256, 0, stream>>>(feats, F0h, F0l, 16000000L);
    conv_mfma_kernel<<<cdiv(NVOX, 128), B256, 0, stream>>>(F0h, F0l, nbr, wh11, wl11, A, NVOX);
    colstats_kernel<64><<<256, B256, 0, stream>>>(A, NVOX, stats + 0 * 256);
    mkscale_kernel<<<1, 64, 0, stream>>>(stats + 0 * 256, g11, b11, 1.0f / NVOX, 64);
    apply_bn_kernel<64, 1, 1><<<cdiv(NVOX * 16L, 256), B256, 0, stream>>>(A, stats + 0 * 256, nullptr, nullptr, A, F1h, F1l, NVOX * 16L);
    conv_mfma_kernel<<<cdiv(NVOX, 128), B256, 0, stream>>>(F1h, F1l, nbr, wh12, wl12, A, NVOX);
    colstats_kernel<64><<<256, B256, 0, stream>>>(A, NVOX, stats + 1 * 256);
    mkscale_kernel<<<1, 64, 0, stream>>>(stats + 1 * 256, g12, b12, 1.0f / NVOX, 64);
    apply_bn_kernel<64, 2, 1><<<cdiv(NVOX * 16L, 256), B256, 0, stream>>>(A, stats + 1 * 256, feats, nullptr, H, F0h, F0l, NVOX * 16L);
    conv_mfma_kernel<<<cdiv(NVOX, 128), B256, 0, stream>>>(F0h, F0l, nbr, wh21, wl21, A, NVOX);
    colstats_kernel<64><<<256, B256, 0, stream>>>(A, NVOX, stats + 2 * 256);
    mkscale_kernel<<<1, 64, 0, stream>>>(stats + 2 * 256, g21, b21, 1.0f / NVOX, 64);
    apply_bn_kernel<64, 1, 1><<<cdiv(NVOX * 16L, 256), B256, 0, stream>>>(A, stats + 2 * 256, nullptr, nullptr, A, F1h, F1l, NVOX * 16L);
    conv_mfma_kernel<<<cdiv(NVOX, 128), B256, 0, stream>>>(F1h, F1l, nbr, wh22, wl22, A, NVOX);
    colstats_kernel<64><<<256, B256, 0, stream>>>(A, NVOX, stats + 3 * 256);
    mkscale_kernel<<<1, 64, 0, stream>>>(stats + 3 * 256, g22, b22, 1.0f / NVOX, 64);
    apply_bn_kernel<64, 3, 0><<<cdiv(NVOX * 16L, 256), B256, 0, stream>>>(A, stats + 3 * 256, H, feats, H, nullptr, nullptr, NVOX * 16L);

    // ---- partial tensor chain (same weights) ----
    xsplit_kernel<<<cdiv(8000000, 256), B256, 0, stream>>>(featsp, P0h, P0l, 8000000L);
    conv_mfma_kernel<<<cdiv(NPART, 128), B256, 0, stream>>>(P0h, P0l, nbrp, wh11, wl11, A, NPART);
    colstats_kernel<64><<<256, B256, 0, stream>>>(A, NPART, stats + 4 * 256);
    mkscale_kernel<<<1, 64, 0, stream>>>(stats + 4 * 256, g11, b11, 1.0f / NPART, 64);
    apply_bn_kernel<64, 1, 1><<<cdiv(NPART * 16L, 256), B256, 0, stream>>>(A, stats + 4 * 256, nullptr, nullptr, A, P1h, P1l, NPART * 16L);
    conv_mfma_kernel<<<cdiv(NPART, 128), B256, 0, stream>>>(P1h, P1l, nbrp, wh12, wl12, A, NPART);
    colstats_kernel<64><<<256, B256, 0, stream>>>(A, NPART, stats + 5 * 256);
    mkscale_kernel<<<1, 64, 0, stream>>>(stats + 5 * 256, g12, b12, 1.0f / NPART, 64);
    apply_bn_kernel<64, 2, 1><<<cdiv(NPART * 16L, 256), B256, 0, stream>>>(A, stats + 5 * 256, featsp, nullptr, Hpf32, P0h, P0l, NPART * 16L);
    conv_mfma_kernel<<<cdiv(NPART, 128), B256, 0, stream>>>(P0h, P0l, nbrp, wh21, wl21, A, NPART);
    colstats_kernel<64><<<256, B256, 0, stream>>>(A, NPART, stats + 6 * 256);
    mkscale_kernel<<<1, 64, 0, stream>>>(stats + 6 * 256, g21, b21, 1.0f / NPART, 64);
    apply_bn_kernel<64, 1, 1><<<cdiv(NPART * 16L, 256), B256, 0, stream>>>(A, stats + 6 * 256, nullptr, nullptr, A, P1h, P1l, NPART * 16L);
    conv_mfma_kernel<<<cdiv(NPART, 128), B256, 0, stream>>>(P1h, P1l, nbrp, wh22, wl22, A, NPART);
    colstats_kernel<64><<<256, B256, 0, stream>>>(A, NPART, stats + 7 * 256);
    mkscale_kernel<<<1, 64, 0, stream>>>(stats + 7 * 256, g22, b22, 1.0f / NPART, 64);
    apply_bn_kernel<64, 2, 0><<<cdiv(NPART * 16L, 256), B256, 0, stream>>>(A, stats + 7 * 256, Hpf32, nullptr, Cp, nullptr, nullptr, NPART * 16L);

    // ---- logits + BCE loss ----
    logit_kernel<<<cdiv(NPART, 4), B256, 0, stream>>>(Cp, nbrp, Wlog, blog, logitb, NPART);
    loss_scatter1_kernel<<<cdiv(NVOX, 256), B256, 0, stream>>>(coors, tflag, winner, NVOX, NPART);
    loss_scatter2_kernel<<<cdiv(NPART, 256), B256, 0, stream>>>(coors, winner, logitb, xdense, NPART);
    loss_reduce_kernel<<<NCELL / 256, B256, 0, stream>>>(xdense, tflag, lacc);

    // ---- CSR builds for cin (NPTS->NNEXT) and dsinv (NVOX->NDS); Hpf32 tail is dead now ----
    fill_u32_kernel<<<cdiv(100000, 256), B256, 0, stream>>>((unsigned*)cnt_cin, 0u, 100000);
    fill_u32_kernel<<<cdiv(100000, 256), B256, 0, stream>>>((unsigned*)cnt_ds, 0u, 100000);
    hist_kernel<<<cdiv(NPTS, 256), B256, 0, stream>>>(cin, cnt_cin, NPTS);
    hist_kernel<<<cdiv(NVOX, 256), B256, 0, stream>>>(dsinv, cnt_ds, NVOX);
    scan_reduce_kernel<<<98, B256, 0, stream>>>(cnt_cin, bsum, 100000);
    scan_top_kernel<<<1, B256, 0, stream>>>(bsum, 98);
    scan_final_kernel<<<98, B256, 0, stream>>>(cnt_cin, bsum, offs_cin, cursor_cin, 100000);
    scan_reduce_kernel<<<98, B256, 0, stream>>>(cnt_ds, bsum, 100000);
    scan_top_kernel<<<1, B256, 0, stream>>>(bsum, 98);
    scan_final_kernel<<<98, B256, 0, stream>>>(cnt_ds, bsum, offs_ds, cursor_ds, 100000);
    place_kernel<<<cdiv(NPTS, 256), B256, 0, stream>>>(cin, cursor_cin, perm_cin, NPTS);
    place_kernel<<<cdiv(NVOX, 256), B256, 0, stream>>>(dsinv, cursor_ds, perm_ds, NVOX);

    // ---- point encoder ----
    segmean_kernel<<<cdiv(NDS, 4), B256, 0, stream>>>(H, perm_ds, offs_ds, cnt_ds, dssum, NDS);
    gemm_kernel<64, 64, 1><<<cdiv(NVOX, 64), B256, 0, stream>>>(H, Wi, bi, A, NVOX);   // A = identity

    gemm_kernel<64, 32, 1><<<cdiv(NDS, 128), B256, 0, stream>>>(dssum, Wp1, bp1, t1b, NDS);
    colstats_kernel<32><<<256, B256, 0, stream>>>(t1b, NDS, stats + 8 * 256);
    mkscale_kernel<<<1, 64, 0, stream>>>(stats + 8 * 256, gp1, bp1n, 1.0f / NDS, 32);
    apply_bn_kernel<32, 0, 0><<<cdiv((long)NDS * 8, 256), B256, 0, stream>>>(t1b, stats + 8 * 256, nullptr, nullptr, t1b, nullptr, nullptr, (long)NDS * 8);

    gemm_kernel<32, 32, 1><<<cdiv(NDS, 128), B256, 0, stream>>>(t1b, Wp2, bp2, t2b, NDS);
    colstats_kernel<32><<<256, B256, 0, stream>>>(t2b, NDS, stats + 9 * 256);
    mkscale_kernel<<<1, 64, 0, stream>>>(stats + 9 * 256, gp2, bp2n, 1.0f / NDS, 32);
    apply_bn_kernel<32, 0, 0><<<cdiv((long)NDS * 8, 256), B256, 0, stream>>>(t2b, stats + 9 * 256, nullptr, nullptr, t2b, nullptr, nullptr, (long)NDS * 8);

    gemm_kernel<32, 64, 1><<<cdiv(NDS, 64), B256, 0, stream>>>(t2b, Wp3, bp3, h3b, NDS);

    // ---- fused layer_out (coalesced lob rows, no atomics) + CSR segment-mean ----
    layer_out_fused_kernel<<<cdiv(NPTS, 64), B256, 0, stream>>>(A, h3b, cil, dsinv, Wo1, bo1, Wo2, bo2, lob0, lob1, lob2, NPTS);
    segmean_lob_kernel<<<cdiv(NNEXT, 4), B256, 0, stream>>>(lob0, lob1, lob2, perm_cin, offs_cin, cnt_cin, psum, NNEXT);

    // ---- final outputs ----
    gather_out_kernel<<<cdiv((long)NPTS * 16, 256), B256, 0, stream>>>(psum, cin, out, NPTS);
    loss_final_kernel<<<1, 1, 0, stream>>>(lacc, out + 38400000L);
}

// Round 7
// 3260.498 us; speedup vs baseline: 1.6953x; 1.1143x over previous
//
#include <hip/hip_runtime.h>
#include <math.h>

#define NVOX 250000
#define NPART 125000
#define NPTS 600000
#define NNEXT 100000
#define NDS 100000
#define NCELL 1382400

static __device__ __forceinline__ float lk(float x) { return x >= 0.f ? x : 0.1f * x; }

// bf16 helpers (RNE)
static __device__ __forceinline__ unsigned short f2bf(float f) {
    unsigned u = __float_as_uint(f);
    unsigned r = (u + 0x7FFFu + ((u >> 16) & 1u)) >> 16;
    return (unsigned short)r;
}
static __device__ __forceinline__ float bf2f(unsigned short h) {
    return __uint_as_float((unsigned)h << 16);
}

typedef short v8s __attribute__((ext_vector_type(8)));   // 8 bf16 = 4 VGPR
typedef float v4f __attribute__((ext_vector_type(4)));   // MFMA acc
#define MFMA16 __builtin_amdgcn_mfma_f32_16x16x32_bf16

// lob 3-region row addressing (regions are dead buffers at layer_out time; see host layout)
static __device__ __forceinline__ float* lob_row(float* r0, float* r1, float* r2, int row) {
    if (row < 200000) return r0 + (size_t)row * 64;
    if (row < 500000) return r1 + (size_t)(row - 200000) * 64;
    return r2 + (size_t)(row - 500000) * 64;
}

// ---------------- fill ----------------
__global__ void fill_u32_kernel(unsigned* __restrict__ p, unsigned v, long n) {
    long i = (long)blockIdx.x * 256 + threadIdx.x;
    if (i < n) p[i] = v;
}

// ---------------- weight transpose + hi/lo split: Wt[k][d][c] = split(W[k][c][d]) ----------------
__global__ void wsplit_kernel(const float* __restrict__ W, unsigned short* __restrict__ hi,
                              unsigned short* __restrict__ lo) {
    int i = blockIdx.x * 256 + threadIdx.x;     // over 27*4096
    if (i < 27 * 4096) {
        int k = i >> 12, rem = i & 4095, d = rem >> 6, c = rem & 63;
        float w = W[k * 4096 + c * 64 + d];
        unsigned short h = f2bf(w);
        hi[i] = h;
        lo[i] = f2bf(w - bf2f(h));
    }
}

// ---------------- activation hi/lo split ----------------
__global__ void xsplit_kernel(const float* __restrict__ X, unsigned short* __restrict__ hi,
                              unsigned short* __restrict__ lo, long n) {
    long i = (long)blockIdx.x * 256 + threadIdx.x;
    if (i < n) {
        float x = X[i];
        unsigned short h = f2bf(x);
        hi[i] = h;
        lo[i] = f2bf(x - bf2f(h));
    }
}

// ---------------- MFMA submanifold conv (v5: v4 + fused per-column stats) ----------------
// v4 proven r4/r6: W staged in LDS double-buffered (MSHR relief), 620 -> 321 us.
// v5 adds: col-sum/sumsq reduction in the epilogue (reuses dead Wlds as scratch),
// removing the 8 separate colstats passes (each a full 64MB re-read of Y).
__global__ __launch_bounds__(256) void conv_mfma_kernel(
    const unsigned short* __restrict__ Xhi, const unsigned short* __restrict__ Xlo,
    const int* __restrict__ nbr,
    const unsigned short* __restrict__ Wthi, const unsigned short* __restrict__ Wtlo,
    float* __restrict__ Y, float* __restrict__ stats, int N)
{
    __shared__ __align__(16) unsigned short Wlds[2][8192];   // 2 bufs x (hi 8KB | lo 8KB) = 32 KB

    const int t = threadIdx.x;
    const int wave = t >> 6, lane = t & 63;
    const int m = lane & 15, q = lane >> 4;
    const int qo = q * 8;
    const long base = (long)blockIdx.x * 128 + wave * 32;

    long r0 = base + m;        // rowsub 0 A-row
    long r1 = base + 16 + m;   // rowsub 1 A-row
    long r0c = r0 < N ? r0 : (long)(N - 1);
    long r1c = r1 < N ? r1 : (long)(N - 1);
    const long o0g = r0c * 27, o1g = r1c * 27;

    // staging geometry: thread covers 4 x 16B of the 16KB (hi|lo) tile, bijective over 256 threads
    const int zb = wave * 4096 + lane * 16;
    const int z0 = zb, z1 = zb + 1024, z2 = zb + 2048, z3 = zb + 3072;
    // XOR swizzle -> conflict-free ds_read_b128
    const int d0 = z0 ^ (((z0 >> 7) & 7) << 4);
    const int d1 = z1 ^ (((z1 >> 7) & 7) << 4);
    const int d2 = z2 ^ (((z2 >> 7) & 7) << 4);
    const int d3 = z3 ^ (((z3 >> 7) & 7) << 4);

    v4f acc[2][4];
    #pragma unroll
    for (int s = 0; s < 2; ++s)
        #pragma unroll
        for (int c = 0; c < 4; ++c)
            acc[s][c] = (v4f){0.f, 0.f, 0.f, 0.f};

    // prologue: stage W[0] into buf 0
    {
        const char* ghb = (const char*)Wthi;
        const char* glb = (const char*)Wtlo;
        v8s w0 = *(const v8s*)(z0 < 8192 ? ghb + z0 : glb + (z0 - 8192));
        v8s w1 = *(const v8s*)(z1 < 8192 ? ghb + z1 : glb + (z1 - 8192));
        v8s w2 = *(const v8s*)(z2 < 8192 ? ghb + z2 : glb + (z2 - 8192));
        v8s w3 = *(const v8s*)(z3 < 8192 ? ghb + z3 : glb + (z3 - 8192));
        char* lb = (char*)&Wlds[0][0];
        *(v8s*)(lb + d0) = w0; *(v8s*)(lb + d1) = w1;
        *(v8s*)(lb + d2) = w2; *(v8s*)(lb + d3) = w3;
    }
    __syncthreads();

    #pragma unroll 1
    for (int k = 0; k < 27; ++k) {
        const int cb = k & 1;
        const bool st = (k + 1 < 27);
        v8s w0, w1, w2, w3;
        if (st) {   // issue next-k W loads early; latency hides under this k's compute
            const char* ghb = (const char*)(Wthi + (size_t)(k + 1) * 4096);
            const char* glb = (const char*)(Wtlo + (size_t)(k + 1) * 4096);
            w0 = *(const v8s*)(z0 < 8192 ? ghb + z0 : glb + (z0 - 8192));
            w1 = *(const v8s*)(z1 < 8192 ? ghb + z1 : glb + (z1 - 8192));
            w2 = *(const v8s*)(z2 < 8192 ? ghb + z2 : glb + (z2 - 8192));
            w3 = *(const v8s*)(z3 < 8192 ? ghb + z3 : glb + (z3 - 8192));
        }
        // X gathers for this k
        int j0 = nbr[o0g + k];
        int j1 = nbr[o1g + k];
        const unsigned short* x0h = Xhi + (size_t)j0 * 64 + qo;
        const unsigned short* x0l = Xlo + (size_t)j0 * 64 + qo;
        const unsigned short* x1h = Xhi + (size_t)j1 * 64 + qo;
        const unsigned short* x1l = Xlo + (size_t)j1 * 64 + qo;
        v8s a0h0 = *(const v8s*)(x0h);
        v8s a0h1 = *(const v8s*)(x0h + 32);
        v8s a0l0 = *(const v8s*)(x0l);
        v8s a0l1 = *(const v8s*)(x0l + 32);
        v8s a1h0 = *(const v8s*)(x1h);
        v8s a1h1 = *(const v8s*)(x1h + 32);
        v8s a1l0 = *(const v8s*)(x1l);
        v8s a1l1 = *(const v8s*)(x1l + 32);
        // B fragments from LDS buf cb (swizzled reads)
        const char* wb = (const char*)&Wlds[cb][0];
        const int sw = (m & 7) << 4;
        #pragma unroll
        for (int ct = 0; ct < 4; ++ct) {
            const int rowoff = (ct * 16 + m) * 128;
            v8s bh0 = *(const v8s*)(wb + rowoff + ((q * 16) ^ sw));
            v8s bh1 = *(const v8s*)(wb + rowoff + ((q * 16 + 64) ^ sw));
            v8s bl0 = *(const v8s*)(wb + 8192 + rowoff + ((q * 16) ^ sw));
            v8s bl1 = *(const v8s*)(wb + 8192 + rowoff + ((q * 16 + 64) ^ sw));
            acc[0][ct] = MFMA16(a0h0, bh0, acc[0][ct], 0, 0, 0);
            acc[0][ct] = MFMA16(a0h1, bh1, acc[0][ct], 0, 0, 0);
            acc[0][ct] = MFMA16(a0l0, bh0, acc[0][ct], 0, 0, 0);
            acc[0][ct] = MFMA16(a0l1, bh1, acc[0][ct], 0, 0, 0);
            acc[0][ct] = MFMA16(a0h0, bl0, acc[0][ct], 0, 0, 0);
            acc[0][ct] = MFMA16(a0h1, bl1, acc[0][ct], 0, 0, 0);
            acc[1][ct] = MFMA16(a1h0, bh0, acc[1][ct], 0, 0, 0);
            acc[1][ct] = MFMA16(a1h1, bh1, acc[1][ct], 0, 0, 0);
            acc[1][ct] = MFMA16(a1l0, bh0, acc[1][ct], 0, 0, 0);
            acc[1][ct] = MFMA16(a1l1, bh1, acc[1][ct], 0, 0, 0);
            acc[1][ct] = MFMA16(a1h0, bl0, acc[1][ct], 0, 0, 0);
            acc[1][ct] = MFMA16(a1h1, bl1, acc[1][ct], 0, 0, 0);
        }
        if (st) {
            char* lb = (char*)&Wlds[1 - cb][0];
            *(v8s*)(lb + d0) = w0; *(v8s*)(lb + d1) = w1;
            *(v8s*)(lb + d2) = w2; *(v8s*)(lb + d3) = w3;
        }
        __syncthreads();
    }

    // C/D layout: col = lane&15, row(within 16) = q*4 + reg
    #pragma unroll
    for (int s = 0; s < 2; ++s)
        #pragma unroll
        for (int ct = 0; ct < 4; ++ct)
            #pragma unroll
            for (int rg = 0; rg < 4; ++rg) {
                long r = base + s * 16 + q * 4 + rg;
                if (r < N) Y[r * 64 + ct * 16 + m] = acc[s][ct][rg];
            }

    // fused per-column stats (Wlds dead now; reuse as reduction scratch)
    float* shred = (float*)&Wlds[0][0];   // 128 floats: [0..63]=sum, [64..127]=sumsq
    if (t < 128) shred[t] = 0.f;
    __syncthreads();
    #pragma unroll
    for (int ct = 0; ct < 4; ++ct) {
        float s = 0.f, s2 = 0.f;
        #pragma unroll
        for (int ss = 0; ss < 2; ++ss)
            #pragma unroll
            for (int rg = 0; rg < 4; ++rg) {
                long r = base + ss * 16 + q * 4 + rg;
                if (r < N) { float v = acc[ss][ct][rg]; s += v; s2 += v * v; }
            }
        atomicAdd(&shred[ct * 16 + m], s);
        atomicAdd(&shred[64 + ct * 16 + m], s2);
    }
    __syncthreads();
    if (t < 64) {
        atomicAdd(&stats[t], shred[t]);
        atomicAdd(&stats[64 + t], shred[64 + t]);
    }
}

// ---------------- per-column sum / sumsq (PPmodel 32-ch paths only) ----------------
template<int CC>
__global__ __launch_bounds__(256) void colstats_kernel(const float* __restrict__ Y, int N, float* __restrict__ stats) {
    constexpr int RG = 256 / CC;
    const int t = threadIdx.x;
    const int c = t % CC, rg = t / CC;
    float s = 0.f, s2 = 0.f;
    for (long r = (long)blockIdx.x * RG + rg; r < N; r += (long)gridDim.x * RG) {
        float v = Y[r * CC + c];
        s += v; s2 += v * v;
    }
    __shared__ float sh[256], sh2[256];
    sh[t] = s; sh2[t] = s2;
    __syncthreads();
    if (t < CC) {
        #pragma unroll
        for (int g = 1; g < RG; ++g) { s += sh[g * CC + t]; s2 += sh2[g * CC + t]; }
        atomicAdd(&stats[t], s);
        atomicAdd(&stats[CC + t], s2);
    }
}

__global__ void mkscale_kernel(float* __restrict__ stats, const float* __restrict__ g,
                               const float* __restrict__ b, float invN, int CC) {
    int c = threadIdx.x;
    if (c < CC) {
        float mu = stats[c] * invN;
        float var = stats[CC + c] * invN - mu * mu;
        float sc = g[c] * rsqrtf(var + 1e-5f);
        stats[2 * CC + c] = sc;
        stats[3 * CC + c] = b[c] - mu * sc;
    }
}

// MODE: 0 = y*s+sh ; 1 = leaky(y*s+sh) ; 2 = leaky(y*s+sh + res) ; 3 = res2 + leaky(y*s+sh + res)
// PAIR: also emit bf16 hi/lo split of the result (next conv's input)
template<int CC, int MODE, int PAIR>
__global__ __launch_bounds__(256) void apply_bn_kernel(
    const float* __restrict__ Yin, const float* __restrict__ stats,
    const float* __restrict__ res, const float* __restrict__ res2,
    float* __restrict__ out, unsigned short* __restrict__ ohi,
    unsigned short* __restrict__ olo, long n4)
{
    long i = (long)blockIdx.x * 256 + threadIdx.x;
    if (i >= n4) return;
    int c4 = (int)(i % (CC / 4)) * 4;
    float4 y = ((const float4*)Yin)[i];
    float4 sc = *(const float4*)(stats + 2 * CC + c4);
    float4 sf = *(const float4*)(stats + 3 * CC + c4);
    float x0 = y.x * sc.x + sf.x;
    float x1 = y.y * sc.y + sf.y;
    float x2 = y.z * sc.z + sf.z;
    float x3 = y.w * sc.w + sf.w;
    if (MODE >= 2) {
        float4 rr = ((const float4*)res)[i];
        x0 += rr.x; x1 += rr.y; x2 += rr.z; x3 += rr.w;
    }
    if (MODE >= 1) { x0 = lk(x0); x1 = lk(x1); x2 = lk(x2); x3 = lk(x3); }
    if (MODE == 3) {
        float4 rr2 = ((const float4*)res2)[i];
        x0 += rr2.x; x1 += rr2.y; x2 += rr2.z; x3 += rr2.w;
    }
    ((float4*)out)[i] = make_float4(x0, x1, x2, x3);
    if (PAIR) {
        ushort4 h, l;
        h.x = f2bf(x0); l.x = f2bf(x0 - bf2f(h.x));
        h.y = f2bf(x1); l.y = f2bf(x1 - bf2f(h.y));
        h.z = f2bf(x2); l.z = f2bf(x2 - bf2f(h.z));
        h.w = f2bf(x3); l.w = f2bf(x3 - bf2f(h.w));
        *(ushort4*)(ohi + i * 4) = h;
        *(ushort4*)(olo + i * 4) = l;
    }
}

// ---------------- generic tiled GEMM: Y = act(X[N,CIN] @ W[CIN,COUT] + bias) ----------------
template<int CIN, int COUT, int ACT>
__global__ __launch_bounds__(256) void gemm_kernel(
    const float* __restrict__ X, const float* __restrict__ W,
    const float* __restrict__ bias, float* __restrict__ Y, int N)
{
    constexpr int TX = COUT / 4;
    constexpr int TY = 256 / TX;
    constexpr int ROWS = TY * 4;
    constexpr int CHUNK = (CIN < 64) ? CIN : 64;
    constexpr int NCH = CIN / CHUNK;
    __shared__ float XsT[CHUNK][ROWS + 4];
    __shared__ float Ws[CHUNK][COUT + 4];
    const int t = threadIdx.x;
    const int row0 = blockIdx.x * ROWS;
    const int ty = t / TX, tx = t % TX;
    float acc[4][4] = {{0.f}};
    for (int cc = 0; cc < NCH; ++cc) {
        __syncthreads();
        for (int i = t * 4; i < CHUNK * COUT; i += 1024) {
            int c = i / COUT, d = i % COUT;
            *(float4*)&Ws[c][d] = *(const float4*)(W + (size_t)(cc * CHUNK + c) * COUT + d);
        }
        for (int i = t * 4; i < ROWS * CHUNK; i += 1024) {
            int r = i / CHUNK, c0 = i % CHUNK;
            int gr = row0 + r;
            float4 v = make_float4(0.f, 0.f, 0.f, 0.f);
            if (gr < N) v = *(const float4*)(X + (size_t)gr * CIN + cc * CHUNK + c0);
            XsT[c0 + 0][r] = v.x; XsT[c0 + 1][r] = v.y; XsT[c0 + 2][r] = v.z; XsT[c0 + 3][r] = v.w;
        }
        __syncthreads();
        #pragma unroll 8
        for (int c = 0; c < CHUNK; ++c) {
            float4 xv = *(const float4*)&XsT[c][ty * 4];
            float4 wv = *(const float4*)&Ws[c][tx * 4];
            acc[0][0] += xv.x * wv.x; acc[0][1] += xv.x * wv.y; acc[0][2] += xv.x * wv.z; acc[0][3] += xv.x * wv.w;
            acc[1][0] += xv.y * wv.x; acc[1][1] += xv.y * wv.y; acc[1][2] += xv.y * wv.z; acc[1][3] += xv.y * wv.w;
            acc[2][0] += xv.z * wv.x; acc[2][1] += xv.z * wv.y; acc[2][2] += xv.z * wv.z; acc[2][3] += xv.z * wv.w;
            acc[3][0] += xv.w * wv.x; acc[3][1] += xv.w * wv.y; acc[3][2] += xv.w * wv.z; acc[3][3] += xv.w * wv.w;
        }
    }
    float4 bv = *(const float4*)(bias + tx * 4);
    #pragma unroll
    for (int i2 = 0; i2 < 4; ++i2) {
        int gr = row0 + ty * 4 + i2;
        if (gr < N) {
            float o0 = acc[i2][0] + bv.x, o1 = acc[i2][1] + bv.y;
            float o2 = acc[i2][2] + bv.z, o3 = acc[i2][3] + bv.w;
            if (ACT) { o0 = lk(o0); o1 = lk(o1); o2 = lk(o2); o3 = lk(o3); }
            *(float4*)(Y + (size_t)gr * COUT + tx * 4) = make_float4(o0, o1, o2, o3);
        }
    }
}

// ---------------- CSR build: histogram -> 2-level exclusive scan -> stable place ----------------
__global__ void hist_kernel(const int* __restrict__ idx, int* __restrict__ cnt, int n) {
    int i = blockIdx.x * 256 + threadIdx.x;
    if (i < n) atomicAdd(&cnt[idx[i]], 1);
}

__global__ void scan_reduce_kernel(const int* __restrict__ cnt, int* __restrict__ bsum, int T) {
    __shared__ int sh[256];
    const int b = blockIdx.x, t = threadIdx.x;
    int s = 0;
    #pragma unroll
    for (int u = 0; u < 4; ++u) {
        int i = b * 1024 + u * 256 + t;
        if (i < T) s += cnt[i];
    }
    sh[t] = s; __syncthreads();
    for (int st = 128; st > 0; st >>= 1) { if (t < st) sh[t] += sh[t + st]; __syncthreads(); }
    if (t == 0) bsum[b] = sh[0];
}

__global__ void scan_top_kernel(int* __restrict__ bsum, int nb) {
    __shared__ int sh[256];
    const int t = threadIdx.x;
    sh[t] = (t < nb) ? bsum[t] : 0;
    __syncthreads();
    if (t == 0) {
        int run = 0;
        for (int i = 0; i < nb; ++i) { int v = sh[i]; sh[i] = run; run += v; }
    }
    __syncthreads();
    if (t < nb) bsum[t] = sh[t];
}

__global__ void scan_final_kernel(const int* __restrict__ cnt, const int* __restrict__ bsum,
                                  int* __restrict__ offs, int* __restrict__ cursor, int T) {
    __shared__ int sh[256];
    const int b = blockIdx.x, t = threadIdx.x;
    const int i0 = b * 1024 + t * 4;
    int v0 = 0, v1 = 0, v2 = 0, v3 = 0;
    if (i0 + 0 < T) v0 = cnt[i0 + 0];
    if (i0 + 1 < T) v1 = cnt[i0 + 1];
    if (i0 + 2 < T) v2 = cnt[i0 + 2];
    if (i0 + 3 < T) v3 = cnt[i0 + 3];
    const int tot = v0 + v1 + v2 + v3;
    sh[t] = tot; __syncthreads();
    for (int st = 1; st < 256; st <<= 1) {
        int x = (t >= st) ? sh[t - st] : 0;
        __syncthreads();
        sh[t] += x;
        __syncthreads();
    }
    int ex = sh[t] - tot + bsum[b];
    if (i0 + 0 < T) { offs[i0 + 0] = ex; cursor[i0 + 0] = ex; } ex += v0;
    if (i0 + 1 < T) { offs[i0 + 1] = ex; cursor[i0 + 1] = ex; } ex += v1;
    if (i0 + 2 < T) { offs[i0 + 2] = ex; cursor[i0 + 2] = ex; } ex += v2;
    if (i0 + 3 < T) { offs[i0 + 3] = ex; cursor[i0 + 3] = ex; }
}

__global__ void place_kernel(const int* __restrict__ idx, int* __restrict__ cursor,
                             int* __restrict__ perm, int n) {
    int i = blockIdx.x * 256 + threadIdx.x;
    if (i < n) { int p = atomicAdd(&cursor[idx[i]], 1); perm[p] = i; }
}

// ---------------- segment mean via CSR (no atomics): 1 wave per target, lane = channel ----------------
__global__ __launch_bounds__(256) void segmean_kernel(
    const float* __restrict__ src, const int* __restrict__ perm,
    const int* __restrict__ offs, const int* __restrict__ cnt,
    float* __restrict__ dst, int T)
{
    const int wave = threadIdx.x >> 6, lane = threadIdx.x & 63;
    const int tg = blockIdx.x * 4 + wave;
    if (tg >= T) return;
    const int o = offs[tg], c = cnt[tg];
    float acc = 0.f;
    for (int j = 0; j < c; ++j) {
        int r = perm[o + j];
        acc += src[(size_t)r * 64 + lane];
    }
    dst[(size_t)tg * 64 + lane] = acc / fmaxf((float)c, 1.0f);
}

__global__ __launch_bounds__(256) void segmean_lob_kernel(
    float* __restrict__ l0, float* __restrict__ l1, float* __restrict__ l2,
    const int* __restrict__ perm, const int* __restrict__ offs, const int* __restrict__ cnt,
    float* __restrict__ dst, int T)
{
    const int wave = threadIdx.x >> 6, lane = threadIdx.x & 63;
    const int tg = blockIdx.x * 4 + wave;
    if (tg >= T) return;
    const int o = offs[tg], c = cnt[tg];
    float acc = 0.f;
    for (int j = 0; j < c; ++j) {
        int r = perm[o + j];
        acc += lob_row(l0, l1, l2, r)[lane];
    }
    dst[(size_t)tg * 64 + lane] = acc / fmaxf((float)c, 1.0f);
}

// ---------------- fused layer_out -> lob rows (no atomics) ----------------
__global__ __launch_bounds__(256) void layer_out_fused_kernel(
    const float* __restrict__ iden, const float* __restrict__ h3,
    const int* __restrict__ cil, const int* __restrict__ dsinv,
    const float* __restrict__ Wo1, const float* __restrict__ bo1,
    const float* __restrict__ Wo2, const float* __restrict__ bo2,
    float* __restrict__ lob0, float* __restrict__ lob1, float* __restrict__ lob2, int N)
{
    __shared__ float XsT[64][68];
    __shared__ float Ws[64][68];
    const int t = threadIdx.x;
    const int row0 = blockIdx.x * 64;
    const int ty = t >> 4, tx = t & 15;
    const int lr = t >> 2, ls = t & 3;
    const int gr = row0 + lr;
    int v = (gr < N) ? cil[gr] : 0;
    int vds = dsinv[v];
    float acc[4][4] = {{0.f}};
    for (int cc = 0; cc < 2; ++cc) {
        const float* src = (cc == 0) ? (iden + (size_t)v * 64) : (h3 + (size_t)vds * 64);
        const float* xr = src + ls * 16;
        float4 v0 = *(const float4*)(xr);
        float4 v1 = *(const float4*)(xr + 4);
        float4 v2f = *(const float4*)(xr + 8);
        float4 v3 = *(const float4*)(xr + 12);
        const float* Wk = Wo1 + (size_t)cc * 4096;
        float4 w0 = *(const float4*)(Wk + t * 4);
        float4 w1 = *(const float4*)(Wk + t * 4 + 1024);
        float4 w2 = *(const float4*)(Wk + t * 4 + 2048);
        float4 w3 = *(const float4*)(Wk + t * 4 + 3072);
        __syncthreads();
        {
            int i0 = t * 4;
            *(float4*)&Ws[i0 >> 6][i0 & 63] = w0; i0 += 1024;
            *(float4*)&Ws[i0 >> 6][i0 & 63] = w1; i0 += 1024;
            *(float4*)&Ws[i0 >> 6][i0 & 63] = w2; i0 += 1024;
            *(float4*)&Ws[i0 >> 6][i0 & 63] = w3;
        }
        const int cb = ls * 16;
        XsT[cb + 0][lr] = v0.x; XsT[cb + 1][lr] = v0.y; XsT[cb + 2][lr] = v0.z; XsT[cb + 3][lr] = v0.w;
        XsT[cb + 4][lr] = v1.x; XsT[cb + 5][lr] = v1.y; XsT[cb + 6][lr] = v1.z; XsT[cb + 7][lr] = v1.w;
        XsT[cb + 8][lr] = v2f.x; XsT[cb + 9][lr] = v2f.y; XsT[cb + 10][lr] = v2f.z; XsT[cb + 11][lr] = v2f.w;
        XsT[cb + 12][lr] = v3.x; XsT[cb + 13][lr] = v3.y; XsT[cb + 14][lr] = v3.z; XsT[cb + 15][lr] = v3.w;
        __syncthreads();
        #pragma unroll 16
        for (int c = 0; c < 64; ++c) {
            float4 xv = *(const float4*)&XsT[c][ty * 4];
            float4 wv = *(const float4*)&Ws[c][tx * 4];
            acc[0][0] += xv.x * wv.x; acc[0][1] += xv.x * wv.y; acc[0][2] += xv.x * wv.z; acc[0][3] += xv.x * wv.w;
            acc[1][0] += xv.y * wv.x; acc[1][1] += xv.y * wv.y; acc[1][2] += xv.y * wv.z; acc[1][3] += xv.y * wv.w;
            acc[2][0] += xv.z * wv.x; acc[2][1] += xv.z * wv.y; acc[2][2] += xv.z * wv.z; acc[2][3] += xv.z * wv.w;
            acc[3][0] += xv.w * wv.x; acc[3][1] += xv.w * wv.y; acc[3][2] += xv.w * wv.z; acc[3][3] += xv.w * wv.w;
        }
    }
    float4 u0 = *(const float4*)(Wo2 + t * 4);
    float4 u1 = *(const float4*)(Wo2 + t * 4 + 1024);
    float4 u2 = *(const float4*)(Wo2 + t * 4 + 2048);
    float4 u3 = *(const float4*)(Wo2 + t * 4 + 3072);
    float4 b1v = *(const float4*)(bo1 + tx * 4);
    __syncthreads();
    {
        int i0 = t * 4;
        *(float4*)&Ws[i0 >> 6][i0 & 63] = u0; i0 += 1024;
        *(float4*)&Ws[i0 >> 6][i0 & 63] = u1; i0 += 1024;
        *(float4*)&Ws[i0 >> 6][i0 & 63] = u2; i0 += 1024;
        *(float4*)&Ws[i0 >> 6][i0 & 63] = u3;
    }
    #pragma unroll
    for (int i = 0; i < 4; ++i) {
        XsT[tx * 4 + 0][ty * 4 + i] = lk(acc[i][0] + b1v.x);
        XsT[tx * 4 + 1][ty * 4 + i] = lk(acc[i][1] + b1v.y);
        XsT[tx * 4 + 2][ty * 4 + i] = lk(acc[i][2] + b1v.z);
        XsT[tx * 4 + 3][ty * 4 + i] = lk(acc[i][3] + b1v.w);
    }
    __syncthreads();
    float acc2[4][4] = {{0.f}};
    #pragma unroll 16
    for (int c = 0; c < 64; ++c) {
        float4 xv = *(const float4*)&XsT[c][ty * 4];
        float4 wv = *(const float4*)&Ws[c][tx * 4];
        acc2[0][0] += xv.x * wv.x; acc2[0][1] += xv.x * wv.y; acc2[0][2] += xv.x * wv.z; acc2[0][3] += xv.x * wv.w;
        acc2[1][0] += xv.y * wv.x; acc2[1][1] += xv.y * wv.y; acc2[1][2] += xv.y * wv.z; acc2[1][3] += xv.y * wv.w;
        acc2[2][0] += xv.z * wv.x; acc2[2][1] += xv.z * wv.y; acc2[2][2] += xv.z * wv.z; acc2[2][3] += xv.z * wv.w;
        acc2[3][0] += xv.w * wv.x; acc2[3][1] += xv.w * wv.y; acc2[3][2] += xv.w * wv.z; acc2[3][3] += xv.w * wv.w;
    }
    float4 b2v = *(const float4*)(bo2 + tx * 4);
    #pragma unroll
    for (int i2 = 0; i2 < 4; ++i2) {
        int gr2 = row0 + ty * 4 + i2;
        if (gr2 < N) {
            float* dst = lob_row(lob0, lob1, lob2, gr2) + tx * 4;
            *(float4*)dst = make_float4(acc2[i2][0] + b2v.x, acc2[i2][1] + b2v.y,
                                        acc2[i2][2] + b2v.z, acc2[i2][3] + b2v.w);
        }
    }
}

__global__ void gather_out_kernel(const float* __restrict__ pf, const int* __restrict__ cin,
                                  float* __restrict__ out, int N) {
    long i = (long)blockIdx.x * 256 + threadIdx.x;
    if (i < (long)N * 16) {
        int p = (int)(i >> 4), q = (int)(i & 15);
        ((float4*)out)[i] = *(const float4*)(pf + (size_t)cin[p] * 64 + q * 4);
    }
}

// ---------------- logit via pre-GEMM: s[j,k] = dot(Cp[j,:], Wlog[k,:]) ----------------
// 64 rows per block; LDS-tiled; padded to kill bank conflicts.
__global__ __launch_bounds__(256) void slog_kernel(
    const float* __restrict__ Cp, const float* __restrict__ Wlog,
    float* __restrict__ s, int N)
{
    __shared__ float CpS[64][65];
    __shared__ float WlS[27][65];
    const int t = threadIdx.x;
    const int j0 = blockIdx.x * 64;
    for (int i = t; i < 1728; i += 256) WlS[i / 64][i % 64] = Wlog[i];
    for (int i = t; i < 1024; i += 256) {            // 64 rows x 16 float4
        int r = i >> 4, c4 = (i & 15) * 4;
        int gj = j0 + r;
        float4 v = make_float4(0.f, 0.f, 0.f, 0.f);
        if (gj < N) v = *(const float4*)(Cp + (size_t)gj * 64 + c4);
        CpS[r][c4 + 0] = v.x; CpS[r][c4 + 1] = v.y; CpS[r][c4 + 2] = v.z; CpS[r][c4 + 3] = v.w;
    }
    __syncthreads();
    for (int i = t; i < 64 * 27; i += 256) {
        int r = i / 27, k = i % 27;
        int gj = j0 + r;
        if (gj < N) {
            float acc = 0.f;
            #pragma unroll 16
            for (int c = 0; c < 64; ++c) acc += CpS[r][c] * WlS[k][c];
            s[(size_t)gj * 27 + k] = acc;
        }
    }
}

// logit[n] = blog + sum_k s[nbr[n,k]*27 + k]  (4B scalar gathers into L2/L3-resident table)
__global__ void logit_gather_kernel(const float* __restrict__ s, const int* __restrict__ nbrp,
                                    const float* __restrict__ blog, float* __restrict__ out, int N) {
    int n = blockIdx.x * 256 + threadIdx.x;
    if (n < N) {
        float acc = blog[0];
        #pragma unroll
        for (int k = 0; k < 27; ++k) {
            int j = nbrp[(size_t)n * 27 + k];
            acc += s[(size_t)j * 27 + k];
        }
        out[n] = acc;
    }
}

// ---------------- loss ----------------
__global__ void loss_scatter1_kernel(const int* __restrict__ coors, int* __restrict__ tflag,
                                     int* __restrict__ winner, int N, int NP) {
    int n = blockIdx.x * 256 + threadIdx.x;
    if (n < N) {
        int b = coors[n * 4], x = coors[n * 4 + 1], y = coors[n * 4 + 2], z = coors[n * 4 + 3];
        int flat = ((b * 240 + x) * 180 + y) * 16 + z;
        tflag[flat] = 1;
        if (n < NP) atomicMax(&winner[flat], n);
    }
}

__global__ void loss_scatter2_kernel(const int* __restrict__ coors, const int* __restrict__ winner,
                                     const float* __restrict__ logit, float* __restrict__ xdense, int NP) {
    int n = blockIdx.x * 256 + threadIdx.x;
    if (n < NP) {
        int b = coors[n * 4], x = coors[n * 4 + 1], y = coors[n * 4 + 2], z = coors[n * 4 + 3];
        int flat = ((b * 240 + x) * 180 + y) * 16 + z;
        if (winner[flat] == n) xdense[flat] = logit[n];
    }
}

__global__ void loss_reduce_kernel(const float* __restrict__ xdense, const int* __restrict__ tflag,
                                   float* __restrict__ accum) {
    int i = blockIdx.x * 256 + threadIdx.x;
    float x = xdense[i];
    float tt = (float)tflag[i];
    float term = fmaxf(x, 0.f) - x * tt + log1pf(expf(-fabsf(x)));
    __shared__ float sh[256];
    sh[threadIdx.x] = term;
    __syncthreads();
    for (int s = 128; s > 0; s >>= 1) {
        if (threadIdx.x < s) sh[threadIdx.x] += sh[threadIdx.x + s];
        __syncthreads();
    }
    if (threadIdx.x == 0) atomicAdd(accum, sh[0]);
}

__global__ void loss_final_kernel(const float* __restrict__ accum, float* __restrict__ out) {
    out[0] = accum[0] / (float)NCELL;
}

// ---------------- host orchestration ----------------
extern "C" void kernel_launch(void* const* d_in, const int* in_sizes, int n_in,
                              void* d_out, int out_size, void* d_ws, size_t ws_size,
                              hipStream_t stream)
{
    const float* feats  = (const float*)d_in[0];
    const float* featsp = (const float*)d_in[1];
    const float* Wv11 = (const float*)d_in[2];
    const float* Wv12 = (const float*)d_in[3];
    const float* Wv21 = (const float*)d_in[4];
    const float* Wv22 = (const float*)d_in[5];
    const float* g11 = (const float*)d_in[6];
    const float* g12 = (const float*)d_in[7];
    const float* g21 = (const float*)d_in[8];
    const float* g22 = (const float*)d_in[9];
    const float* b11 = (const float*)d_in[10];
    const float* b12 = (const float*)d_in[11];
    const float* b21 = (const float*)d_in[12];
    const float* b22 = (const float*)d_in[13];
    const float* Wlog = (const float*)d_in[14];
    const float* blog = (const float*)d_in[15];
    const float* Wi  = (const float*)d_in[16];
    const float* bi  = (const float*)d_in[17];
    const float* Wp1 = (const float*)d_in[18];
    const float* bp1 = (const float*)d_in[19];
    const float* gp1 = (const float*)d_in[20];
    const float* bp1n = (const float*)d_in[21];
    const float* Wp2 = (const float*)d_in[22];
    const float* bp2 = (const float*)d_in[23];
    const float* gp2 = (const float*)d_in[24];
    const float* bp2n = (const float*)d_in[25];
    const float* Wp3 = (const float*)d_in[26];
    const float* bp3 = (const float*)d_in[27];
    const float* Wo1 = (const float*)d_in[28];
    const float* bo1 = (const float*)d_in[29];
    const float* Wo2 = (const float*)d_in[30];
    const float* bo2 = (const float*)d_in[31];
    const int* nbr   = (const int*)d_in[32];
    const int* nbrp  = (const int*)d_in[33];
    const int* coors = (const int*)d_in[34];
    const int* cil   = (const int*)d_in[35];
    const int* cin   = (const int*)d_in[36];
    const int* dsinv = (const int*)d_in[37];
    (void)in_sizes; (void)n_in; (void)out_size; (void)ws_size;

    // ---- ws layout (<= 47M floats; >=192 MB proven available) ----
    float* ws = (float*)d_ws;
    float* A     = ws;                  // 16M : conv fp32 out -> identity (live through layer_out)
    float* H     = ws + 16000000L;      // 16M : X1 fp32 -> feat_sum (dead after segmean_ds + Wi gemm)
    float* Hpf32 = ws + 32000000L;      //  8M : partial X1 residual (dead after partial chain)
    float* lob2  = ws + 32000000L;      //  lob R2: rows 500000..599999 (6.4M; reuses dead Hpf32)
    // CSR arrays (ints) in the Hpf32 tail, 38.4M..40M (written after partial chain)
    int* perm_cin   = (int*)(ws + 38400000L);   // 600k
    int* offs_cin   = (int*)(ws + 39000000L);   // 100k
    int* cursor_cin = (int*)(ws + 39100000L);   // 100k
    int* cnt_cin    = (int*)(ws + 39200000L);   // 100k
    int* perm_ds    = (int*)(ws + 39300000L);   // 250k
    int* offs_ds    = (int*)(ws + 39550000L);   // 100k
    int* cursor_ds  = (int*)(ws + 39650000L);   // 100k
    int* cnt_ds     = (int*)(ws + 39750000L);   // 100k
    int* bsum       = (int*)(ws + 39850000L);   // 256
    float* psum  = ws + 40000000L;      //  6.4M (slog table first, then segmean_lob output)
    float* slog  = psum;                //  3.375M floats (dead before segmean_lob writes psum)
    unsigned short* wt = (unsigned short*)(ws + 46500000L);  // 8 x 110592 bf16
    float* stats = ws + 46950000L;      //  10 x 256
    float* lacc  = ws + 46952560L;      //  1
    unsigned short* wh11 = wt + 0L * 110592;
    unsigned short* wl11 = wt + 1L * 110592;
    unsigned short* wh12 = wt + 2L * 110592;
    unsigned short* wl12 = wt + 3L * 110592;
    unsigned short* wh21 = wt + 4L * 110592;
    unsigned short* wl21 = wt + 5L * 110592;
    unsigned short* wh22 = wt + 6L * 110592;
    unsigned short* wl22 = wt + 7L * 110592;

    // ---- d_out as scratch (38.4M floats, fully overwritten by final gather) ----
    float* o = (float*)d_out;
    // conv-phase: full-tensor bf16 pairs
    unsigned short* F0h = (unsigned short*)(o);               // 16M bf16
    unsigned short* F0l = (unsigned short*)(o + 8000000L);
    unsigned short* F1h = (unsigned short*)(o + 16000000L);
    unsigned short* F1l = (unsigned short*)(o + 24000000L);
    // partial-phase pairs (after full convs done)
    unsigned short* P0h = (unsigned short*)(o);
    unsigned short* P0l = (unsigned short*)(o + 4000000L);
    unsigned short* P1h = (unsigned short*)(o + 8000000L);
    unsigned short* P1l = (unsigned short*)(o + 12000000L);
    float* Cp = o + 16000000L;          // 8M : Vp fp32 (slog input)
    // loss region (disjoint from pairs; dead once loss_reduce folds into lacc)
    float* xdense = o + 32000000L;      // 1.3824M
    int*   tflag  = (int*)(o + 33382400L);
    int*   winner = (int*)(o + 34764800L);
    float* logitb = o + 36147200L;      // 125k
    // post-conv phase (pairs dead)
    float* dssum = o;                   // 6.4M (dead after Wp1 gemm)
    float* t1b   = o + 6400000L;        // 3.2M
    float* t2b   = o + 9600000L;        // 3.2M
    float* h3b   = o + 12800000L;       // 6.4M (live through layer_out)
    // lob regions (live layer_out -> segmean_lob; all prior tenants dead by then)
    float* lob0 = o;                    // rows 0..199999        (o+0 .. 12.8M)
    float* lob1 = o + 19200000L;        // rows 200000..499999   (o+19.2M .. 38.4M)
    float* out = (float*)d_out;

    auto cdiv = [](long a, long b) { return (unsigned)((a + b - 1) / b); };
    dim3 B256(256);

    // ---- inits ----
    fill_u32_kernel<<<cdiv(2561, 256), B256, 0, stream>>>((unsigned*)stats, 0u, 2561);
    fill_u32_kernel<<<cdiv(2764800, 256), B256, 0, stream>>>((unsigned*)xdense, 0u, 2764800);   // xdense+tflag
    fill_u32_kernel<<<cdiv(1382400, 256), B256, 0, stream>>>((unsigned*)winner, 0xFFFFFFFFu, 1382400);

    // ---- weight transpose + split ----
    wsplit_kernel<<<432, B256, 0, stream>>>(Wv11, wh11, wl11);
    wsplit_kernel<<<432, B256, 0, stream>>>(Wv12, wh12, wl12);
    wsplit_kernel<<<432, B256, 0, stream>>>(Wv21, wh21, wl21);
    wsplit_kernel<<<432, B256, 0, stream>>>(Wv22, wh22, wl22);

    // ---- full tensor chain (conv now fuses colstats) ----
    xsplit_kernel<<<cdiv(16000000, 256), B256, 0, stream>>>(feats, F0h, F0l, 16000000L);
    conv_mfma_kernel<<<cdiv(NVOX, 128), B256, 0, stream>>>(F0h, F0l, nbr, wh11, wl11, A, stats + 0 * 256, NVOX);
    mkscale_kernel<<<1, 64, 0, stream>>>(stats + 0 * 256, g11, b11, 1.0f / NVOX, 64);
    apply_bn_kernel<64, 1, 1><<<cdiv(NVOX * 16L, 256), B256, 0, stream>>>(A, stats + 0 * 256, nullptr, nullptr, A, F1h, F1l, NVOX * 16L);
    conv_mfma_kernel<<<cdiv(NVOX, 128), B256, 0, stream>>>(F1h, F1l, nbr, wh12, wl12, A, stats + 1 * 256, NVOX);
    mkscale_kernel<<<1, 64, 0, stream>>>(stats + 1 * 256, g12, b12, 1.0f / NVOX, 64);
    apply_bn_kernel<64, 2, 1><<<cdiv(NVOX * 16L, 256), B256, 0, stream>>>(A, stats + 1 * 256, feats, nullptr, H, F0h, F0l, NVOX * 16L);
    conv_mfma_kernel<<<cdiv(NVOX, 128), B256, 0, stream>>>(F0h, F0l, nbr, wh21, wl21, A, stats + 2 * 256, NVOX);
    mkscale_kernel<<<1, 64, 0, stream>>>(stats + 2 * 256, g21, b21, 1.0f / NVOX, 64);
    apply_bn_kernel<64, 1, 1><<<cdiv(NVOX * 16L, 256), B256, 0, stream>>>(A, stats + 2 * 256, nullptr, nullptr, A, F1h, F1l, NVOX * 16L);
    conv_mfma_kernel<<<cdiv(NVOX, 128), B256, 0, stream>>>(F1h, F1l, nbr, wh22, wl22, A, stats + 3 * 256, NVOX);
    mkscale_kernel<<<1, 64, 0, stream>>>(stats + 3 * 256, g22, b22, 1.0f / NVOX, 64);
    apply_bn_kernel<64, 3, 0><<<cdiv(NVOX * 16L, 256), B256, 0, stream>>>(A, stats + 3 * 256, H, feats, H, nullptr, nullptr, NVOX * 16L);

    // ---- partial tensor chain (same weights) ----
    xsplit_kernel<<<cdiv(8000000, 256), B256, 0, stream>>>(featsp, P0h, P0l, 8000000L);
    conv_mfma_kernel<<<cdiv(NPART, 128), B256, 0, stream>>>(P0h, P0l, nbrp, wh11, wl11, A, stats + 4 * 256, NPART);
    mkscale_kernel<<<1, 64, 0, stream>>>(stats + 4 * 256, g11, b11, 1.0f / NPART, 64);
    apply_bn_kernel<64, 1, 1><<<cdiv(NPART * 16L, 256), B256, 0, stream>>>(A, stats + 4 * 256, nullptr, nullptr, A, P1h, P1l, NPART * 16L);
    conv_mfma_kernel<<<cdiv(NPART, 128), B256, 0, stream>>>(P1h, P1l, nbrp, wh12, wl12, A, stats + 5 * 256, NPART);
    mkscale_kernel<<<1, 64, 0, stream>>>(stats + 5 * 256, g12, b12, 1.0f / NPART, 64);
    apply_bn_kernel<64, 2, 1><<<cdiv(NPART * 16L, 256), B256, 0, stream>>>(A, stats + 5 * 256, featsp, nullptr, Hpf32, P0h, P0l, NPART * 16L);
    conv_mfma_kernel<<<cdiv(NPART, 128), B256, 0, stream>>>(P0h, P0l, nbrp, wh21, wl21, A, stats + 6 * 256, NPART);
    mkscale_kernel<<<1, 64, 0, stream>>>(stats + 6 * 256, g21, b21, 1.0f / NPART, 64);
    apply_bn_kernel<64, 1, 1><<<cdiv(NPART * 16L, 256), B256, 0, stream>>>(A, stats + 6 * 256, nullptr, nullptr, A, P1h, P1l, NPART * 16L);
    conv_mfma_kernel<<<cdiv(NPART, 128), B256, 0, stream>>>(P1h, P1l, nbrp, wh22, wl22, A, stats + 7 * 256, NPART);
    mkscale_kernel<<<1, 64, 0, stream>>>(stats + 7 * 256, g22, b22, 1.0f / NPART, 64);
    apply_bn_kernel<64, 2, 0><<<cdiv(NPART * 16L, 256), B256, 0, stream>>>(A, stats + 7 * 256, Hpf32, nullptr, Cp, nullptr, nullptr, NPART * 16L);

    // ---- logits (pre-GEMM + scalar gather) + BCE loss ----
    slog_kernel<<<cdiv(NPART, 64), B256, 0, stream>>>(Cp, Wlog, slog, NPART);
    logit_gather_kernel<<<cdiv(NPART, 256), B256, 0, stream>>>(slog, nbrp, blog, logitb, NPART);
    loss_scatter1_kernel<<<cdiv(NVOX, 256), B256, 0, stream>>>(coors, tflag, winner, NVOX, NPART);
    loss_scatter2_kernel<<<cdiv(NPART, 256), B256, 0, stream>>>(coors, winner, logitb, xdense, NPART);
    loss_reduce_kernel<<<NCELL / 256, B256, 0, stream>>>(xdense, tflag, lacc);

    // ---- CSR builds for cin (NPTS->NNEXT) and dsinv (NVOX->NDS); Hpf32 tail is dead now ----
    fill_u32_kernel<<<cdiv(100000, 256), B256, 0, stream>>>((unsigned*)cnt_cin, 0u, 100000);
    fill_u32_kernel<<<cdiv(100000, 256), B256, 0, stream>>>((unsigned*)cnt_ds, 0u, 100000);
    hist_kernel<<<cdiv(NPTS, 256), B256, 0, stream>>>(cin, cnt_cin, NPTS);
    hist_kernel<<<cdiv(NVOX, 256), B256, 0, stream>>>(dsinv, cnt_ds, NVOX);
    scan_reduce_kernel<<<98, B256, 0, stream>>>(cnt_cin, bsum, 100000);
    scan_top_kernel<<<1, B256, 0, stream>>>(bsum, 98);
    scan_final_kernel<<<98, B256, 0, stream>>>(cnt_cin, bsum, offs_cin, cursor_cin, 100000);
    scan_reduce_kernel<<<98, B256, 0, stream>>>(cnt_ds, bsum, 100000);
    scan_top_kernel<<<1, B256, 0, stream>>>(bsum, 98);
    scan_final_kernel<<<98, B256, 0, stream>>>(cnt_ds, bsum, offs_ds, cursor_ds, 100000);
    place_kernel<<<cdiv(NPTS, 256), B256, 0, stream>>>(cin, cursor_cin, perm_cin, NPTS);
    place_kernel<<<cdiv(NVOX, 256), B256, 0, stream>>>(dsinv, cursor_ds, perm_ds, NVOX);

    // ---- point encoder ----
    segmean_kernel<<<cdiv(NDS, 4), B256, 0, stream>>>(H, perm_ds, offs_ds, cnt_ds, dssum, NDS);
    gemm_kernel<64, 64, 1><<<cdiv(NVOX, 64), B256, 0, stream>>>(H, Wi, bi, A, NVOX);   // A = identity

    gemm_kernel<64, 32, 1><<<cdiv(NDS, 128), B256, 0, stream>>>(dssum, Wp1, bp1, t1b, NDS);
    colstats_kernel<32><<<256, B256, 0, stream>>>(t1b, NDS, stats + 8 * 256);
    mkscale_kernel<<<1, 64, 0, stream>>>(stats + 8 * 256, gp1, bp1n, 1.0f / NDS, 32);
    apply_bn_kernel<32, 0, 0><<<cdiv((long)NDS * 8, 256), B256, 0, stream>>>(t1b, stats + 8 * 256, nullptr, nullptr, t1b, nullptr, nullptr, (long)NDS * 8);

    gemm_kernel<32, 32, 1><<<cdiv(NDS, 128), B256, 0, stream>>>(t1b, Wp2, bp2, t2b, NDS);
    colstats_kernel<32><<<256, B256, 0, stream>>>(t2b, NDS, stats + 9 * 256);
    mkscale_kernel<<<1, 64, 0, stream>>>(stats + 9 * 256, gp2, bp2n, 1.0f / NDS, 32);
    apply_bn_kernel<32, 0, 0><<<cdiv((long)NDS * 8, 256), B256, 0, stream>>>(t2b, stats + 9 * 256, nullptr, nullptr, t2b, nullptr, nullptr, (long)NDS * 8);

    gemm_kernel<32, 64, 1><<<cdiv(NDS, 64), B256, 0, stream>>>(t2b, Wp3, bp3, h3b, NDS);

    // ---- fused layer_out (coalesced lob rows, no atomics) + CSR segment-mean ----
    layer_out_fused_kernel<<<cdiv(NPTS, 64), B256, 0, stream>>>(A, h3b, cil, dsinv, Wo1, bo1, Wo2, bo2, lob0, lob1, lob2, NPTS);
    segmean_lob_kernel<<<cdiv(NNEXT, 4), B256, 0, stream>>>(lob0, lob1, lob2, perm_cin, offs_cin, cnt_cin, psum, NNEXT);

    // ---- final outputs ----
    gather_out_kernel<<<cdiv((long)NPTS * 16, 256), B256, 0, stream>>>(psum, cin, out, NPTS);
    loss_final_kernel<<<1, 1, 0, stream>>>(lacc, out + 38400000L);
}

// Round 8
// 2507.747 us; speedup vs baseline: 2.2041x; 1.3002x over previous
//
#include <hip/hip_runtime.h>
#include <math.h>

#define NVOX 250000
#define NPART 125000
#define NPTS 600000
#define NNEXT 100000
#define NDS 100000
#define NCELL 1382400

static __device__ __forceinline__ float lk(float x) { return x >= 0.f ? x : 0.1f * x; }

// bf16 helpers (RNE) -- still used for nothing numeric-critical now, kept for reference
static __device__ __forceinline__ unsigned short f2bf(float f) {
    unsigned u = __float_as_uint(f);
    unsigned r = (u + 0x7FFFu + ((u >> 16) & 1u)) >> 16;
    return (unsigned short)r;
}
// fp16 helpers
static __device__ __forceinline__ unsigned short f2h(float f) {
    _Float16 h = (_Float16)f;
    return *(unsigned short*)&h;
}
static __device__ __forceinline__ float h2f(unsigned short u) {
    _Float16 h = *(_Float16*)&u;
    return (float)h;
}

typedef short v8s __attribute__((ext_vector_type(8)));       // 8x16-bit raw
typedef _Float16 v8h __attribute__((ext_vector_type(8)));    // 8 fp16 = 4 VGPR
typedef float v4f __attribute__((ext_vector_type(4)));       // MFMA acc
#define MFMAH __builtin_amdgcn_mfma_f32_16x16x32_f16

// lob 3-region row addressing (regions are dead buffers at layer_out time; see host layout)
static __device__ __forceinline__ float* lob_row(float* r0, float* r1, float* r2, int row) {
    if (row < 200000) return r0 + (size_t)row * 64;
    if (row < 500000) return r1 + (size_t)(row - 200000) * 64;
    return r2 + (size_t)(row - 500000) * 64;
}

// ---------------- fill ----------------
__global__ void fill_u32_kernel(unsigned* __restrict__ p, unsigned v, long n) {
    long i = (long)blockIdx.x * 256 + threadIdx.x;
    if (i < n) p[i] = v;
}

// ---------------- weight transpose + fp16 hi/lo split: Wt[k][d][c] = split(W[k][c][d]) ----------------
__global__ void wsplit_kernel(const float* __restrict__ W, unsigned short* __restrict__ hi,
                              unsigned short* __restrict__ lo) {
    int i = blockIdx.x * 256 + threadIdx.x;     // over 27*4096
    if (i < 27 * 4096) {
        int k = i >> 12, rem = i & 4095, d = rem >> 6, c = rem & 63;
        float w = W[k * 4096 + c * 64 + d];
        unsigned short h = f2h(w);
        hi[i] = h;
        lo[i] = f2h(w - h2f(h));
    }
}

// ---------------- activation fp16 convert ----------------
__global__ void xhalf_kernel(const float* __restrict__ X, unsigned short* __restrict__ out, long n) {
    long i = (long)blockIdx.x * 256 + threadIdx.x;
    if (i < n) out[i] = f2h(X[i]);
}

// ---------------- MFMA submanifold conv (v6: fp16-X single, fp16-W hi/lo in LDS) ----------------
// v4/v5 proven: W LDS-staged double-buffered (MSHR relief) + fused colstats.
// v6: X rows are single fp16 (128B/row, half the gather lines -- the binding resource),
// W is fp16 hi/lo (error-free weights). MFMA count 48 -> 32 per wave*k.
__global__ __launch_bounds__(256) void conv_mfma_kernel(
    const unsigned short* __restrict__ Xh,
    const int* __restrict__ nbr,
    const unsigned short* __restrict__ Wthi, const unsigned short* __restrict__ Wtlo,
    float* __restrict__ Y, float* __restrict__ stats, int N)
{
    __shared__ __align__(16) unsigned short Wlds[2][8192];   // 2 bufs x (hi 8KB | lo 8KB) = 32 KB

    const int t = threadIdx.x;
    const int wave = t >> 6, lane = t & 63;
    const int m = lane & 15, q = lane >> 4;
    const int qo = q * 8;
    const long base = (long)blockIdx.x * 128 + wave * 32;

    long r0 = base + m;        // rowsub 0 A-row
    long r1 = base + 16 + m;   // rowsub 1 A-row
    long r0c = r0 < N ? r0 : (long)(N - 1);
    long r1c = r1 < N ? r1 : (long)(N - 1);
    const long o0g = r0c * 27, o1g = r1c * 27;

    // staging geometry: thread covers 4 x 16B of the 16KB (hi|lo) tile, bijective over 256 threads
    const int zb = wave * 4096 + lane * 16;
    const int z0 = zb, z1 = zb + 1024, z2 = zb + 2048, z3 = zb + 3072;
    // XOR swizzle -> conflict-free ds_read_b128
    const int d0 = z0 ^ (((z0 >> 7) & 7) << 4);
    const int d1 = z1 ^ (((z1 >> 7) & 7) << 4);
    const int d2 = z2 ^ (((z2 >> 7) & 7) << 4);
    const int d3 = z3 ^ (((z3 >> 7) & 7) << 4);

    v4f acc[2][4];
    #pragma unroll
    for (int s = 0; s < 2; ++s)
        #pragma unroll
        for (int c = 0; c < 4; ++c)
            acc[s][c] = (v4f){0.f, 0.f, 0.f, 0.f};

    // prologue: stage W[0] into buf 0
    {
        const char* ghb = (const char*)Wthi;
        const char* glb = (const char*)Wtlo;
        v8s w0 = *(const v8s*)(z0 < 8192 ? ghb + z0 : glb + (z0 - 8192));
        v8s w1 = *(const v8s*)(z1 < 8192 ? ghb + z1 : glb + (z1 - 8192));
        v8s w2 = *(const v8s*)(z2 < 8192 ? ghb + z2 : glb + (z2 - 8192));
        v8s w3 = *(const v8s*)(z3 < 8192 ? ghb + z3 : glb + (z3 - 8192));
        char* lb = (char*)&Wlds[0][0];
        *(v8s*)(lb + d0) = w0; *(v8s*)(lb + d1) = w1;
        *(v8s*)(lb + d2) = w2; *(v8s*)(lb + d3) = w3;
    }
    __syncthreads();

    #pragma unroll 1
    for (int k = 0; k < 27; ++k) {
        const int cb = k & 1;
        const bool st = (k + 1 < 27);
        v8s w0, w1, w2, w3;
        if (st) {   // issue next-k W loads early; latency hides under this k's compute
            const char* ghb = (const char*)(Wthi + (size_t)(k + 1) * 4096);
            const char* glb = (const char*)(Wtlo + (size_t)(k + 1) * 4096);
            w0 = *(const v8s*)(z0 < 8192 ? ghb + z0 : glb + (z0 - 8192));
            w1 = *(const v8s*)(z1 < 8192 ? ghb + z1 : glb + (z1 - 8192));
            w2 = *(const v8s*)(z2 < 8192 ? ghb + z2 : glb + (z2 - 8192));
            w3 = *(const v8s*)(z3 < 8192 ? ghb + z3 : glb + (z3 - 8192));
        }
        // X gathers for this k (single fp16 rows, 128B each)
        int j0 = nbr[o0g + k];
        int j1 = nbr[o1g + k];
        const unsigned short* x0 = Xh + (size_t)j0 * 64;
        const unsigned short* x1 = Xh + (size_t)j1 * 64;
        v8h a00 = *(const v8h*)(x0 + qo);
        v8h a01 = *(const v8h*)(x0 + 32 + qo);
        v8h a10 = *(const v8h*)(x1 + qo);
        v8h a11 = *(const v8h*)(x1 + 32 + qo);
        // B fragments from LDS buf cb (swizzled reads)
        const char* wb = (const char*)&Wlds[cb][0];
        const int sw = (m & 7) << 4;
        #pragma unroll
        for (int ct = 0; ct < 4; ++ct) {
            const int rowoff = (ct * 16 + m) * 128;
            v8h bh0 = *(const v8h*)(wb + rowoff + ((q * 16) ^ sw));
            v8h bh1 = *(const v8h*)(wb + rowoff + ((q * 16 + 64) ^ sw));
            v8h bl0 = *(const v8h*)(wb + 8192 + rowoff + ((q * 16) ^ sw));
            v8h bl1 = *(const v8h*)(wb + 8192 + rowoff + ((q * 16 + 64) ^ sw));
            acc[0][ct] = MFMAH(a00, bh0, acc[0][ct], 0, 0, 0);
            acc[0][ct] = MFMAH(a01, bh1, acc[0][ct], 0, 0, 0);
            acc[0][ct] = MFMAH(a00, bl0, acc[0][ct], 0, 0, 0);
            acc[0][ct] = MFMAH(a01, bl1, acc[0][ct], 0, 0, 0);
            acc[1][ct] = MFMAH(a10, bh0, acc[1][ct], 0, 0, 0);
            acc[1][ct] = MFMAH(a11, bh1, acc[1][ct], 0, 0, 0);
            acc[1][ct] = MFMAH(a10, bl0, acc[1][ct], 0, 0, 0);
            acc[1][ct] = MFMAH(a11, bl1, acc[1][ct], 0, 0, 0);
        }
        if (st) {
            char* lb = (char*)&Wlds[1 - cb][0];
            *(v8s*)(lb + d0) = w0; *(v8s*)(lb + d1) = w1;
            *(v8s*)(lb + d2) = w2; *(v8s*)(lb + d3) = w3;
        }
        __syncthreads();
    }

    // C/D layout: col = lane&15, row(within 16) = q*4 + reg
    #pragma unroll
    for (int s = 0; s < 2; ++s)
        #pragma unroll
        for (int ct = 0; ct < 4; ++ct)
            #pragma unroll
            for (int rg = 0; rg < 4; ++rg) {
                long r = base + s * 16 + q * 4 + rg;
                if (r < N) Y[r * 64 + ct * 16 + m] = acc[s][ct][rg];
            }

    // fused per-column stats (Wlds dead now; reuse as reduction scratch)
    float* shred = (float*)&Wlds[0][0];   // 128 floats: [0..63]=sum, [64..127]=sumsq
    if (t < 128) shred[t] = 0.f;
    __syncthreads();
    #pragma unroll
    for (int ct = 0; ct < 4; ++ct) {
        float s = 0.f, s2 = 0.f;
        #pragma unroll
        for (int ss = 0; ss < 2; ++ss)
            #pragma unroll
            for (int rg = 0; rg < 4; ++rg) {
                long r = base + ss * 16 + q * 4 + rg;
                if (r < N) { float v = acc[ss][ct][rg]; s += v; s2 += v * v; }
            }
        atomicAdd(&shred[ct * 16 + m], s);
        atomicAdd(&shred[64 + ct * 16 + m], s2);
    }
    __syncthreads();
    if (t < 64) {
        atomicAdd(&stats[t], shred[t]);
        atomicAdd(&stats[64 + t], shred[64 + t]);
    }
}

// ---------------- per-column sum / sumsq (PPmodel 32-ch paths only) ----------------
template<int CC>
__global__ __launch_bounds__(256) void colstats_kernel(const float* __restrict__ Y, int N, float* __restrict__ stats) {
    constexpr int RG = 256 / CC;
    const int t = threadIdx.x;
    const int c = t % CC, rg = t / CC;
    float s = 0.f, s2 = 0.f;
    for (long r = (long)blockIdx.x * RG + rg; r < N; r += (long)gridDim.x * RG) {
        float v = Y[r * CC + c];
        s += v; s2 += v * v;
    }
    __shared__ float sh[256], sh2[256];
    sh[t] = s; sh2[t] = s2;
    __syncthreads();
    if (t < CC) {
        #pragma unroll
        for (int g = 1; g < RG; ++g) { s += sh[g * CC + t]; s2 += sh2[g * CC + t]; }
        atomicAdd(&stats[t], s);
        atomicAdd(&stats[CC + t], s2);
    }
}

__global__ void mkscale_kernel(float* __restrict__ stats, const float* __restrict__ g,
                               const float* __restrict__ b, float invN, int CC) {
    int c = threadIdx.x;
    if (c < CC) {
        float mu = stats[c] * invN;
        float var = stats[CC + c] * invN - mu * mu;
        float sc = g[c] * rsqrtf(var + 1e-5f);
        stats[2 * CC + c] = sc;
        stats[3 * CC + c] = b[c] - mu * sc;
    }
}

// MODE: 0 = y*s+sh ; 1 = leaky(y*s+sh) ; 2 = leaky(y*s+sh + res) ; 3 = res2 + leaky(y*s+sh + res)
// PAIR: also emit fp16 of the result (next conv's input). WOUT: write the fp32 result (0 = dead store, skip)
template<int CC, int MODE, int PAIR, int WOUT>
__global__ __launch_bounds__(256) void apply_bn_kernel(
    const float* __restrict__ Yin, const float* __restrict__ stats,
    const float* __restrict__ res, const float* __restrict__ res2,
    float* __restrict__ out, unsigned short* __restrict__ ohalf, long n4)
{
    long i = (long)blockIdx.x * 256 + threadIdx.x;
    if (i >= n4) return;
    int c4 = (int)(i % (CC / 4)) * 4;
    float4 y = ((const float4*)Yin)[i];
    float4 sc = *(const float4*)(stats + 2 * CC + c4);
    float4 sf = *(const float4*)(stats + 3 * CC + c4);
    float x0 = y.x * sc.x + sf.x;
    float x1 = y.y * sc.y + sf.y;
    float x2 = y.z * sc.z + sf.z;
    float x3 = y.w * sc.w + sf.w;
    if (MODE >= 2) {
        float4 rr = ((const float4*)res)[i];
        x0 += rr.x; x1 += rr.y; x2 += rr.z; x3 += rr.w;
    }
    if (MODE >= 1) { x0 = lk(x0); x1 = lk(x1); x2 = lk(x2); x3 = lk(x3); }
    if (MODE == 3) {
        float4 rr2 = ((const float4*)res2)[i];
        x0 += rr2.x; x1 += rr2.y; x2 += rr2.z; x3 += rr2.w;
    }
    if (WOUT) ((float4*)out)[i] = make_float4(x0, x1, x2, x3);
    if (PAIR) {
        ushort4 h;
        h.x = f2h(x0); h.y = f2h(x1); h.z = f2h(x2); h.w = f2h(x3);
        *(ushort4*)(ohalf + i * 4) = h;
    }
}

// ---------------- generic tiled GEMM: Y = act(X[N,CIN] @ W[CIN,COUT] + bias) ----------------
template<int CIN, int COUT, int ACT>
__global__ __launch_bounds__(256) void gemm_kernel(
    const float* __restrict__ X, const float* __restrict__ W,
    const float* __restrict__ bias, float* __restrict__ Y, int N)
{
    constexpr int TX = COUT / 4;
    constexpr int TY = 256 / TX;
    constexpr int ROWS = TY * 4;
    constexpr int CHUNK = (CIN < 64) ? CIN : 64;
    constexpr int NCH = CIN / CHUNK;
    __shared__ float XsT[CHUNK][ROWS + 4];
    __shared__ float Ws[CHUNK][COUT + 4];
    const int t = threadIdx.x;
    const int row0 = blockIdx.x * ROWS;
    const int ty = t / TX, tx = t % TX;
    float acc[4][4] = {{0.f}};
    for (int cc = 0; cc < NCH; ++cc) {
        __syncthreads();
        for (int i = t * 4; i < CHUNK * COUT; i += 1024) {
            int c = i / COUT, d = i % COUT;
            *(float4*)&Ws[c][d] = *(const float4*)(W + (size_t)(cc * CHUNK + c) * COUT + d);
        }
        for (int i = t * 4; i < ROWS * CHUNK; i += 1024) {
            int r = i / CHUNK, c0 = i % CHUNK;
            int gr = row0 + r;
            float4 v = make_float4(0.f, 0.f, 0.f, 0.f);
            if (gr < N) v = *(const float4*)(X + (size_t)gr * CIN + cc * CHUNK + c0);
            XsT[c0 + 0][r] = v.x; XsT[c0 + 1][r] = v.y; XsT[c0 + 2][r] = v.z; XsT[c0 + 3][r] = v.w;
        }
        __syncthreads();
        #pragma unroll 8
        for (int c = 0; c < CHUNK; ++c) {
            float4 xv = *(const float4*)&XsT[c][ty * 4];
            float4 wv = *(const float4*)&Ws[c][tx * 4];
            acc[0][0] += xv.x * wv.x; acc[0][1] += xv.x * wv.y; acc[0][2] += xv.x * wv.z; acc[0][3] += xv.x * wv.w;
            acc[1][0] += xv.y * wv.x; acc[1][1] += xv.y * wv.y; acc[1][2] += xv.y * wv.z; acc[1][3] += xv.y * wv.w;
            acc[2][0] += xv.z * wv.x; acc[2][1] += xv.z * wv.y; acc[2][2] += xv.z * wv.z; acc[2][3] += xv.z * wv.w;
            acc[3][0] += xv.w * wv.x; acc[3][1] += xv.w * wv.y; acc[3][2] += xv.w * wv.z; acc[3][3] += xv.w * wv.w;
        }
    }
    float4 bv = *(const float4*)(bias + tx * 4);
    #pragma unroll
    for (int i2 = 0; i2 < 4; ++i2) {
        int gr = row0 + ty * 4 + i2;
        if (gr < N) {
            float o0 = acc[i2][0] + bv.x, o1 = acc[i2][1] + bv.y;
            float o2 = acc[i2][2] + bv.z, o3 = acc[i2][3] + bv.w;
            if (ACT) { o0 = lk(o0); o1 = lk(o1); o2 = lk(o2); o3 = lk(o3); }
            *(float4*)(Y + (size_t)gr * COUT + tx * 4) = make_float4(o0, o1, o2, o3);
        }
    }
}

// ---------------- CSR build: histogram -> 2-level exclusive scan -> stable place ----------------
__global__ void hist_kernel(const int* __restrict__ idx, int* __restrict__ cnt, int n) {
    int i = blockIdx.x * 256 + threadIdx.x;
    if (i < n) atomicAdd(&cnt[idx[i]], 1);
}

__global__ void scan_reduce_kernel(const int* __restrict__ cnt, int* __restrict__ bsum, int T) {
    __shared__ int sh[256];
    const int b = blockIdx.x, t = threadIdx.x;
    int s = 0;
    #pragma unroll
    for (int u = 0; u < 4; ++u) {
        int i = b * 1024 + u * 256 + t;
        if (i < T) s += cnt[i];
    }
    sh[t] = s; __syncthreads();
    for (int st = 128; st > 0; st >>= 1) { if (t < st) sh[t] += sh[t + st]; __syncthreads(); }
    if (t == 0) bsum[b] = sh[0];
}

__global__ void scan_top_kernel(int* __restrict__ bsum, int nb) {
    __shared__ int sh[256];
    const int t = threadIdx.x;
    sh[t] = (t < nb) ? bsum[t] : 0;
    __syncthreads();
    if (t == 0) {
        int run = 0;
        for (int i = 0; i < nb; ++i) { int v = sh[i]; sh[i] = run; run += v; }
    }
    __syncthreads();
    if (t < nb) bsum[t] = sh[t];
}

__global__ void scan_final_kernel(const int* __restrict__ cnt, const int* __restrict__ bsum,
                                  int* __restrict__ offs, int* __restrict__ cursor, int T) {
    __shared__ int sh[256];
    const int b = blockIdx.x, t = threadIdx.x;
    const int i0 = b * 1024 + t * 4;
    int v0 = 0, v1 = 0, v2 = 0, v3 = 0;
    if (i0 + 0 < T) v0 = cnt[i0 + 0];
    if (i0 + 1 < T) v1 = cnt[i0 + 1];
    if (i0 + 2 < T) v2 = cnt[i0 + 2];
    if (i0 + 3 < T) v3 = cnt[i0 + 3];
    const int tot = v0 + v1 + v2 + v3;
    sh[t] = tot; __syncthreads();
    for (int st = 1; st < 256; st <<= 1) {
        int x = (t >= st) ? sh[t - st] : 0;
        __syncthreads();
        sh[t] += x;
        __syncthreads();
    }
    int ex = sh[t] - tot + bsum[b];
    if (i0 + 0 < T) { offs[i0 + 0] = ex; cursor[i0 + 0] = ex; } ex += v0;
    if (i0 + 1 < T) { offs[i0 + 1] = ex; cursor[i0 + 1] = ex; } ex += v1;
    if (i0 + 2 < T) { offs[i0 + 2] = ex; cursor[i0 + 2] = ex; } ex += v2;
    if (i0 + 3 < T) { offs[i0 + 3] = ex; cursor[i0 + 3] = ex; }
}

__global__ void place_kernel(const int* __restrict__ idx, int* __restrict__ cursor,
                             int* __restrict__ perm, int n) {
    int i = blockIdx.x * 256 + threadIdx.x;
    if (i < n) { int p = atomicAdd(&cursor[idx[i]], 1); perm[p] = i; }
}

// ---------------- segment mean via CSR (no atomics): 1 wave per target, lane = channel ----------------
__global__ __launch_bounds__(256) void segmean_kernel(
    const float* __restrict__ src, const int* __restrict__ perm,
    const int* __restrict__ offs, const int* __restrict__ cnt,
    float* __restrict__ dst, int T)
{
    const int wave = threadIdx.x >> 6, lane = threadIdx.x & 63;
    const int tg = blockIdx.x * 4 + wave;
    if (tg >= T) return;
    const int o = offs[tg], c = cnt[tg];
    float acc = 0.f;
    for (int j = 0; j < c; ++j) {
        int r = perm[o + j];
        acc += src[(size_t)r * 64 + lane];
    }
    dst[(size_t)tg * 64 + lane] = acc / fmaxf((float)c, 1.0f);
}

__global__ __launch_bounds__(256) void segmean_lob_kernel(
    float* __restrict__ l0, float* __restrict__ l1, float* __restrict__ l2,
    const int* __restrict__ perm, const int* __restrict__ offs, const int* __restrict__ cnt,
    float* __restrict__ dst, int T)
{
    const int wave = threadIdx.x >> 6, lane = threadIdx.x & 63;
    const int tg = blockIdx.x * 4 + wave;
    if (tg >= T) return;
    const int o = offs[tg], c = cnt[tg];
    float acc = 0.f;
    for (int j = 0; j < c; ++j) {
        int r = perm[o + j];
        acc += lob_row(l0, l1, l2, r)[lane];
    }
    dst[(size_t)tg * 64 + lane] = acc / fmaxf((float)c, 1.0f);
}

// ---------------- fused layer_out -> lob rows (no atomics) ----------------
__global__ __launch_bounds__(256) void layer_out_fused_kernel(
    const float* __restrict__ iden, const float* __restrict__ h3,
    const int* __restrict__ cil, const int* __restrict__ dsinv,
    const float* __restrict__ Wo1, const float* __restrict__ bo1,
    const float* __restrict__ Wo2, const float* __restrict__ bo2,
    float* __restrict__ lob0, float* __restrict__ lob1, float* __restrict__ lob2, int N)
{
    __shared__ float XsT[64][68];
    __shared__ float Ws[64][68];
    const int t = threadIdx.x;
    const int row0 = blockIdx.x * 64;
    const int ty = t >> 4, tx = t & 15;
    const int lr = t >> 2, ls = t & 3;
    const int gr = row0 + lr;
    int v = (gr < N) ? cil[gr] : 0;
    int vds = dsinv[v];
    float acc[4][4] = {{0.f}};
    for (int cc = 0; cc < 2; ++cc) {
        const float* src = (cc == 0) ? (iden + (size_t)v * 64) : (h3 + (size_t)vds * 64);
        const float* xr = src + ls * 16;
        float4 v0 = *(const float4*)(xr);
        float4 v1 = *(const float4*)(xr + 4);
        float4 v2f = *(const float4*)(xr + 8);
        float4 v3 = *(const float4*)(xr + 12);
        const float* Wk = Wo1 + (size_t)cc * 4096;
        float4 w0 = *(const float4*)(Wk + t * 4);
        float4 w1 = *(const float4*)(Wk + t * 4 + 1024);
        float4 w2 = *(const float4*)(Wk + t * 4 + 2048);
        float4 w3 = *(const float4*)(Wk + t * 4 + 3072);
        __syncthreads();
        {
            int i0 = t * 4;
            *(float4*)&Ws[i0 >> 6][i0 & 63] = w0; i0 += 1024;
            *(float4*)&Ws[i0 >> 6][i0 & 63] = w1; i0 += 1024;
            *(float4*)&Ws[i0 >> 6][i0 & 63] = w2; i0 += 1024;
            *(float4*)&Ws[i0 >> 6][i0 & 63] = w3;
        }
        const int cb = ls * 16;
        XsT[cb + 0][lr] = v0.x; XsT[cb + 1][lr] = v0.y; XsT[cb + 2][lr] = v0.z; XsT[cb + 3][lr] = v0.w;
        XsT[cb + 4][lr] = v1.x; XsT[cb + 5][lr] = v1.y; XsT[cb + 6][lr] = v1.z; XsT[cb + 7][lr] = v1.w;
        XsT[cb + 8][lr] = v2f.x; XsT[cb + 9][lr] = v2f.y; XsT[cb + 10][lr] = v2f.z; XsT[cb + 11][lr] = v2f.w;
        XsT[cb + 12][lr] = v3.x; XsT[cb + 13][lr] = v3.y; XsT[cb + 14][lr] = v3.z; XsT[cb + 15][lr] = v3.w;
        __syncthreads();
        #pragma unroll 16
        for (int c = 0; c < 64; ++c) {
            float4 xv = *(const float4*)&XsT[c][ty * 4];
            float4 wv = *(const float4*)&Ws[c][tx * 4];
            acc[0][0] += xv.x * wv.x; acc[0][1] += xv.x * wv.y; acc[0][2] += xv.x * wv.z; acc[0][3] += xv.x * wv.w;
            acc[1][0] += xv.y * wv.x; acc[1][1] += xv.y * wv.y; acc[1][2] += xv.y * wv.z; acc[1][3] += xv.y * wv.w;
            acc[2][0] += xv.z * wv.x; acc[2][1] += xv.z * wv.y; acc[2][2] += xv.z * wv.z; acc[2][3] += xv.z * wv.w;
            acc[3][0] += xv.w * wv.x; acc[3][1] += xv.w * wv.y; acc[3][2] += xv.w * wv.z; acc[3][3] += xv.w * wv.w;
        }
    }
    float4 u0 = *(const float4*)(Wo2 + t * 4);
    float4 u1 = *(const float4*)(Wo2 + t * 4 + 1024);
    float4 u2 = *(const float4*)(Wo2 + t * 4 + 2048);
    float4 u3 = *(const float4*)(Wo2 + t * 4 + 3072);
    float4 b1v = *(const float4*)(bo1 + tx * 4);
    __syncthreads();
    {
        int i0 = t * 4;
        *(float4*)&Ws[i0 >> 6][i0 & 63] = u0; i0 += 1024;
        *(float4*)&Ws[i0 >> 6][i0 & 63] = u1; i0 += 1024;
        *(float4*)&Ws[i0 >> 6][i0 & 63] = u2; i0 += 1024;
        *(float4*)&Ws[i0 >> 6][i0 & 63] = u3;
    }
    #pragma unroll
    for (int i = 0; i < 4; ++i) {
        XsT[tx * 4 + 0][ty * 4 + i] = lk(acc[i][0] + b1v.x);
        XsT[tx * 4 + 1][ty * 4 + i] = lk(acc[i][1] + b1v.y);
        XsT[tx * 4 + 2][ty * 4 + i] = lk(acc[i][2] + b1v.z);
        XsT[tx * 4 + 3][ty * 4 + i] = lk(acc[i][3] + b1v.w);
    }
    __syncthreads();
    float acc2[4][4] = {{0.f}};
    #pragma unroll 16
    for (int c = 0; c < 64; ++c) {
        float4 xv = *(const float4*)&XsT[c][ty * 4];
        float4 wv = *(const float4*)&Ws[c][tx * 4];
        acc2[0][0] += xv.x * wv.x; acc2[0][1] += xv.x * wv.y; acc2[0][2] += xv.x * wv.z; acc2[0][3] += xv.x * wv.w;
        acc2[1][0] += xv.y * wv.x; acc2[1][1] += xv.y * wv.y; acc2[1][2] += xv.y * wv.z; acc2[1][3] += xv.y * wv.w;
        acc2[2][0] += xv.z * wv.x; acc2[2][1] += xv.z * wv.y; acc2[2][2] += xv.z * wv.z; acc2[2][3] += xv.z * wv.w;
        acc2[3][0] += xv.w * wv.x; acc2[3][1] += xv.w * wv.y; acc2[3][2] += xv.w * wv.z; acc2[3][3] += xv.w * wv.w;
    }
    float4 b2v = *(const float4*)(bo2 + tx * 4);
    #pragma unroll
    for (int i2 = 0; i2 < 4; ++i2) {
        int gr2 = row0 + ty * 4 + i2;
        if (gr2 < N) {
            float* dst = lob_row(lob0, lob1, lob2, gr2) + tx * 4;
            *(float4*)dst = make_float4(acc2[i2][0] + b2v.x, acc2[i2][1] + b2v.y,
                                        acc2[i2][2] + b2v.z, acc2[i2][3] + b2v.w);
        }
    }
}

__global__ void gather_out_kernel(const float* __restrict__ pf, const int* __restrict__ cin,
                                  float* __restrict__ out, int N) {
    long i = (long)blockIdx.x * 256 + threadIdx.x;
    if (i < (long)N * 16) {
        int p = (int)(i >> 4), q = (int)(i & 15);
        ((float4*)out)[i] = *(const float4*)(pf + (size_t)cin[p] * 64 + q * 4);
    }
}

// ---------------- logit via pre-GEMM: s[j,k] = dot(Cp[j,:], Wlog[k,:]) ----------------
__global__ __launch_bounds__(256) void slog_kernel(
    const float* __restrict__ Cp, const float* __restrict__ Wlog,
    float* __restrict__ s, int N)
{
    __shared__ float CpS[64][65];
    __shared__ float WlS[27][65];
    const int t = threadIdx.x;
    const int j0 = blockIdx.x * 64;
    for (int i = t; i < 1728; i += 256) WlS[i / 64][i % 64] = Wlog[i];
    for (int i = t; i < 1024; i += 256) {            // 64 rows x 16 float4
        int r = i >> 4, c4 = (i & 15) * 4;
        int gj = j0 + r;
        float4 v = make_float4(0.f, 0.f, 0.f, 0.f);
        if (gj < N) v = *(const float4*)(Cp + (size_t)gj * 64 + c4);
        CpS[r][c4 + 0] = v.x; CpS[r][c4 + 1] = v.y; CpS[r][c4 + 2] = v.z; CpS[r][c4 + 3] = v.w;
    }
    __syncthreads();
    for (int i = t; i < 64 * 27; i += 256) {
        int r = i / 27, k = i % 27;
        int gj = j0 + r;
        if (gj < N) {
            float acc = 0.f;
            #pragma unroll 16
            for (int c = 0; c < 64; ++c) acc += CpS[r][c] * WlS[k][c];
            s[(size_t)gj * 27 + k] = acc;
        }
    }
}

// logit[n] = blog + sum_k s[nbr[n,k]*27 + k]
__global__ void logit_gather_kernel(const float* __restrict__ s, const int* __restrict__ nbrp,
                                    const float* __restrict__ blog, float* __restrict__ out, int N) {
    int n = blockIdx.x * 256 + threadIdx.x;
    if (n < N) {
        float acc = blog[0];
        #pragma unroll
        for (int k = 0; k < 27; ++k) {
            int j = nbrp[(size_t)n * 27 + k];
            acc += s[(size_t)j * 27 + k];
        }
        out[n] = acc;
    }
}

// ---------------- loss ----------------
__global__ void loss_scatter1_kernel(const int* __restrict__ coors, int* __restrict__ tflag,
                                     int* __restrict__ winner, int N, int NP) {
    int n = blockIdx.x * 256 + threadIdx.x;
    if (n < N) {
        int b = coors[n * 4], x = coors[n * 4 + 1], y = coors[n * 4 + 2], z = coors[n * 4 + 3];
        int flat = ((b * 240 + x) * 180 + y) * 16 + z;
        tflag[flat] = 1;
        if (n < NP) atomicMax(&winner[flat], n);
    }
}

__global__ void loss_scatter2_kernel(const int* __restrict__ coors, const int* __restrict__ winner,
                                     const float* __restrict__ logit, float* __restrict__ xdense, int NP) {
    int n = blockIdx.x * 256 + threadIdx.x;
    if (n < NP) {
        int b = coors[n * 4], x = coors[n * 4 + 1], y = coors[n * 4 + 2], z = coors[n * 4 + 3];
        int flat = ((b * 240 + x) * 180 + y) * 16 + z;
        if (winner[flat] == n) xdense[flat] = logit[n];
    }
}

__global__ void loss_reduce_kernel(const float* __restrict__ xdense, const int* __restrict__ tflag,
                                   float* __restrict__ accum) {
    int i = blockIdx.x * 256 + threadIdx.x;
    float x = xdense[i];
    float tt = (float)tflag[i];
    float term = fmaxf(x, 0.f) - x * tt + log1pf(expf(-fabsf(x)));
    __shared__ float sh[256];
    sh[threadIdx.x] = term;
    __syncthreads();
    for (int s = 128; s > 0; s >>= 1) {
        if (threadIdx.x < s) sh[threadIdx.x] += sh[threadIdx.x + s];
        __syncthreads();
    }
    if (threadIdx.x == 0) atomicAdd(accum, sh[0]);
}

__global__ void loss_final_kernel(const float* __restrict__ accum, float* __restrict__ out) {
    out[0] = accum[0] / (float)NCELL;
}

// ---------------- host orchestration ----------------
extern "C" void kernel_launch(void* const* d_in, const int* in_sizes, int n_in,
                              void* d_out, int out_size, void* d_ws, size_t ws_size,
                              hipStream_t stream)
{
    const float* feats  = (const float*)d_in[0];
    const float* featsp = (const float*)d_in[1];
    const float* Wv11 = (const float*)d_in[2];
    const float* Wv12 = (const float*)d_in[3];
    const float* Wv21 = (const float*)d_in[4];
    const float* Wv22 = (const float*)d_in[5];
    const float* g11 = (const float*)d_in[6];
    const float* g12 = (const float*)d_in[7];
    const float* g21 = (const float*)d_in[8];
    const float* g22 = (const float*)d_in[9];
    const float* b11 = (const float*)d_in[10];
    const float* b12 = (const float*)d_in[11];
    const float* b21 = (const float*)d_in[12];
    const float* b22 = (const float*)d_in[13];
    const float* Wlog = (const float*)d_in[14];
    const float* blog = (const float*)d_in[15];
    const float* Wi  = (const float*)d_in[16];
    const float* bi  = (const float*)d_in[17];
    const float* Wp1 = (const float*)d_in[18];
    const float* bp1 = (const float*)d_in[19];
    const float* gp1 = (const float*)d_in[20];
    const float* bp1n = (const float*)d_in[21];
    const float* Wp2 = (const float*)d_in[22];
    const float* bp2 = (const float*)d_in[23];
    const float* gp2 = (const float*)d_in[24];
    const float* bp2n = (const float*)d_in[25];
    const float* Wp3 = (const float*)d_in[26];
    const float* bp3 = (const float*)d_in[27];
    const float* Wo1 = (const float*)d_in[28];
    const float* bo1 = (const float*)d_in[29];
    const float* Wo2 = (const float*)d_in[30];
    const float* bo2 = (const float*)d_in[31];
    const int* nbr   = (const int*)d_in[32];
    const int* nbrp  = (const int*)d_in[33];
    const int* coors = (const int*)d_in[34];
    const int* cil   = (const int*)d_in[35];
    const int* cin   = (const int*)d_in[36];
    const int* dsinv = (const int*)d_in[37];
    (void)in_sizes; (void)n_in; (void)out_size; (void)ws_size;

    // ---- ws layout (<= 47M floats; >=192 MB proven available) ----
    float* ws = (float*)d_ws;
    float* A     = ws;                  // 16M : conv fp32 out -> identity (live through layer_out)
    float* H     = ws + 16000000L;      // 16M : X1 fp32 -> feat_sum
    float* Hpf32 = ws + 32000000L;      //  8M : partial X1 residual (dead after partial chain)
    float* lob2  = ws + 32000000L;      //  lob R2: rows 500000..599999 (6.4M; reuses dead Hpf32)
    // CSR arrays (ints) in the Hpf32 tail, 38.4M..40M (written after partial chain)
    int* perm_cin   = (int*)(ws + 38400000L);   // 600k
    int* offs_cin   = (int*)(ws + 39000000L);   // 100k
    int* cursor_cin = (int*)(ws + 39100000L);   // 100k
    int* cnt_cin    = (int*)(ws + 39200000L);   // 100k
    int* perm_ds    = (int*)(ws + 39300000L);   // 250k
    int* offs_ds    = (int*)(ws + 39550000L);   // 100k
    int* cursor_ds  = (int*)(ws + 39650000L);   // 100k
    int* cnt_ds     = (int*)(ws + 39750000L);   // 100k
    int* bsum       = (int*)(ws + 39850000L);   // 256
    float* psum  = ws + 40000000L;      //  6.4M (slog table first, then segmean_lob output)
    float* slog  = psum;                //  3.375M floats (dead before segmean_lob writes psum)
    unsigned short* wt = (unsigned short*)(ws + 46500000L);  // 8 x 110592 fp16
    float* stats = ws + 46950000L;      //  10 x 256
    float* lacc  = ws + 46952560L;      //  1
    unsigned short* wh11 = wt + 0L * 110592;
    unsigned short* wl11 = wt + 1L * 110592;
    unsigned short* wh12 = wt + 2L * 110592;
    unsigned short* wl12 = wt + 3L * 110592;
    unsigned short* wh21 = wt + 4L * 110592;
    unsigned short* wl21 = wt + 5L * 110592;
    unsigned short* wh22 = wt + 6L * 110592;
    unsigned short* wl22 = wt + 7L * 110592;

    // ---- d_out as scratch (38.4M floats, fully overwritten by final gather) ----
    float* o = (float*)d_out;
    // conv-phase: full-tensor fp16 activations (single, 16M halves = 8M floats each)
    unsigned short* F0 = (unsigned short*)(o);
    unsigned short* F1 = (unsigned short*)(o + 8000000L);
    // partial-phase (after full convs done): 8M halves = 4M floats each
    unsigned short* P0 = (unsigned short*)(o);
    unsigned short* P1 = (unsigned short*)(o + 4000000L);
    float* Cp = o + 16000000L;          // 8M : Vp fp32 (slog input)
    // loss region (disjoint; dead once loss_reduce folds into lacc)
    float* xdense = o + 32000000L;      // 1.3824M
    int*   tflag  = (int*)(o + 33382400L);
    int*   winner = (int*)(o + 34764800L);
    float* logitb = o + 36147200L;      // 125k
    // post-conv phase
    float* dssum = o;                   // 6.4M (dead after Wp1 gemm)
    float* t1b   = o + 6400000L;        // 3.2M
    float* t2b   = o + 9600000L;        // 3.2M
    float* h3b   = o + 12800000L;       // 6.4M (live through layer_out)
    // lob regions (live layer_out -> segmean_lob; all prior tenants dead by then)
    float* lob0 = o;                    // rows 0..199999        (o+0 .. 12.8M)
    float* lob1 = o + 19200000L;        // rows 200000..499999   (o+19.2M .. 38.4M)
    float* out = (float*)d_out;

    auto cdiv = [](long a, long b) { return (unsigned)((a + b - 1) / b); };
    dim3 B256(256);

    // ---- inits ----
    fill_u32_kernel<<<cdiv(2561, 256), B256, 0, stream>>>((unsigned*)stats, 0u, 2561);
    fill_u32_kernel<<<cdiv(2764800, 256), B256, 0, stream>>>((unsigned*)xdense, 0u, 2764800);   // xdense+tflag
    fill_u32_kernel<<<cdiv(1382400, 256), B256, 0, stream>>>((unsigned*)winner, 0xFFFFFFFFu, 1382400);

    // ---- weight transpose + fp16 split ----
    wsplit_kernel<<<432, B256, 0, stream>>>(Wv11, wh11, wl11);
    wsplit_kernel<<<432, B256, 0, stream>>>(Wv12, wh12, wl12);
    wsplit_kernel<<<432, B256, 0, stream>>>(Wv21, wh21, wl21);
    wsplit_kernel<<<432, B256, 0, stream>>>(Wv22, wh22, wl22);

    // ---- full tensor chain (conv fuses colstats; X fp16 single) ----
    xhalf_kernel<<<cdiv(16000000, 256), B256, 0, stream>>>(feats, F0, 16000000L);
    conv_mfma_kernel<<<cdiv(NVOX, 128), B256, 0, stream>>>(F0, nbr, wh11, wl11, A, stats + 0 * 256, NVOX);
    mkscale_kernel<<<1, 64, 0, stream>>>(stats + 0 * 256, g11, b11, 1.0f / NVOX, 64);
    apply_bn_kernel<64, 1, 1, 0><<<cdiv(NVOX * 16L, 256), B256, 0, stream>>>(A, stats + 0 * 256, nullptr, nullptr, nullptr, F1, NVOX * 16L);
    conv_mfma_kernel<<<cdiv(NVOX, 128), B256, 0, stream>>>(F1, nbr, wh12, wl12, A, stats + 1 * 256, NVOX);
    mkscale_kernel<<<1, 64, 0, stream>>>(stats + 1 * 256, g12, b12, 1.0f / NVOX, 64);
    apply_bn_kernel<64, 2, 1, 1><<<cdiv(NVOX * 16L, 256), B256, 0, stream>>>(A, stats + 1 * 256, feats, nullptr, H, F0, NVOX * 16L);
    conv_mfma_kernel<<<cdiv(NVOX, 128), B256, 0, stream>>>(F0, nbr, wh21, wl21, A, stats + 2 * 256, NVOX);
    mkscale_kernel<<<1, 64, 0, stream>>>(stats + 2 * 256, g21, b21, 1.0f / NVOX, 64);
    apply_bn_kernel<64, 1, 1, 0><<<cdiv(NVOX * 16L, 256), B256, 0, stream>>>(A, stats + 2 * 256, nullptr, nullptr, nullptr, F1, NVOX * 16L);
    conv_mfma_kernel<<<cdiv(NVOX, 128), B256, 0, stream>>>(F1, nbr, wh22, wl22, A, stats + 3 * 256, NVOX);
    mkscale_kernel<<<1, 64, 0, stream>>>(stats + 3 * 256, g22, b22, 1.0f / NVOX, 64);
    apply_bn_kernel<64, 3, 0, 1><<<cdiv(NVOX * 16L, 256), B256, 0, stream>>>(A, stats + 3 * 256, H, feats, H, nullptr, NVOX * 16L);

    // ---- partial tensor chain (same weights) ----
    xhalf_kernel<<<cdiv(8000000, 256), B256, 0, stream>>>(featsp, P0, 8000000L);
    conv_mfma_kernel<<<cdiv(NPART, 128), B256, 0, stream>>>(P0, nbrp, wh11, wl11, A, stats + 4 * 256, NPART);
    mkscale_kernel<<<1, 64, 0, stream>>>(stats + 4 * 256, g11, b11, 1.0f / NPART, 64);
    apply_bn_kernel<64, 1, 1, 0><<<cdiv(NPART * 16L, 256), B256, 0, stream>>>(A, stats + 4 * 256, nullptr, nullptr, nullptr, P1, NPART * 16L);
    conv_mfma_kernel<<<cdiv(NPART, 128), B256, 0, stream>>>(P1, nbrp, wh12, wl12, A, stats + 5 * 256, NPART);
    mkscale_kernel<<<1, 64, 0, stream>>>(stats + 5 * 256, g12, b12, 1.0f / NPART, 64);
    apply_bn_kernel<64, 2, 1, 1><<<cdiv(NPART * 16L, 256), B256, 0, stream>>>(A, stats + 5 * 256, featsp, nullptr, Hpf32, P0, NPART * 16L);
    conv_mfma_kernel<<<cdiv(NPART, 128), B256, 0, stream>>>(P0, nbrp, wh21, wl21, A, stats + 6 * 256, NPART);
    mkscale_kernel<<<1, 64, 0, stream>>>(stats + 6 * 256, g21, b21, 1.0f / NPART, 64);
    apply_bn_kernel<64, 1, 1, 0><<<cdiv(NPART * 16L, 256), B256, 0, stream>>>(A, stats + 6 * 256, nullptr, nullptr, nullptr, P1, NPART * 16L);
    conv_mfma_kernel<<<cdiv(NPART, 128), B256, 0, stream>>>(P1, nbrp, wh22, wl22, A, stats + 7 * 256, NPART);
    mkscale_kernel<<<1, 64, 0, stream>>>(stats + 7 * 256, g22, b22, 1.0f / NPART, 64);
    apply_bn_kernel<64, 2, 0, 1><<<cdiv(NPART * 16L, 256), B256, 0, stream>>>(A, stats + 7 * 256, Hpf32, nullptr, Cp, nullptr, NPART * 16L);

    // ---- logits (pre-GEMM + scalar gather) + BCE loss ----
    slog_kernel<<<cdiv(NPART, 64), B256, 0, stream>>>(Cp, Wlog, slog, NPART);
    logit_gather_kernel<<<cdiv(NPART, 256), B256, 0, stream>>>(slog, nbrp, blog, logitb, NPART);
    loss_scatter1_kernel<<<cdiv(NVOX, 256), B256, 0, stream>>>(coors, tflag, winner, NVOX, NPART);
    loss_scatter2_kernel<<<cdiv(NPART, 256), B256, 0, stream>>>(coors, winner, logitb, xdense, NPART);
    loss_reduce_kernel<<<NCELL / 256, B256, 0, stream>>>(xdense, tflag, lacc);

    // ---- CSR builds for cin (NPTS->NNEXT) and dsinv (NVOX->NDS) ----
    fill_u32_kernel<<<cdiv(100000, 256), B256, 0, stream>>>((unsigned*)cnt_cin, 0u, 100000);
    fill_u32_kernel<<<cdiv(100000, 256), B256, 0, stream>>>((unsigned*)cnt_ds, 0u, 100000);
    hist_kernel<<<cdiv(NPTS, 256), B256, 0, stream>>>(cin, cnt_cin, NPTS);
    hist_kernel<<<cdiv(NVOX, 256), B256, 0, stream>>>(dsinv, cnt_ds, NVOX);
    scan_reduce_kernel<<<98, B256, 0, stream>>>(cnt_cin, bsum, 100000);
    scan_top_kernel<<<1, B256, 0, stream>>>(bsum, 98);
    scan_final_kernel<<<98, B256, 0, stream>>>(cnt_cin, bsum, offs_cin, cursor_cin, 100000);
    scan_reduce_kernel<<<98, B256, 0, stream>>>(cnt_ds, bsum, 100000);
    scan_top_kernel<<<1, B256, 0, stream>>>(bsum, 98);
    scan_final_kernel<<<98, B256, 0, stream>>>(cnt_ds, bsum, offs_ds, cursor_ds, 100000);
    place_kernel<<<cdiv(NPTS, 256), B256, 0, stream>>>(cin, cursor_cin, perm_cin, NPTS);
    place_kernel<<<cdiv(NVOX, 256), B256, 0, stream>>>(dsinv, cursor_ds, perm_ds, NVOX);

    // ---- point encoder ----
    segmean_kernel<<<cdiv(NDS, 4), B256, 0, stream>>>(H, perm_ds, offs_ds, cnt_ds, dssum, NDS);
    gemm_kernel<64, 64, 1><<<cdiv(NVOX, 64), B256, 0, stream>>>(H, Wi, bi, A, NVOX);   // A = identity

    gemm_kernel<64, 32, 1><<<cdiv(NDS, 128), B256, 0, stream>>>(dssum, Wp1, bp1, t1b, NDS);
    colstats_kernel<32><<<256, B256, 0, stream>>>(t1b, NDS, stats + 8 * 256);
    mkscale_kernel<<<1, 64, 0, stream>>>(stats + 8 * 256, gp1, bp1n, 1.0f / NDS, 32);
    apply_bn_kernel<32, 0, 0, 1><<<cdiv((long)NDS * 8, 256), B256, 0, stream>>>(t1b, stats + 8 * 256, nullptr, nullptr, t1b, nullptr, (long)NDS * 8);

    gemm_kernel<32, 32, 1><<<cdiv(NDS, 128), B256, 0, stream>>>(t1b, Wp2, bp2, t2b, NDS);
    colstats_kernel<32><<<256, B256, 0, stream>>>(t2b, NDS, stats + 9 * 256);
    mkscale_kernel<<<1, 64, 0, stream>>>(stats + 9 * 256, gp2, bp2n, 1.0f / NDS, 32);
    apply_bn_kernel<32, 0, 0, 1><<<cdiv((long)NDS * 8, 256), B256, 0, stream>>>(t2b, stats + 9 * 256, nullptr, nullptr, t2b, nullptr, (long)NDS * 8);

    gemm_kernel<32, 64, 1><<<cdiv(NDS, 64), B256, 0, stream>>>(t2b, Wp3, bp3, h3b, NDS);

    // ---- fused layer_out (coalesced lob rows, no atomics) + CSR segment-mean ----
    layer_out_fused_kernel<<<cdiv(NPTS, 64), B256, 0, stream>>>(A, h3b, cil, dsinv, Wo1, bo1, Wo2, bo2, lob0, lob1, lob2, NPTS);
    segmean_lob_kernel<<<cdiv(NNEXT, 4), B256, 0, stream>>>(lob0, lob1, lob2, perm_cin, offs_cin, cnt_cin, psum, NNEXT);

    // ---- final outputs ----
    gather_out_kernel<<<cdiv((long)NPTS * 16, 256), B256, 0, stream>>>(psum, cin, out, NPTS);
    loss_final_kernel<<<1, 1, 0, stream>>>(lacc, out + 38400000L);
}

// Round 9
// 2425.984 us; speedup vs baseline: 2.2784x; 1.0337x over previous
//
#include <hip/hip_runtime.h>
#include <math.h>

#define NVOX 250000
#define NPART 125000
#define NPTS 600000
#define NNEXT 100000
#define NDS 100000
#define NCELL 1382400

static __device__ __forceinline__ float lk(float x) { return x >= 0.f ? x : 0.1f * x; }

// fp16 helpers
static __device__ __forceinline__ unsigned short f2h(float f) {
    _Float16 h = (_Float16)f;
    return *(unsigned short*)&h;
}
static __device__ __forceinline__ float h2f(unsigned short u) {
    _Float16 h = *(_Float16*)&u;
    return (float)h;
}

typedef short v8s __attribute__((ext_vector_type(8)));       // 8x16-bit raw
typedef _Float16 v8h __attribute__((ext_vector_type(8)));    // 8 fp16 = 4 VGPR
typedef float v4f __attribute__((ext_vector_type(4)));       // MFMA acc
#define MFMAH __builtin_amdgcn_mfma_f32_16x16x32_f16

// lob 3-region row addressing (regions are dead buffers at layer_out time; see host layout)
static __device__ __forceinline__ float* lob_row(float* r0, float* r1, float* r2, int row) {
    if (row < 200000) return r0 + (size_t)row * 64;
    if (row < 500000) return r1 + (size_t)(row - 200000) * 64;
    return r2 + (size_t)(row - 500000) * 64;
}

// ---------------- fill ----------------
__global__ void fill_u32_kernel(unsigned* __restrict__ p, unsigned v, long n) {
    long i = (long)blockIdx.x * 256 + threadIdx.x;
    if (i < n) p[i] = v;
}

// ---------------- conv weight transpose + fp16 hi/lo split: Wt[k][d][c] ----------------
__global__ void wsplit_kernel(const float* __restrict__ W, unsigned short* __restrict__ hi,
                              unsigned short* __restrict__ lo) {
    int i = blockIdx.x * 256 + threadIdx.x;     // over 27*4096
    if (i < 27 * 4096) {
        int k = i >> 12, rem = i & 4095, d = rem >> 6, c = rem & 63;
        float w = W[k * 4096 + c * 64 + d];
        unsigned short h = f2h(w);
        hi[i] = h;
        lo[i] = f2h(w - h2f(h));
    }
}

// Wo1 [128][64] -> Wt[64][128] fp16 hi/lo
__global__ void wsplit_o1_kernel(const float* __restrict__ W, unsigned short* __restrict__ hi,
                                 unsigned short* __restrict__ lo) {
    int i = blockIdx.x * 256 + threadIdx.x;     // over 8192
    if (i < 8192) {
        int d = i >> 7, kk = i & 127;
        float w = W[kk * 64 + d];
        unsigned short h = f2h(w);
        hi[i] = h;
        lo[i] = f2h(w - h2f(h));
    }
}

// Wo2 [64][64] -> Wt[64][64] fp16 hi/lo
__global__ void wsplit_o2_kernel(const float* __restrict__ W, unsigned short* __restrict__ hi,
                                 unsigned short* __restrict__ lo) {
    int i = blockIdx.x * 256 + threadIdx.x;     // over 4096
    if (i < 4096) {
        int d = i >> 6, kk = i & 63;
        float w = W[kk * 64 + d];
        unsigned short h = f2h(w);
        hi[i] = h;
        lo[i] = f2h(w - h2f(h));
    }
}

// ---------------- activation fp16 convert ----------------
__global__ void xhalf_kernel(const float* __restrict__ X, unsigned short* __restrict__ out, long n) {
    long i = (long)blockIdx.x * 256 + threadIdx.x;
    if (i < n) out[i] = f2h(X[i]);
}

// ---------------- MFMA submanifold conv (v6: fp16-X single, fp16-W hi/lo in LDS) ----------------
__global__ __launch_bounds__(256) void conv_mfma_kernel(
    const unsigned short* __restrict__ Xh,
    const int* __restrict__ nbr,
    const unsigned short* __restrict__ Wthi, const unsigned short* __restrict__ Wtlo,
    float* __restrict__ Y, float* __restrict__ stats, int N)
{
    __shared__ __align__(16) unsigned short Wlds[2][8192];   // 2 bufs x (hi 8KB | lo 8KB) = 32 KB

    const int t = threadIdx.x;
    const int wave = t >> 6, lane = t & 63;
    const int m = lane & 15, q = lane >> 4;
    const int qo = q * 8;
    const long base = (long)blockIdx.x * 128 + wave * 32;

    long r0 = base + m;        // rowsub 0 A-row
    long r1 = base + 16 + m;   // rowsub 1 A-row
    long r0c = r0 < N ? r0 : (long)(N - 1);
    long r1c = r1 < N ? r1 : (long)(N - 1);
    const long o0g = r0c * 27, o1g = r1c * 27;

    const int zb = wave * 4096 + lane * 16;
    const int z0 = zb, z1 = zb + 1024, z2 = zb + 2048, z3 = zb + 3072;
    const int d0 = z0 ^ (((z0 >> 7) & 7) << 4);
    const int d1 = z1 ^ (((z1 >> 7) & 7) << 4);
    const int d2 = z2 ^ (((z2 >> 7) & 7) << 4);
    const int d3 = z3 ^ (((z3 >> 7) & 7) << 4);

    v4f acc[2][4];
    #pragma unroll
    for (int s = 0; s < 2; ++s)
        #pragma unroll
        for (int c = 0; c < 4; ++c)
            acc[s][c] = (v4f){0.f, 0.f, 0.f, 0.f};

    {
        const char* ghb = (const char*)Wthi;
        const char* glb = (const char*)Wtlo;
        v8s w0 = *(const v8s*)(z0 < 8192 ? ghb + z0 : glb + (z0 - 8192));
        v8s w1 = *(const v8s*)(z1 < 8192 ? ghb + z1 : glb + (z1 - 8192));
        v8s w2 = *(const v8s*)(z2 < 8192 ? ghb + z2 : glb + (z2 - 8192));
        v8s w3 = *(const v8s*)(z3 < 8192 ? ghb + z3 : glb + (z3 - 8192));
        char* lb = (char*)&Wlds[0][0];
        *(v8s*)(lb + d0) = w0; *(v8s*)(lb + d1) = w1;
        *(v8s*)(lb + d2) = w2; *(v8s*)(lb + d3) = w3;
    }
    __syncthreads();

    #pragma unroll 1
    for (int k = 0; k < 27; ++k) {
        const int cb = k & 1;
        const bool st = (k + 1 < 27);
        v8s w0, w1, w2, w3;
        if (st) {
            const char* ghb = (const char*)(Wthi + (size_t)(k + 1) * 4096);
            const char* glb = (const char*)(Wtlo + (size_t)(k + 1) * 4096);
            w0 = *(const v8s*)(z0 < 8192 ? ghb + z0 : glb + (z0 - 8192));
            w1 = *(const v8s*)(z1 < 8192 ? ghb + z1 : glb + (z1 - 8192));
            w2 = *(const v8s*)(z2 < 8192 ? ghb + z2 : glb + (z2 - 8192));
            w3 = *(const v8s*)(z3 < 8192 ? ghb + z3 : glb + (z3 - 8192));
        }
        int j0 = nbr[o0g + k];
        int j1 = nbr[o1g + k];
        const unsigned short* x0 = Xh + (size_t)j0 * 64;
        const unsigned short* x1 = Xh + (size_t)j1 * 64;
        v8h a00 = *(const v8h*)(x0 + qo);
        v8h a01 = *(const v8h*)(x0 + 32 + qo);
        v8h a10 = *(const v8h*)(x1 + qo);
        v8h a11 = *(const v8h*)(x1 + 32 + qo);
        const char* wb = (const char*)&Wlds[cb][0];
        const int sw = (m & 7) << 4;
        #pragma unroll
        for (int ct = 0; ct < 4; ++ct) {
            const int rowoff = (ct * 16 + m) * 128;
            v8h bh0 = *(const v8h*)(wb + rowoff + ((q * 16) ^ sw));
            v8h bh1 = *(const v8h*)(wb + rowoff + ((q * 16 + 64) ^ sw));
            v8h bl0 = *(const v8h*)(wb + 8192 + rowoff + ((q * 16) ^ sw));
            v8h bl1 = *(const v8h*)(wb + 8192 + rowoff + ((q * 16 + 64) ^ sw));
            acc[0][ct] = MFMAH(a00, bh0, acc[0][ct], 0, 0, 0);
            acc[0][ct] = MFMAH(a01, bh1, acc[0][ct], 0, 0, 0);
            acc[0][ct] = MFMAH(a00, bl0, acc[0][ct], 0, 0, 0);
            acc[0][ct] = MFMAH(a01, bl1, acc[0][ct], 0, 0, 0);
            acc[1][ct] = MFMAH(a10, bh0, acc[1][ct], 0, 0, 0);
            acc[1][ct] = MFMAH(a11, bh1, acc[1][ct], 0, 0, 0);
            acc[1][ct] = MFMAH(a10, bl0, acc[1][ct], 0, 0, 0);
            acc[1][ct] = MFMAH(a11, bl1, acc[1][ct], 0, 0, 0);
        }
        if (st) {
            char* lb = (char*)&Wlds[1 - cb][0];
            *(v8s*)(lb + d0) = w0; *(v8s*)(lb + d1) = w1;
            *(v8s*)(lb + d2) = w2; *(v8s*)(lb + d3) = w3;
        }
        __syncthreads();
    }

    #pragma unroll
    for (int s = 0; s < 2; ++s)
        #pragma unroll
        for (int ct = 0; ct < 4; ++ct)
            #pragma unroll
            for (int rg = 0; rg < 4; ++rg) {
                long r = base + s * 16 + q * 4 + rg;
                if (r < N) Y[r * 64 + ct * 16 + m] = acc[s][ct][rg];
            }

    // fused per-column stats (Wlds dead now; reuse as reduction scratch)
    float* shred = (float*)&Wlds[0][0];   // 128 floats: [0..63]=sum, [64..127]=sumsq
    if (t < 128) shred[t] = 0.f;
    __syncthreads();
    #pragma unroll
    for (int ct = 0; ct < 4; ++ct) {
        float s = 0.f, s2 = 0.f;
        #pragma unroll
        for (int ss = 0; ss < 2; ++ss)
            #pragma unroll
            for (int rg = 0; rg < 4; ++rg) {
                long r = base + ss * 16 + q * 4 + rg;
                if (r < N) { float v = acc[ss][ct][rg]; s += v; s2 += v * v; }
            }
        atomicAdd(&shred[ct * 16 + m], s);
        atomicAdd(&shred[64 + ct * 16 + m], s2);
    }
    __syncthreads();
    if (t < 64) {
        atomicAdd(&stats[t], shred[t]);
        atomicAdd(&stats[64 + t], shred[64 + t]);
    }
}

// ---------------- per-column sum / sumsq (PPmodel 32-ch paths only) ----------------
template<int CC>
__global__ __launch_bounds__(256) void colstats_kernel(const float* __restrict__ Y, int N, float* __restrict__ stats) {
    constexpr int RG = 256 / CC;
    const int t = threadIdx.x;
    const int c = t % CC, rg = t / CC;
    float s = 0.f, s2 = 0.f;
    for (long r = (long)blockIdx.x * RG + rg; r < N; r += (long)gridDim.x * RG) {
        float v = Y[r * CC + c];
        s += v; s2 += v * v;
    }
    __shared__ float sh[256], sh2[256];
    sh[t] = s; sh2[t] = s2;
    __syncthreads();
    if (t < CC) {
        #pragma unroll
        for (int g = 1; g < RG; ++g) { s += sh[g * CC + t]; s2 += sh2[g * CC + t]; }
        atomicAdd(&stats[t], s);
        atomicAdd(&stats[CC + t], s2);
    }
}

__global__ void mkscale_kernel(float* __restrict__ stats, const float* __restrict__ g,
                               const float* __restrict__ b, float invN, int CC) {
    int c = threadIdx.x;
    if (c < CC) {
        float mu = stats[c] * invN;
        float var = stats[CC + c] * invN - mu * mu;
        float sc = g[c] * rsqrtf(var + 1e-5f);
        stats[2 * CC + c] = sc;
        stats[3 * CC + c] = b[c] - mu * sc;
    }
}

// MODE: 0 = y*s+sh ; 1 = leaky(y*s+sh) ; 2 = leaky(y*s+sh + res) ; 3 = res2 + leaky(y*s+sh + res)
// PAIR: also emit fp16 of the result. WOUT: write the fp32 result (0 = dead store, skip)
template<int CC, int MODE, int PAIR, int WOUT>
__global__ __launch_bounds__(256) void apply_bn_kernel(
    const float* __restrict__ Yin, const float* __restrict__ stats,
    const float* __restrict__ res, const float* __restrict__ res2,
    float* __restrict__ out, unsigned short* __restrict__ ohalf, long n4)
{
    long i = (long)blockIdx.x * 256 + threadIdx.x;
    if (i >= n4) return;
    int c4 = (int)(i % (CC / 4)) * 4;
    float4 y = ((const float4*)Yin)[i];
    float4 sc = *(const float4*)(stats + 2 * CC + c4);
    float4 sf = *(const float4*)(stats + 3 * CC + c4);
    float x0 = y.x * sc.x + sf.x;
    float x1 = y.y * sc.y + sf.y;
    float x2 = y.z * sc.z + sf.z;
    float x3 = y.w * sc.w + sf.w;
    if (MODE >= 2) {
        float4 rr = ((const float4*)res)[i];
        x0 += rr.x; x1 += rr.y; x2 += rr.z; x3 += rr.w;
    }
    if (MODE >= 1) { x0 = lk(x0); x1 = lk(x1); x2 = lk(x2); x3 = lk(x3); }
    if (MODE == 3) {
        float4 rr2 = ((const float4*)res2)[i];
        x0 += rr2.x; x1 += rr2.y; x2 += rr2.z; x3 += rr2.w;
    }
    if (WOUT) ((float4*)out)[i] = make_float4(x0, x1, x2, x3);
    if (PAIR) {
        ushort4 h;
        h.x = f2h(x0); h.y = f2h(x1); h.z = f2h(x2); h.w = f2h(x3);
        *(ushort4*)(ohalf + i * 4) = h;
    }
}

// ---------------- generic tiled GEMM: Y = act(X[N,CIN] @ W[CIN,COUT] + bias) ----------------
// H16: store output as fp16 (ushort) instead of fp32
template<int CIN, int COUT, int ACT, int H16>
__global__ __launch_bounds__(256) void gemm_kernel(
    const float* __restrict__ X, const float* __restrict__ W,
    const float* __restrict__ bias, void* __restrict__ Yv, int N)
{
    constexpr int TX = COUT / 4;
    constexpr int TY = 256 / TX;
    constexpr int ROWS = TY * 4;
    constexpr int CHUNK = (CIN < 64) ? CIN : 64;
    constexpr int NCH = CIN / CHUNK;
    __shared__ float XsT[CHUNK][ROWS + 4];
    __shared__ float Ws[CHUNK][COUT + 4];
    const int t = threadIdx.x;
    const int row0 = blockIdx.x * ROWS;
    const int ty = t / TX, tx = t % TX;
    float acc[4][4] = {{0.f}};
    for (int cc = 0; cc < NCH; ++cc) {
        __syncthreads();
        for (int i = t * 4; i < CHUNK * COUT; i += 1024) {
            int c = i / COUT, d = i % COUT;
            *(float4*)&Ws[c][d] = *(const float4*)(W + (size_t)(cc * CHUNK + c) * COUT + d);
        }
        for (int i = t * 4; i < ROWS * CHUNK; i += 1024) {
            int r = i / CHUNK, c0 = i % CHUNK;
            int gr = row0 + r;
            float4 v = make_float4(0.f, 0.f, 0.f, 0.f);
            if (gr < N) v = *(const float4*)(X + (size_t)gr * CIN + cc * CHUNK + c0);
            XsT[c0 + 0][r] = v.x; XsT[c0 + 1][r] = v.y; XsT[c0 + 2][r] = v.z; XsT[c0 + 3][r] = v.w;
        }
        __syncthreads();
        #pragma unroll 8
        for (int c = 0; c < CHUNK; ++c) {
            float4 xv = *(const float4*)&XsT[c][ty * 4];
            float4 wv = *(const float4*)&Ws[c][tx * 4];
            acc[0][0] += xv.x * wv.x; acc[0][1] += xv.x * wv.y; acc[0][2] += xv.x * wv.z; acc[0][3] += xv.x * wv.w;
            acc[1][0] += xv.y * wv.x; acc[1][1] += xv.y * wv.y; acc[1][2] += xv.y * wv.z; acc[1][3] += xv.y * wv.w;
            acc[2][0] += xv.z * wv.x; acc[2][1] += xv.z * wv.y; acc[2][2] += xv.z * wv.z; acc[2][3] += xv.z * wv.w;
            acc[3][0] += xv.w * wv.x; acc[3][1] += xv.w * wv.y; acc[3][2] += xv.w * wv.z; acc[3][3] += xv.w * wv.w;
        }
    }
    float4 bv = *(const float4*)(bias + tx * 4);
    #pragma unroll
    for (int i2 = 0; i2 < 4; ++i2) {
        int gr = row0 + ty * 4 + i2;
        if (gr < N) {
            float o0 = acc[i2][0] + bv.x, o1 = acc[i2][1] + bv.y;
            float o2 = acc[i2][2] + bv.z, o3 = acc[i2][3] + bv.w;
            if (ACT) { o0 = lk(o0); o1 = lk(o1); o2 = lk(o2); o3 = lk(o3); }
            if (H16) {
                ushort4 h;
                h.x = f2h(o0); h.y = f2h(o1); h.z = f2h(o2); h.w = f2h(o3);
                *(ushort4*)((unsigned short*)Yv + (size_t)gr * COUT + tx * 4) = h;
            } else {
                *(float4*)((float*)Yv + (size_t)gr * COUT + tx * 4) = make_float4(o0, o1, o2, o3);
            }
        }
    }
}

// ---------------- CSR build: histogram -> 2-level exclusive scan -> stable place ----------------
__global__ void hist_kernel(const int* __restrict__ idx, int* __restrict__ cnt, int n) {
    int i = blockIdx.x * 256 + threadIdx.x;
    if (i < n) atomicAdd(&cnt[idx[i]], 1);
}

__global__ void scan_reduce_kernel(const int* __restrict__ cnt, int* __restrict__ bsum, int T) {
    __shared__ int sh[256];
    const int b = blockIdx.x, t = threadIdx.x;
    int s = 0;
    #pragma unroll
    for (int u = 0; u < 4; ++u) {
        int i = b * 1024 + u * 256 + t;
        if (i < T) s += cnt[i];
    }
    sh[t] = s; __syncthreads();
    for (int st = 128; st > 0; st >>= 1) { if (t < st) sh[t] += sh[t + st]; __syncthreads(); }
    if (t == 0) bsum[b] = sh[0];
}

__global__ void scan_top_kernel(int* __restrict__ bsum, int nb) {
    __shared__ int sh[256];
    const int t = threadIdx.x;
    sh[t] = (t < nb) ? bsum[t] : 0;
    __syncthreads();
    if (t == 0) {
        int run = 0;
        for (int i = 0; i < nb; ++i) { int v = sh[i]; sh[i] = run; run += v; }
    }
    __syncthreads();
    if (t < nb) bsum[t] = sh[t];
}

__global__ void scan_final_kernel(const int* __restrict__ cnt, const int* __restrict__ bsum,
                                  int* __restrict__ offs, int* __restrict__ cursor, int T) {
    __shared__ int sh[256];
    const int b = blockIdx.x, t = threadIdx.x;
    const int i0 = b * 1024 + t * 4;
    int v0 = 0, v1 = 0, v2 = 0, v3 = 0;
    if (i0 + 0 < T) v0 = cnt[i0 + 0];
    if (i0 + 1 < T) v1 = cnt[i0 + 1];
    if (i0 + 2 < T) v2 = cnt[i0 + 2];
    if (i0 + 3 < T) v3 = cnt[i0 + 3];
    const int tot = v0 + v1 + v2 + v3;
    sh[t] = tot; __syncthreads();
    for (int st = 1; st < 256; st <<= 1) {
        int x = (t >= st) ? sh[t - st] : 0;
        __syncthreads();
        sh[t] += x;
        __syncthreads();
    }
    int ex = sh[t] - tot + bsum[b];
    if (i0 + 0 < T) { offs[i0 + 0] = ex; cursor[i0 + 0] = ex; } ex += v0;
    if (i0 + 1 < T) { offs[i0 + 1] = ex; cursor[i0 + 1] = ex; } ex += v1;
    if (i0 + 2 < T) { offs[i0 + 2] = ex; cursor[i0 + 2] = ex; } ex += v2;
    if (i0 + 3 < T) { offs[i0 + 3] = ex; cursor[i0 + 3] = ex; }
}

__global__ void place_kernel(const int* __restrict__ idx, int* __restrict__ cursor,
                             int* __restrict__ perm, int n) {
    int i = blockIdx.x * 256 + threadIdx.x;
    if (i < n) { int p = atomicAdd(&cursor[idx[i]], 1); perm[p] = i; }
}

// ---------------- segment mean via CSR (no atomics): 1 wave per target, lane = channel ----------------
__global__ __launch_bounds__(256) void segmean_kernel(
    const float* __restrict__ src, const int* __restrict__ perm,
    const int* __restrict__ offs, const int* __restrict__ cnt,
    float* __restrict__ dst, int T)
{
    const int wave = threadIdx.x >> 6, lane = threadIdx.x & 63;
    const int tg = blockIdx.x * 4 + wave;
    if (tg >= T) return;
    const int o = offs[tg], c = cnt[tg];
    float acc = 0.f;
    for (int j = 0; j < c; ++j) {
        int r = perm[o + j];
        acc += src[(size_t)r * 64 + lane];
    }
    dst[(size_t)tg * 64 + lane] = acc / fmaxf((float)c, 1.0f);
}

__global__ __launch_bounds__(256) void segmean_lob_kernel(
    float* __restrict__ l0, float* __restrict__ l1, float* __restrict__ l2,
    const int* __restrict__ perm, const int* __restrict__ offs, const int* __restrict__ cnt,
    float* __restrict__ dst, int T)
{
    const int wave = threadIdx.x >> 6, lane = threadIdx.x & 63;
    const int tg = blockIdx.x * 4 + wave;
    if (tg >= T) return;
    const int o = offs[tg], c = cnt[tg];
    float acc = 0.f;
    for (int j = 0; j < c; ++j) {
        int r = perm[o + j];
        acc += lob_row(l0, l1, l2, r)[lane];
    }
    dst[(size_t)tg * 64 + lane] = acc / fmaxf((float)c, 1.0f);
}

// ---------------- layer_out via MFMA (v2): fp16 gathered inputs, fp16 hi/lo weights ----------------
// Block = 4 waves x 16 rows = 64 points. GEMM1: cat128 @ Wo1 (K=128), leaky -> per-wave LDS fp16 tile
// -> GEMM2: @ Wo2 (K=64) -> lob rows. Fragment geometry mirrors conv (lane m = A-row/C-col, q = k-chunk).
// LDS rows padded (+8 fp16) so worst-case aliasing is 2-way (free); replaces the VALU GEMM's 1.08e7 conflicts.
__global__ __launch_bounds__(256) void layer_out_mfma_kernel(
    const unsigned short* __restrict__ Ah,     // [NVOX][64] fp16 identity
    const unsigned short* __restrict__ h3h,    // [NDS][64] fp16 h3
    const int* __restrict__ cil, const int* __restrict__ dsinv,
    const unsigned short* __restrict__ W1hi, const unsigned short* __restrict__ W1lo,  // [64][128]
    const unsigned short* __restrict__ W2hi, const unsigned short* __restrict__ W2lo,  // [64][64]
    const float* __restrict__ bo1, const float* __restrict__ bo2,
    float* __restrict__ lob0, float* __restrict__ lob1, float* __restrict__ lob2, int N)
{
    __shared__ __align__(16) _Float16 W1s[2][64][136];  // 34816 B (hi, lo)
    __shared__ __align__(16) _Float16 W2s[2][64][72];   // 18432 B
    __shared__ __align__(16) _Float16 hs[4][16][72];    //  9216 B (per-wave intermediate)

    const int t = threadIdx.x;
    // stage W1 (each buf 64 rows x 128 fp16 = 1024 chunks of 8)
    for (int i = t; i < 1024; i += 256) {
        int r = i >> 4, c8 = (i & 15) * 8;
        *(v8h*)&W1s[0][r][c8] = *(const v8h*)(W1hi + r * 128 + c8);
        *(v8h*)&W1s[1][r][c8] = *(const v8h*)(W1lo + r * 128 + c8);
    }
    // stage W2 (each buf 64 rows x 64 fp16 = 512 chunks of 8)
    for (int i = t; i < 512; i += 256) {
        int r = i >> 3, c8 = (i & 7) * 8;
        *(v8h*)&W2s[0][r][c8] = *(const v8h*)(W2hi + r * 64 + c8);
        *(v8h*)&W2s[1][r][c8] = *(const v8h*)(W2lo + r * 64 + c8);
    }
    __syncthreads();

    const int wave = t >> 6, lane = t & 63;
    const int m = lane & 15, q = lane >> 4;
    const int row0 = blockIdx.x * 64 + wave * 16;

    // gather my A-row (row = m within the wave's 16)
    int gr = row0 + m;
    int grc = gr < N ? gr : N - 1;
    int v = cil[grc];
    int vds = dsinv[v];
    const unsigned short* arow = Ah + (size_t)v * 64;
    const unsigned short* hrow = h3h + (size_t)vds * 64;
    v8h a0 = *(const v8h*)(arow + q * 8);        // k = 0..31 chunk
    v8h a1 = *(const v8h*)(arow + 32 + q * 8);   // k = 32..63
    v8h a2 = *(const v8h*)(hrow + q * 8);        // k = 64..95
    v8h a3 = *(const v8h*)(hrow + 32 + q * 8);   // k = 96..127

    // GEMM1: 16x64, K=128 -> 4 ct x 4 ks x 2 (hi/lo) = 32 MFMAs
    v4f acc1[4];
    #pragma unroll
    for (int ct = 0; ct < 4; ++ct) acc1[ct] = (v4f){0.f, 0.f, 0.f, 0.f};
    #pragma unroll
    for (int ct = 0; ct < 4; ++ct) {
        const int d = ct * 16 + m;
        v8h b0h = *(const v8h*)&W1s[0][d][q * 8];
        v8h b1h = *(const v8h*)&W1s[0][d][32 + q * 8];
        v8h b2h = *(const v8h*)&W1s[0][d][64 + q * 8];
        v8h b3h = *(const v8h*)&W1s[0][d][96 + q * 8];
        v8h b0l = *(const v8h*)&W1s[1][d][q * 8];
        v8h b1l = *(const v8h*)&W1s[1][d][32 + q * 8];
        v8h b2l = *(const v8h*)&W1s[1][d][64 + q * 8];
        v8h b3l = *(const v8h*)&W1s[1][d][96 + q * 8];
        acc1[ct] = MFMAH(a0, b0h, acc1[ct], 0, 0, 0);
        acc1[ct] = MFMAH(a1, b1h, acc1[ct], 0, 0, 0);
        acc1[ct] = MFMAH(a2, b2h, acc1[ct], 0, 0, 0);
        acc1[ct] = MFMAH(a3, b3h, acc1[ct], 0, 0, 0);
        acc1[ct] = MFMAH(a0, b0l, acc1[ct], 0, 0, 0);
        acc1[ct] = MFMAH(a1, b1l, acc1[ct], 0, 0, 0);
        acc1[ct] = MFMAH(a2, b2l, acc1[ct], 0, 0, 0);
        acc1[ct] = MFMAH(a3, b3l, acc1[ct], 0, 0, 0);
    }
    // bias + leaky -> per-wave fp16 tile (C/D layout: col = ct*16+m, row = q*4+rg)
    #pragma unroll
    for (int ct = 0; ct < 4; ++ct) {
        const int col = ct * 16 + m;
        const float b1 = bo1[col];
        #pragma unroll
        for (int rg = 0; rg < 4; ++rg)
            hs[wave][q * 4 + rg][col] = (_Float16)lk(acc1[ct][rg] + b1);
    }
    __syncthreads();

    // GEMM2: 16x64, K=64 -> 4 ct x 2 ks x 2 = 16 MFMAs; A from hs (row = m)
    v8h c0 = *(const v8h*)&hs[wave][m][q * 8];
    v8h c1 = *(const v8h*)&hs[wave][m][32 + q * 8];
    v4f acc2[4];
    #pragma unroll
    for (int ct = 0; ct < 4; ++ct) acc2[ct] = (v4f){0.f, 0.f, 0.f, 0.f};
    #pragma unroll
    for (int ct = 0; ct < 4; ++ct) {
        const int d = ct * 16 + m;
        v8h d0h = *(const v8h*)&W2s[0][d][q * 8];
        v8h d1h = *(const v8h*)&W2s[0][d][32 + q * 8];
        v8h d0l = *(const v8h*)&W2s[1][d][q * 8];
        v8h d1l = *(const v8h*)&W2s[1][d][32 + q * 8];
        acc2[ct] = MFMAH(c0, d0h, acc2[ct], 0, 0, 0);
        acc2[ct] = MFMAH(c1, d1h, acc2[ct], 0, 0, 0);
        acc2[ct] = MFMAH(c0, d0l, acc2[ct], 0, 0, 0);
        acc2[ct] = MFMAH(c1, d1l, acc2[ct], 0, 0, 0);
    }
    // store to lob rows
    #pragma unroll
    for (int ct = 0; ct < 4; ++ct) {
        const int col = ct * 16 + m;
        const float b2 = bo2[col];
        #pragma unroll
        for (int rg = 0; rg < 4; ++rg) {
            int r = row0 + q * 4 + rg;
            if (r < N) lob_row(lob0, lob1, lob2, r)[col] = acc2[ct][rg] + b2;
        }
    }
}

__global__ void gather_out_kernel(const float* __restrict__ pf, const int* __restrict__ cin,
                                  float* __restrict__ out, int N) {
    long i = (long)blockIdx.x * 256 + threadIdx.x;
    if (i < (long)N * 16) {
        int p = (int)(i >> 4), q = (int)(i & 15);
        ((float4*)out)[i] = *(const float4*)(pf + (size_t)cin[p] * 64 + q * 4);
    }
}

// ---------------- logit via pre-GEMM: s[j,k] = dot(Cp[j,:], Wlog[k,:]) ----------------
__global__ __launch_bounds__(256) void slog_kernel(
    const float* __restrict__ Cp, const float* __restrict__ Wlog,
    float* __restrict__ s, int N)
{
    __shared__ float CpS[64][65];
    __shared__ float WlS[27][65];
    const int t = threadIdx.x;
    const int j0 = blockIdx.x * 64;
    for (int i = t; i < 1728; i += 256) WlS[i / 64][i % 64] = Wlog[i];
    for (int i = t; i < 1024; i += 256) {            // 64 rows x 16 float4
        int r = i >> 4, c4 = (i & 15) * 4;
        int gj = j0 + r;
        float4 v = make_float4(0.f, 0.f, 0.f, 0.f);
        if (gj < N) v = *(const float4*)(Cp + (size_t)gj * 64 + c4);
        CpS[r][c4 + 0] = v.x; CpS[r][c4 + 1] = v.y; CpS[r][c4 + 2] = v.z; CpS[r][c4 + 3] = v.w;
    }
    __syncthreads();
    for (int i = t; i < 64 * 27; i += 256) {
        int r = i / 27, k = i % 27;
        int gj = j0 + r;
        if (gj < N) {
            float acc = 0.f;
            #pragma unroll 16
            for (int c = 0; c < 64; ++c) acc += CpS[r][c] * WlS[k][c];
            s[(size_t)gj * 27 + k] = acc;
        }
    }
}

// logit[n] = blog + sum_k s[nbr[n,k]*27 + k]
__global__ void logit_gather_kernel(const float* __restrict__ s, const int* __restrict__ nbrp,
                                    const float* __restrict__ blog, float* __restrict__ out, int N) {
    int n = blockIdx.x * 256 + threadIdx.x;
    if (n < N) {
        float acc = blog[0];
        #pragma unroll
        for (int k = 0; k < 27; ++k) {
            int j = nbrp[(size_t)n * 27 + k];
            acc += s[(size_t)j * 27 + k];
        }
        out[n] = acc;
    }
}

// ---------------- loss ----------------
__global__ void loss_scatter1_kernel(const int* __restrict__ coors, int* __restrict__ tflag,
                                     int* __restrict__ winner, int N, int NP) {
    int n = blockIdx.x * 256 + threadIdx.x;
    if (n < N) {
        int b = coors[n * 4], x = coors[n * 4 + 1], y = coors[n * 4 + 2], z = coors[n * 4 + 3];
        int flat = ((b * 240 + x) * 180 + y) * 16 + z;
        tflag[flat] = 1;
        if (n < NP) atomicMax(&winner[flat], n);
    }
}

__global__ void loss_scatter2_kernel(const int* __restrict__ coors, const int* __restrict__ winner,
                                     const float* __restrict__ logit, float* __restrict__ xdense, int NP) {
    int n = blockIdx.x * 256 + threadIdx.x;
    if (n < NP) {
        int b = coors[n * 4], x = coors[n * 4 + 1], y = coors[n * 4 + 2], z = coors[n * 4 + 3];
        int flat = ((b * 240 + x) * 180 + y) * 16 + z;
        if (winner[flat] == n) xdense[flat] = logit[n];
    }
}

__global__ void loss_reduce_kernel(const float* __restrict__ xdense, const int* __restrict__ tflag,
                                   float* __restrict__ accum) {
    int i = blockIdx.x * 256 + threadIdx.x;
    float x = xdense[i];
    float tt = (float)tflag[i];
    float term = fmaxf(x, 0.f) - x * tt + log1pf(expf(-fabsf(x)));
    __shared__ float sh[256];
    sh[threadIdx.x] = term;
    __syncthreads();
    for (int s = 128; s > 0; s >>= 1) {
        if (threadIdx.x < s) sh[threadIdx.x] += sh[threadIdx.x + s];
        __syncthreads();
    }
    if (threadIdx.x == 0) atomicAdd(accum, sh[0]);
}

__global__ void loss_final_kernel(const float* __restrict__ accum, float* __restrict__ out) {
    out[0] = accum[0] / (float)NCELL;
}

// ---------------- host orchestration ----------------
extern "C" void kernel_launch(void* const* d_in, const int* in_sizes, int n_in,
                              void* d_out, int out_size, void* d_ws, size_t ws_size,
                              hipStream_t stream)
{
    const float* feats  = (const float*)d_in[0];
    const float* featsp = (const float*)d_in[1];
    const float* Wv11 = (const float*)d_in[2];
    const float* Wv12 = (const float*)d_in[3];
    const float* Wv21 = (const float*)d_in[4];
    const float* Wv22 = (const float*)d_in[5];
    const float* g11 = (const float*)d_in[6];
    const float* g12 = (const float*)d_in[7];
    const float* g21 = (const float*)d_in[8];
    const float* g22 = (const float*)d_in[9];
    const float* b11 = (const float*)d_in[10];
    const float* b12 = (const float*)d_in[11];
    const float* b21 = (const float*)d_in[12];
    const float* b22 = (const float*)d_in[13];
    const float* Wlog = (const float*)d_in[14];
    const float* blog = (const float*)d_in[15];
    const float* Wi  = (const float*)d_in[16];
    const float* bi  = (const float*)d_in[17];
    const float* Wp1 = (const float*)d_in[18];
    const float* bp1 = (const float*)d_in[19];
    const float* gp1 = (const float*)d_in[20];
    const float* bp1n = (const float*)d_in[21];
    const float* Wp2 = (const float*)d_in[22];
    const float* bp2 = (const float*)d_in[23];
    const float* gp2 = (const float*)d_in[24];
    const float* bp2n = (const float*)d_in[25];
    const float* Wp3 = (const float*)d_in[26];
    const float* bp3 = (const float*)d_in[27];
    const float* Wo1 = (const float*)d_in[28];
    const float* bo1 = (const float*)d_in[29];
    const float* Wo2 = (const float*)d_in[30];
    const float* bo2 = (const float*)d_in[31];
    const int* nbr   = (const int*)d_in[32];
    const int* nbrp  = (const int*)d_in[33];
    const int* coors = (const int*)d_in[34];
    const int* cil   = (const int*)d_in[35];
    const int* cin   = (const int*)d_in[36];
    const int* dsinv = (const int*)d_in[37];
    (void)in_sizes; (void)n_in; (void)out_size; (void)ws_size;

    // ---- ws layout (<= 47M floats; >=192 MB proven available) ----
    float* ws = (float*)d_ws;
    float* A     = ws;                  // 16M : conv fp32 out (conv phase); dead after Cp -> Ah reuses
    unsigned short* Ah = (unsigned short*)ws;   // fp16 identity [NVOX][64] (8M floats), written by Wi gemm
    float* H     = ws + 16000000L;      // 16M : X1 fp32 -> feat_sum (dead after segmean_ds + Wi gemm)
    float* Hpf32 = ws + 32000000L;      //  8M : partial X1 residual (dead after partial chain)
    float* lob2  = ws + 32000000L;      //  lob R2: rows 500000..599999 (6.4M; reuses dead Hpf32)
    // CSR arrays (ints) in the Hpf32 tail, 38.4M..40M (written after partial chain)
    int* perm_cin   = (int*)(ws + 38400000L);   // 600k
    int* offs_cin   = (int*)(ws + 39000000L);   // 100k
    int* cursor_cin = (int*)(ws + 39100000L);   // 100k
    int* cnt_cin    = (int*)(ws + 39200000L);   // 100k
    int* perm_ds    = (int*)(ws + 39300000L);   // 250k
    int* offs_ds    = (int*)(ws + 39550000L);   // 100k
    int* cursor_ds  = (int*)(ws + 39650000L);   // 100k
    int* cnt_ds     = (int*)(ws + 39750000L);   // 100k
    int* bsum       = (int*)(ws + 39850000L);   // 256
    float* psum  = ws + 40000000L;      //  6.4M (slog table first, then segmean_lob output)
    float* slog  = psum;                //  3.375M floats (dead before segmean_lob writes psum)
    // layer_out transposed fp16 weights at 46.4M (free gap; written at launch start, read at layer_out)
    unsigned short* wo = (unsigned short*)(ws + 46400000L);
    unsigned short* wo1hi = wo;                 // 8192 halves
    unsigned short* wo1lo = wo + 8192;
    unsigned short* wo2hi = wo + 16384;         // 4096 halves
    unsigned short* wo2lo = wo + 20480;         // ends 24576 halves = 12288 floats < 100k gap
    unsigned short* wt = (unsigned short*)(ws + 46500000L);  // 8 x 110592 fp16
    float* stats = ws + 46950000L;      //  10 x 256
    float* lacc  = ws + 46952560L;      //  1
    unsigned short* wh11 = wt + 0L * 110592;
    unsigned short* wl11 = wt + 1L * 110592;
    unsigned short* wh12 = wt + 2L * 110592;
    unsigned short* wl12 = wt + 3L * 110592;
    unsigned short* wh21 = wt + 4L * 110592;
    unsigned short* wl21 = wt + 5L * 110592;
    unsigned short* wh22 = wt + 6L * 110592;
    unsigned short* wl22 = wt + 7L * 110592;

    // ---- d_out as scratch (38.4M floats, fully overwritten by final gather) ----
    float* o = (float*)d_out;
    // conv-phase: full-tensor fp16 activations (single, 16M halves = 8M floats each)
    unsigned short* F0 = (unsigned short*)(o);
    unsigned short* F1 = (unsigned short*)(o + 8000000L);
    // partial-phase (after full convs done): 8M halves = 4M floats each
    unsigned short* P0 = (unsigned short*)(o);
    unsigned short* P1 = (unsigned short*)(o + 4000000L);
    float* Cp = o + 16000000L;          // 8M : Vp fp32 (slog input)
    // loss region (disjoint; dead once loss_reduce folds into lacc)
    float* xdense = o + 32000000L;      // 1.3824M
    int*   tflag  = (int*)(o + 33382400L);
    int*   winner = (int*)(o + 34764800L);
    float* logitb = o + 36147200L;      // 125k
    // post-conv phase
    float* dssum = o;                   // 6.4M (dead after Wp1 gemm)
    float* t1b   = o + 6400000L;        // 3.2M
    float* t2b   = o + 9600000L;        // 3.2M
    unsigned short* h3h = (unsigned short*)(o + 12800000L);  // fp16 h3 [NDS][64] (3.2M floats), live thru layer_out
    // lob regions (live layer_out -> segmean_lob; all prior tenants dead by then)
    float* lob0 = o;                    // rows 0..199999        (o+0 .. 12.8M)
    float* lob1 = o + 19200000L;        // rows 200000..499999   (o+19.2M .. 38.4M)
    float* out = (float*)d_out;

    auto cdiv = [](long a, long b) { return (unsigned)((a + b - 1) / b); };
    dim3 B256(256);

    // ---- inits ----
    fill_u32_kernel<<<cdiv(2561, 256), B256, 0, stream>>>((unsigned*)stats, 0u, 2561);
    fill_u32_kernel<<<cdiv(2764800, 256), B256, 0, stream>>>((unsigned*)xdense, 0u, 2764800);   // xdense+tflag
    fill_u32_kernel<<<cdiv(1382400, 256), B256, 0, stream>>>((unsigned*)winner, 0xFFFFFFFFu, 1382400);

    // ---- weight transpose + fp16 splits ----
    wsplit_kernel<<<432, B256, 0, stream>>>(Wv11, wh11, wl11);
    wsplit_kernel<<<432, B256, 0, stream>>>(Wv12, wh12, wl12);
    wsplit_kernel<<<432, B256, 0, stream>>>(Wv21, wh21, wl21);
    wsplit_kernel<<<432, B256, 0, stream>>>(Wv22, wh22, wl22);
    wsplit_o1_kernel<<<32, B256, 0, stream>>>(Wo1, wo1hi, wo1lo);
    wsplit_o2_kernel<<<16, B256, 0, stream>>>(Wo2, wo2hi, wo2lo);

    // ---- full tensor chain (conv fuses colstats; X fp16 single) ----
    xhalf_kernel<<<cdiv(16000000, 256), B256, 0, stream>>>(feats, F0, 16000000L);
    conv_mfma_kernel<<<cdiv(NVOX, 128), B256, 0, stream>>>(F0, nbr, wh11, wl11, A, stats + 0 * 256, NVOX);
    mkscale_kernel<<<1, 64, 0, stream>>>(stats + 0 * 256, g11, b11, 1.0f / NVOX, 64);
    apply_bn_kernel<64, 1, 1, 0><<<cdiv(NVOX * 16L, 256), B256, 0, stream>>>(A, stats + 0 * 256, nullptr, nullptr, nullptr, F1, NVOX * 16L);
    conv_mfma_kernel<<<cdiv(NVOX, 128), B256, 0, stream>>>(F1, nbr, wh12, wl12, A, stats + 1 * 256, NVOX);
    mkscale_kernel<<<1, 64, 0, stream>>>(stats + 1 * 256, g12, b12, 1.0f / NVOX, 64);
    apply_bn_kernel<64, 2, 1, 1><<<cdiv(NVOX * 16L, 256), B256, 0, stream>>>(A, stats + 1 * 256, feats, nullptr, H, F0, NVOX * 16L);
    conv_mfma_kernel<<<cdiv(NVOX, 128), B256, 0, stream>>>(F0, nbr, wh21, wl21, A, stats + 2 * 256, NVOX);
    mkscale_kernel<<<1, 64, 0, stream>>>(stats + 2 * 256, g21, b21, 1.0f / NVOX, 64);
    apply_bn_kernel<64, 1, 1, 0><<<cdiv(NVOX * 16L, 256), B256, 0, stream>>>(A, stats + 2 * 256, nullptr, nullptr, nullptr, F1, NVOX * 16L);
    conv_mfma_kernel<<<cdiv(NVOX, 128), B256, 0, stream>>>(F1, nbr, wh22, wl22, A, stats + 3 * 256, NVOX);
    mkscale_kernel<<<1, 64, 0, stream>>>(stats + 3 * 256, g22, b22, 1.0f / NVOX, 64);
    apply_bn_kernel<64, 3, 0, 1><<<cdiv(NVOX * 16L, 256), B256, 0, stream>>>(A, stats + 3 * 256, H, feats, H, nullptr, NVOX * 16L);

    // ---- partial tensor chain (same weights) ----
    xhalf_kernel<<<cdiv(8000000, 256), B256, 0, stream>>>(featsp, P0, 8000000L);
    conv_mfma_kernel<<<cdiv(NPART, 128), B256, 0, stream>>>(P0, nbrp, wh11, wl11, A, stats + 4 * 256, NPART);
    mkscale_kernel<<<1, 64, 0, stream>>>(stats + 4 * 256, g11, b11, 1.0f / NPART, 64);
    apply_bn_kernel<64, 1, 1, 0><<<cdiv(NPART * 16L, 256), B256, 0, stream>>>(A, stats + 4 * 256, nullptr, nullptr, nullptr, P1, NPART * 16L);
    conv_mfma_kernel<<<cdiv(NPART, 128), B256, 0, stream>>>(P1, nbrp, wh12, wl12, A, stats + 5 * 256, NPART);
    mkscale_kernel<<<1, 64, 0, stream>>>(stats + 5 * 256, g12, b12, 1.0f / NPART, 64);
    apply_bn_kernel<64, 2, 1, 1><<<cdiv(NPART * 16L, 256), B256, 0, stream>>>(A, stats + 5 * 256, featsp, nullptr, Hpf32, P0, NPART * 16L);
    conv_mfma_kernel<<<cdiv(NPART, 128), B256, 0, stream>>>(P0, nbrp, wh21, wl21, A, stats + 6 * 256, NPART);
    mkscale_kernel<<<1, 64, 0, stream>>>(stats + 6 * 256, g21, b21, 1.0f / NPART, 64);
    apply_bn_kernel<64, 1, 1, 0><<<cdiv(NPART * 16L, 256), B256, 0, stream>>>(A, stats + 6 * 256, nullptr, nullptr, nullptr, P1, NPART * 16L);
    conv_mfma_kernel<<<cdiv(NPART, 128), B256, 0, stream>>>(P1, nbrp, wh22, wl22, A, stats + 7 * 256, NPART);
    mkscale_kernel<<<1, 64, 0, stream>>>(stats + 7 * 256, g22, b22, 1.0f / NPART, 64);
    apply_bn_kernel<64, 2, 0, 1><<<cdiv(NPART * 16L, 256), B256, 0, stream>>>(A, stats + 7 * 256, Hpf32, nullptr, Cp, nullptr, NPART * 16L);

    // ---- logits (pre-GEMM + scalar gather) + BCE loss ----
    slog_kernel<<<cdiv(NPART, 64), B256, 0, stream>>>(Cp, Wlog, slog, NPART);
    logit_gather_kernel<<<cdiv(NPART, 256), B256, 0, stream>>>(slog, nbrp, blog, logitb, NPART);
    loss_scatter1_kernel<<<cdiv(NVOX, 256), B256, 0, stream>>>(coors, tflag, winner, NVOX, NPART);
    loss_scatter2_kernel<<<cdiv(NPART, 256), B256, 0, stream>>>(coors, winner, logitb, xdense, NPART);
    loss_reduce_kernel<<<NCELL / 256, B256, 0, stream>>>(xdense, tflag, lacc);

    // ---- CSR builds for cin (NPTS->NNEXT) and dsinv (NVOX->NDS) ----
    fill_u32_kernel<<<cdiv(100000, 256), B256, 0, stream>>>((unsigned*)cnt_cin, 0u, 100000);
    fill_u32_kernel<<<cdiv(100000, 256), B256, 0, stream>>>((unsigned*)cnt_ds, 0u, 100000);
    hist_kernel<<<cdiv(NPTS, 256), B256, 0, stream>>>(cin, cnt_cin, NPTS);
    hist_kernel<<<cdiv(NVOX, 256), B256, 0, stream>>>(dsinv, cnt_ds, NVOX);
    scan_reduce_kernel<<<98, B256, 0, stream>>>(cnt_cin, bsum, 100000);
    scan_top_kernel<<<1, B256, 0, stream>>>(bsum, 98);
    scan_final_kernel<<<98, B256, 0, stream>>>(cnt_cin, bsum, offs_cin, cursor_cin, 100000);
    scan_reduce_kernel<<<98, B256, 0, stream>>>(cnt_ds, bsum, 100000);
    scan_top_kernel<<<1, B256, 0, stream>>>(bsum, 98);
    scan_final_kernel<<<98, B256, 0, stream>>>(cnt_ds, bsum, offs_ds, cursor_ds, 100000);
    place_kernel<<<cdiv(NPTS, 256), B256, 0, stream>>>(cin, cursor_cin, perm_cin, NPTS);
    place_kernel<<<cdiv(NVOX, 256), B256, 0, stream>>>(dsinv, cursor_ds, perm_ds, NVOX);

    // ---- point encoder ----
    segmean_kernel<<<cdiv(NDS, 4), B256, 0, stream>>>(H, perm_ds, offs_ds, cnt_ds, dssum, NDS);
    // identity = leaky(H @ Wi + bi) -> fp16 Ah (A fp32 dead; region reused)
    gemm_kernel<64, 64, 1, 1><<<cdiv(NVOX, 64), B256, 0, stream>>>(H, Wi, bi, Ah, NVOX);

    gemm_kernel<64, 32, 1, 0><<<cdiv(NDS, 128), B256, 0, stream>>>(dssum, Wp1, bp1, t1b, NDS);
    colstats_kernel<32><<<256, B256, 0, stream>>>(t1b, NDS, stats + 8 * 256);
    mkscale_kernel<<<1, 64, 0, stream>>>(stats + 8 * 256, gp1, bp1n, 1.0f / NDS, 32);
    apply_bn_kernel<32, 0, 0, 1><<<cdiv((long)NDS * 8, 256), B256, 0, stream>>>(t1b, stats + 8 * 256, nullptr, nullptr, t1b, nullptr, (long)NDS * 8);

    gemm_kernel<32, 32, 1, 0><<<cdiv(NDS, 128), B256, 0, stream>>>(t1b, Wp2, bp2, t2b, NDS);
    colstats_kernel<32><<<256, B256, 0, stream>>>(t2b, NDS, stats + 9 * 256);
    mkscale_kernel<<<1, 64, 0, stream>>>(stats + 9 * 256, gp2, bp2n, 1.0f / NDS, 32);
    apply_bn_kernel<32, 0, 0, 1><<<cdiv((long)NDS * 8, 256), B256, 0, stream>>>(t2b, stats + 9 * 256, nullptr, nullptr, t2b, nullptr, (long)NDS * 8);

    // h3 = leaky(t2 @ Wp3 + bp3) -> fp16 h3h
    gemm_kernel<32, 64, 1, 1><<<cdiv(NDS, 64), B256, 0, stream>>>(t2b, Wp3, bp3, h3h, NDS);

    // ---- MFMA layer_out + CSR segment-mean ----
    layer_out_mfma_kernel<<<cdiv(NPTS, 64), B256, 0, stream>>>(Ah, h3h, cil, dsinv,
        wo1hi, wo1lo, wo2hi, wo2lo, bo1, bo2, lob0, lob1, lob2, NPTS);
    segmean_lob_kernel<<<cdiv(NNEXT, 4), B256, 0, stream>>>(lob0, lob1, lob2, perm_cin, offs_cin, cnt_cin, psum, NNEXT);

    // ---- final outputs ----
    gather_out_kernel<<<cdiv((long)NPTS * 16, 256), B256, 0, stream>>>(psum, cin, out, NPTS);
    loss_final_kernel<<<1, 1, 0, stream>>>(lacc, out + 38400000L);
}